// Round 2
// baseline (429.640 us; speedup 1.0000x reference)
//
#include <hip/hip_runtime.h>
#include <hip/hip_bf16.h>
#include <hip/hip_cooperative_groups.h>
#include <math.h>

namespace cg = cooperative_groups;

// TimeBERT forward on MI355X. Inputs fp32 (runtime bf16 detector, inline).
// OUTPUT FP32: [cls_pooling (8,128) | last_hidden (8,512,128)].
//
// R19: single cooperative mega-kernel. Analysis showed total compute is only
// ~30-40us but end-to-end was ~185us: ~75% was the 5 inter-kernel boundaries
// (drain + dispatch ramp + launch latency ~25us each). All six phases are now
// grid-stride loops inside ONE kernel separated by grid.sync() (~3-6us each).
// Phase bodies identical to R18; six standalone kernels kept as fallback if
// cooperative launch fails under graph capture.

static constexpr int NM_ = 8 * 513;           // 4104 main rows
static constexpr int NC_ = 8 * 129;           // 1032 cls rows
static constexpr int NT_ = NM_ + NC_;         // 5136 total (= 321 * 16)
static constexpr int VTS_ = 5248;             // vT row stride (>= 5136+..., 16-mult)

using bf = __hip_bfloat16;
typedef __attribute__((ext_vector_type(8))) short bf16x8;
typedef __attribute__((ext_vector_type(4))) short bf16x4;
typedef __attribute__((ext_vector_type(4))) float floatx4;
typedef __attribute__((ext_vector_type(8))) unsigned short ushortx8;

__device__ __forceinline__ float wave_reduce_sum(float v) {
    #pragma unroll
    for (int off = 32; off >= 1; off >>= 1) v += __shfl_xor(v, off);
    return v;
}
__device__ __forceinline__ float wave_reduce_max(float v) {
    #pragma unroll
    for (int off = 32; off >= 1; off >>= 1) v = fmaxf(v, __shfl_xor(v, off));
    return v;
}
__device__ __forceinline__ float u2f(unsigned short u) {
    return __uint_as_float(((unsigned)u) << 16);
}
__device__ __forceinline__ unsigned short f2u(float f) {   // RNE, finite
    unsigned u = __float_as_uint(f);
    return (unsigned short)((u + 0x7FFF + ((u >> 16) & 1)) >> 16);
}
__device__ __forceinline__ bf16x8 join8(bf16x4 lo, bf16x4 hi) {
    return __builtin_shufflevector(lo, hi, 0, 1, 2, 3, 4, 5, 6, 7);
}
__device__ __forceinline__ float rdin(const void* p, int i, int flag) {
    return flag ? u2f(((const unsigned short*)p)[i]) : ((const float*)p)[i];
}

// ---------------------------------------------------------------------------
// Shared-memory structs (union'd in the fused kernel; max = 21,760 B)
struct MaS { unsigned short sp[16][520]; float red[1280]; };
struct MqS { float As32[16][36]; unsigned short As[16][136]; };
struct TbS { unsigned short sp[16][588]; float rinv[16]; };
struct AoS {
    unsigned short As[16][136]; float Xs[16][128]; unsigned short Hs[16][136];
    float redS[4][4][4], redQ[4][4][4], smean[16], sinv[16], x2row[128];
    int poolb;
};
union SMem { MaS ma; MqS mq; TbS tb; AoS ao; };

// ---------------------------------------------------------------------------
// prep: [0,ncv) dense conversion; [ncv,+512) weight swizzle; [+2112) time emb;
// [+32) Bt build; [+7) vT tail zero.
struct PrepAll {
    const void* src[32]; int n[32]; int dstoff[32];
    int cstart[32]; int cnum[32];
    int ncv;
    const void* wsrc[8]; unsigned short* wdst[8]; float wscale[8];
    const void* ts; const void* w_per; const void* b_per;
    const void* w_lin; const void* b_lin;
    unsigned short* key_e16;
    unsigned short* btg;            // [b][c(16)][k(512)] bf16: c<8 -> x*m, else m
    const void* xsrc;               // raw x input (B,512,16)
    unsigned short* vt;             // transposed V buffer (tail-zeroed here)
    const unsigned short* det;
};

__device__ __forceinline__ void prep_body(const PrepAll& a, float* dst, int blk,
                                          int tid, int flag) {
    if (blk < a.ncv) {
        int which = -1, bi = 0;
        #pragma unroll
        for (int i = 0; i < 32; ++i)
            if (blk >= a.cstart[i] && blk < a.cstart[i] + a.cnum[i]) { which = i; bi = blk - a.cstart[i]; }
        if (which >= 0) {
            int i = bi * 256 + tid;
            if (i < a.n[which]) dst[a.dstoff[which] + i] = rdin(a.src[which], i, flag);
        }
    } else if (blk < a.ncv + 512) {
        int p = blk - a.ncv;
        int m = p >> 6;
        int idx = (p & 63) * 256 + tid;
        int c = idx >> 9;
        int l = (idx >> 3) & 63;
        int j = idx & 7;
        int k = (c >> 3) * 32 + (l >> 4) * 8 + j;
        int n = (c & 7) * 16 + (l & 15);
        a.wdst[m][idx] = f2u(rdin(a.wsrc[m], k * 128 + n, flag) * a.wscale[m]);
    } else if (blk < a.ncv + 512 + 2112) {
        int p = blk - a.ncv - 512;
        int row = p * 2 + (tid >> 7), j = tid & 127;
        float t = (row < 4096) ? rdin(a.ts, row, flag)
                               : (float)(row - 4096) * (1.0f / 127.0f);
        float v;
        if (j == 0) v = t * rdin(a.w_lin, 0, flag) + rdin(a.b_lin, 0, flag);
        else        v = sinf(t * rdin(a.w_per, j - 1, flag) + rdin(a.b_per, j - 1, flag));
        a.key_e16[row * 128 + j] = f2u(v);
    } else if (blk < a.ncv + 512 + 2112 + 32) {
        int p = blk - a.ncv - 512 - 2112;
        int e0 = (p * 256 + tid) * 8;
        int b = e0 >> 13;
        int c = (e0 >> 9) & 15;
        int k0 = e0 & 511;
        unsigned short out[8];
        #pragma unroll
        for (int j = 0; j < 8; ++j) {
            int k = k0 + j;
            float m = rdin(a.xsrc, (b * 512 + k) * 16 + 8 + (c & 7), flag);
            float val = (c < 8) ? rdin(a.xsrc, (b * 512 + k) * 16 + c, flag) * m : m;
            out[j] = f2u(val);
        }
        *(ushortx8*)(a.btg + e0) = *(ushortx8*)out;
    } else {
        int p = blk - a.ncv - 512 - 2112 - 32;
        int idx = p * 256 + tid;            // 0..1791 = 128*14
        if (idx < 128 * 14) {
            int n = idx / 14, c8 = idx - n * 14;
            ushortx8 z = {0, 0, 0, 0, 0, 0, 0, 0};
            *(ushortx8*)(a.vt + (size_t)n * VTS_ + 5136 + c8 * 8) = z;
        }
    }
}

__global__ void prep_all_kernel(PrepAll a, float* dst) {
    int flag = (a.det[0] == 0x3F80u) ? 1 : 0;
    prep_body(a, dst, blockIdx.x, threadIdx.x, flag);
}

// ---------------------------------------------------------------------------
// MFMA GEMM (projections): C16 = bf16(A16@W + bias*bscale). A-frags direct
// from global (tiles 16-row aligned, M multiple of 16) -> no LDS, no barrier.
struct GemmM {
    const void* A[3]; const unsigned short* W[3]; const float* bias[3];
    unsigned short* C[3];
    int M[3]; float bscale[3];
};

__device__ __forceinline__ void gemm_body(const unsigned short* A, const unsigned short* Wsw,
                                          const float* bias, unsigned short* C,
                                          float bscale, int m0, int tid) {
    int wv = tid >> 6, lane = tid & 63;
    int am = lane & 15, aq = lane >> 4;
    const unsigned short* Arow = A + (size_t)(m0 + am) * 128;
    floatx4 acc0 = {0.f, 0.f, 0.f, 0.f}, acc1 = acc0;
    #pragma unroll
    for (int ks = 0; ks < 4; ++ks) {
        bf16x8 af = *(const bf16x8*)(Arow + ks * 32 + aq * 8);
        const unsigned short* base = Wsw + ((size_t)ks * 8 + 2 * wv) * 512 + lane * 8;
        bf16x8 b0 = *(const bf16x8*)(base);
        bf16x8 b1 = *(const bf16x8*)(base + 512);
        acc0 = __builtin_amdgcn_mfma_f32_16x16x32_bf16(af, b0, acc0, 0, 0, 0);
        acc1 = __builtin_amdgcn_mfma_f32_16x16x32_bf16(af, b1, acc1, 0, 0, 0);
    }
    int col = lane & 15, rowb = (lane >> 4) * 4;
    #pragma unroll
    for (int t = 0; t < 2; ++t) {
        floatx4 acc = t ? acc1 : acc0;
        int n = wv * 32 + t * 16 + col;
        float bv = bias[n] * bscale;
        #pragma unroll
        for (int rg = 0; rg < 4; ++rg)
            C[(size_t)(m0 + rowb + rg) * 128 + n] = f2u(acc[rg] + bv);
    }
}

__global__ void __launch_bounds__(256)
gemm_mfma_kernel(GemmM p) {
    int y = blockIdx.y;
    int m0 = blockIdx.x * 16;
    if (m0 >= p.M[y]) return;
    gemm_body((const unsigned short*)p.A[y], p.W[y], p.bias[y], p.C[y], p.bscale[y],
              m0, threadIdx.x);
}

// ---------------------------------------------------------------------------
// mta attention: MFMA QK^T with K B-frags direct from global (L2-resident),
// masked sums as P@Bt (Bt precomputed, global).
__device__ __forceinline__ void mta_att_body(
    const unsigned short* qp_cls, const unsigned short* qp_main,
    const unsigned short* kp, const unsigned short* btg,
    float* att_cls, float* att_mn,
    int is_cls, int qt, int h, int b, int tid, MaS* S)
{
    __syncthreads();                 // protect LDS reuse across loop iterations
    int lane = tid & 63, wv = tid >> 6;
    int q0 = qt * 16;
    int m = lane & 15, g = lane >> 4;

    const unsigned short* qrow = is_cls ? (qp_cls + (size_t)(q0 + m) * 128 + h * 64)
                                        : (qp_main + (size_t)(b * 512 + q0 + m) * 128 + h * 64);
    bf16x8 qf0 = *(const bf16x8*)(qrow + g * 8);
    bf16x8 qf1 = *(const bf16x8*)(qrow + 32 + g * 8);

    const unsigned short* kbase = kp + ((size_t)b * 512) * 128 + h * 64;
    #pragma unroll
    for (int kt = 0; kt < 8; ++kt) {
        int colk = kt * 64 + wv * 16 + m;
        const unsigned short* kb = kbase + (size_t)colk * 128;
        bf16x8 b0 = *(const bf16x8*)(kb + g * 8);
        bf16x8 b1 = *(const bf16x8*)(kb + 32 + g * 8);
        floatx4 acc = {0.f, 0.f, 0.f, 0.f};
        acc = __builtin_amdgcn_mfma_f32_16x16x32_bf16(qf0, b0, acc, 0, 0, 0);
        acc = __builtin_amdgcn_mfma_f32_16x16x32_bf16(qf1, b1, acc, 0, 0, 0);
        #pragma unroll
        for (int rg = 0; rg < 4; ++rg) S->sp[g * 4 + rg][colk] = f2u(acc[rg]);
    }
    __syncthreads();

    for (int rr = wv; rr < 16; rr += 4) {
        float mx = -1e30f;
        for (int k = lane; k < 512; k += 64) mx = fmaxf(mx, u2f(S->sp[rr][k]));
        mx = wave_reduce_max(mx);
        for (int k = lane; k < 512; k += 64) S->sp[rr][k] = f2u(expf(u2f(S->sp[rr][k]) - mx));
    }
    __syncthreads();

    floatx4 macc = {0.f, 0.f, 0.f, 0.f};
    {
        const unsigned short* bbase = btg + ((size_t)(b * 16 + m)) * 512 + g * 8;
        #pragma unroll
        for (int cc = 0; cc < 4; ++cc) {
            int koff = (wv + cc * 4) * 32;
            bf16x8 af = *(const bf16x8*)&S->sp[m][koff + g * 8];
            bf16x8 bfv = *(const bf16x8*)(bbase + koff);
            macc = __builtin_amdgcn_mfma_f32_16x16x32_bf16(af, bfv, macc, 0, 0, 0);
        }
    }
    float* redC = S->red;
    float* Cfull = S->red + 1024;
    #pragma unroll
    for (int rg = 0; rg < 4; ++rg) redC[tid * 4 + rg] = macc[rg];
    __syncthreads();
    {
        int l = tid >> 2, rg = tid & 3;
        float s = redC[l * 4 + rg] + redC[(64 + l) * 4 + rg]
                + redC[(128 + l) * 4 + rg] + redC[(192 + l) * 4 + rg];
        int row = (l >> 4) * 4 + rg, c = l & 15;
        Cfull[row * 16 + c] = s;
    }
    __syncthreads();
    if (tid < 128) {
        int r = tid >> 3, c = tid & 7;
        float num = Cfull[r * 16 + c];
        float den = Cfull[r * 16 + 8 + c];
        int row = q0 + r;
        float* dst = is_cls ? (att_cls + (size_t)(b * 128 + row) * 32)
                            : (att_mn + (size_t)(b * 512 + row) * 32);
        dst[h * 16 + c] = num / den;
        dst[h * 16 + 8 + c] = 1.0f;
    }
}

__global__ void __launch_bounds__(256)
mta_att_kernel(const unsigned short* qp_cls, const unsigned short* qp_main,
               const unsigned short* kp, const unsigned short* btg,
               float* att_cls, float* att_mn) {
    __shared__ MaS S;
    int xx = blockIdx.x;
    mta_att_body(qp_cls, qp_main, kp, btg, att_cls, att_mn,
                 xx >= 32, (xx >= 32) ? xx - 32 : xx, blockIdx.y, blockIdx.z,
                 threadIdx.x, &S);
}

// ---------------------------------------------------------------------------
// mta-out (K=32, inverse row map) + assemble + QKV MFMA (V written transposed).
__device__ __forceinline__ void mta_qkv_body(
    const float* att, const float* Wo, const float* bo,
    const float* cls_emb, const float* pos, float* xin,
    const unsigned short* Wq, const unsigned short* Wk, const unsigned short* Wv,
    const float* bq, const float* bk, const float* bv_,
    unsigned short* outq, unsigned short* outk, unsigned short* vT,
    int m0, int tid, MqS* S)
{
    __syncthreads();
    int r = tid >> 4, g = tid & 15, c0 = g * 8;

    int R = m0 + r;
    int srow, prow;
    if (R < NM_) {
        int b = R / 513, rr = R - b * 513;
        srow = (rr == 0) ? -1 : 1024 + b * 512 + (rr - 1);
        prow = rr;
    } else {
        int mc = R - NM_;
        int b = mc / 129, rr = mc - b * 129;
        srow = (rr == 0) ? -1 : b * 128 + (rr - 1);
        prow = -1;
    }
    if (g < 2 && srow >= 0) {
        const float* src = att + (size_t)srow * 32 + g * 16;
        *(float4*)&S->As32[r][g * 16]      = *(const float4*)(src);
        *(float4*)&S->As32[r][g * 16 + 4]  = *(const float4*)(src + 4);
        *(float4*)&S->As32[r][g * 16 + 8]  = *(const float4*)(src + 8);
        *(float4*)&S->As32[r][g * 16 + 12] = *(const float4*)(src + 12);
    }
    __syncthreads();

    float acc[8];
    if (srow < 0) {
        #pragma unroll
        for (int j = 0; j < 8; ++j) acc[j] = cls_emb[c0 + j];
    } else {
        #pragma unroll
        for (int j = 0; j < 8; ++j) acc[j] = bo[c0 + j];
        #pragma unroll 8
        for (int k = 0; k < 32; ++k) {
            float a = S->As32[r][k];
            const float4 w0 = *(const float4*)(Wo + (size_t)k * 128 + c0);
            const float4 w1 = *(const float4*)(Wo + (size_t)k * 128 + c0 + 4);
            acc[0] = fmaf(a, w0.x, acc[0]); acc[1] = fmaf(a, w0.y, acc[1]);
            acc[2] = fmaf(a, w0.z, acc[2]); acc[3] = fmaf(a, w0.w, acc[3]);
            acc[4] = fmaf(a, w1.x, acc[4]); acc[5] = fmaf(a, w1.y, acc[5]);
            acc[6] = fmaf(a, w1.z, acc[6]); acc[7] = fmaf(a, w1.w, acc[7]);
        }
    }
    if (prow >= 0) {
        const float* pr = pos + (size_t)prow * 128 + c0;
        float4 p0 = *(const float4*)(pr);
        float4 p1 = *(const float4*)(pr + 4);
        acc[0] += p0.x; acc[1] += p0.y; acc[2] += p0.z; acc[3] += p0.w;
        acc[4] += p1.x; acc[5] += p1.y; acc[6] += p1.z; acc[7] += p1.w;
    }
    *(float4*)(xin + (size_t)R * 128 + c0) = make_float4(acc[0], acc[1], acc[2], acc[3]);
    *(float4*)(xin + (size_t)R * 128 + c0 + 4) = make_float4(acc[4], acc[5], acc[6], acc[7]);
    *(ushort4*)&S->As[r][c0] = make_ushort4(f2u(acc[0]), f2u(acc[1]), f2u(acc[2]), f2u(acc[3]));
    *(ushort4*)&S->As[r][c0 + 4] = make_ushort4(f2u(acc[4]), f2u(acc[5]), f2u(acc[6]), f2u(acc[7]));
    __syncthreads();

    int wv = tid >> 6, lane = tid & 63;
    int am = lane & 15, aq = lane >> 4;
    int col = lane & 15, rowb = (lane >> 4) * 4;
    const unsigned short* Ws[3] = {Wq, Wk, Wv};
    const float* bs[3] = {bq, bk, bv_};
    float bsc[3] = {0.125f, 1.f, 1.f};
    unsigned short* Cs[2] = {outq, outk};
    #pragma unroll
    for (int y = 0; y < 3; ++y) {
        floatx4 acc0 = {0.f, 0.f, 0.f, 0.f}, acc1 = acc0;
        #pragma unroll
        for (int ks = 0; ks < 4; ++ks) {
            bf16x8 af = *(bf16x8*)&S->As[am][ks * 32 + aq * 8];
            const unsigned short* base = Ws[y] + ((size_t)ks * 8 + 2 * wv) * 512 + lane * 8;
            bf16x8 b0 = *(const bf16x8*)(base);
            bf16x8 b1 = *(const bf16x8*)(base + 512);
            acc0 = __builtin_amdgcn_mfma_f32_16x16x32_bf16(af, b0, acc0, 0, 0, 0);
            acc1 = __builtin_amdgcn_mfma_f32_16x16x32_bf16(af, b1, acc1, 0, 0, 0);
        }
        #pragma unroll
        for (int t = 0; t < 2; ++t) {
            floatx4 a2 = t ? acc1 : acc0;
            int n = wv * 32 + t * 16 + col;
            float bvv = bs[y][n] * bsc[y];
            #pragma unroll
            for (int rg = 0; rg < 4; ++rg) {
                unsigned short val = f2u(a2[rg] + bvv);
                if (y < 2) Cs[y][(size_t)(m0 + rowb + rg) * 128 + n] = val;
                else       vT[(size_t)n * VTS_ + (m0 + rowb + rg)] = val;
            }
        }
    }
}

__global__ void __launch_bounds__(256)
mta_qkv_kernel(const float* att, const float* Wo, const float* bo,
               const float* cls_emb, const float* pos, float* xin,
               const unsigned short* Wq, const unsigned short* Wk, const unsigned short* Wv,
               const float* bq, const float* bk, const float* bv_,
               unsigned short* outq, unsigned short* outk, unsigned short* vT) {
    __shared__ MqS S;
    mta_qkv_body(att, Wo, bo, cls_emb, pos, xin, Wq, Wk, Wv, bq, bk, bv_,
                 outq, outk, vT, blockIdx.x * 16, threadIdx.x, &S);
}

// ---------------------------------------------------------------------------
// tblock attention: MFMA QK^T + PV, K and V^T B-frags direct from global.
__device__ __forceinline__ void tb_att_body(
    const unsigned short* qp, const unsigned short* kp,
    const unsigned short* vT, unsigned short* outp,
    int is_cls, int qt, int h, int b, int tid, TbS* S)
{
    __syncthreads();                 // PV of prev iteration reads sp after last sync
    int Lq = is_cls ? 129 : 513;
    int base = is_cls ? (4104 + b * 129) : (b * 513);
    int nkt = is_cls ? 3 : 9;
    int lane = tid & 63, wv = tid >> 6;
    int q0 = qt * 16;
    int m = lane & 15, g = lane >> 4;

    int qr = q0 + m; if (qr >= Lq) qr = Lq - 1;   // padded rows: duplicate, discarded
    const unsigned short* qrow = qp + (size_t)(base + qr) * 128 + h * 64;
    bf16x8 qf0 = *(const bf16x8*)(qrow + g * 8);
    bf16x8 qf1 = *(const bf16x8*)(qrow + 32 + g * 8);

    for (int kt = 0; kt < nkt; ++kt) {
        int colk = kt * 64 + wv * 16 + m;
        int krow = (colk < Lq) ? colk : (Lq - 1);
        const unsigned short* kb = kp + (size_t)(base + krow) * 128 + h * 64;
        bf16x8 b0 = *(const bf16x8*)(kb + g * 8);
        bf16x8 b1 = *(const bf16x8*)(kb + 32 + g * 8);
        floatx4 acc = {0.f, 0.f, 0.f, 0.f};
        acc = __builtin_amdgcn_mfma_f32_16x16x32_bf16(qf0, b0, acc, 0, 0, 0);
        acc = __builtin_amdgcn_mfma_f32_16x16x32_bf16(qf1, b1, acc, 0, 0, 0);
        #pragma unroll
        for (int rg = 0; rg < 4; ++rg)
            S->sp[g * 4 + rg][colk] = f2u((colk < Lq) ? acc[rg] : -1e30f);
    }
    __syncthreads();

    int kend = nkt * 64;
    for (int rr = wv; rr < 16; rr += 4) {
        float mx = -1e30f;
        for (int k = lane; k < kend; k += 64) mx = fmaxf(mx, u2f(S->sp[rr][k]));
        mx = wave_reduce_max(mx);
        float sum = 0.f;
        for (int k = lane; k < kend; k += 64) {
            float e = expf(u2f(S->sp[rr][k]) - mx);
            S->sp[rr][k] = f2u(e);
            sum += e;
        }
        sum = wave_reduce_sum(sum);
        if (lane == 0) S->rinv[rr] = 1.f / sum;
    }
    __syncthreads();

    floatx4 oacc = {0.f, 0.f, 0.f, 0.f};
    const unsigned short* vbase = vT + (size_t)(h * 64 + wv * 16 + m) * VTS_ + base;
    for (int kt = 0; kt < nkt; ++kt) {
        int k0 = kt * 64;
        #pragma unroll
        for (int c = 0; c < 2; ++c) {
            bf16x4 plo = *(const bf16x4*)&S->sp[m][k0 + c * 32 + g * 8];
            bf16x4 phi = *(const bf16x4*)&S->sp[m][k0 + c * 32 + g * 8 + 4];
            bf16x8 vf = *(const bf16x8*)(vbase + k0 + c * 32 + g * 8);
            oacc = __builtin_amdgcn_mfma_f32_16x16x32_bf16(join8(plo, phi), vf, oacc, 0, 0, 0);
        }
    }
    int dcol = wv * 16 + m;
    #pragma unroll
    for (int rg = 0; rg < 4; ++rg) {
        int q = g * 4 + rg;
        int qout = q0 + q;
        if (qout < Lq)
            outp[(size_t)(base + qout) * 128 + h * 64 + dcol] = f2u(oacc[rg] * S->rinv[q]);
    }
}

__global__ void __launch_bounds__(256)
tb_att_kernel(const unsigned short* qp, const unsigned short* kp,
              const unsigned short* vT, unsigned short* outp) {
    __shared__ TbS S;
    int xx = blockIdx.x;
    tb_att_body(qp, kp, vT, outp, xx >= 33, (xx >= 33) ? xx - 33 : xx,
                blockIdx.y, blockIdx.z, threadIdx.x, &S);
}

// ---------------------------------------------------------------------------
// attnout + LN1 + FFN1 + FFN2 + LN2 + pool -> d_out.
__device__ __forceinline__ void attnout_body(
    const unsigned short* A, const unsigned short* Wao, const float* bao,
    const float* resid, const float* g1, const float* b1ln,
    const unsigned short* W1, const float* fb1,
    const unsigned short* W2, const float* fb2,
    const float* g2, const float* b2ln,
    const float* pW, const float* pb, float* dout,
    int m0, int tid, AoS* S)
{
    __syncthreads();
    if (tid == 0) S->poolb = -1;
    {
        int r = tid >> 4, c0 = (tid & 15) * 8;
        *(ushortx8*)&S->As[r][c0] = *(const ushortx8*)(A + (size_t)(m0 + r) * 128 + c0);
    }
    __syncthreads();

    int wv = tid >> 6, lane = tid & 63;
    int am = lane & 15, aq = lane >> 4;
    int col = lane & 15, g = lane >> 4, rowb = g * 4;

    float ov[2][4];
    {
        floatx4 acc0 = {0.f, 0.f, 0.f, 0.f}, acc1 = acc0;
        #pragma unroll
        for (int ks = 0; ks < 4; ++ks) {
            bf16x8 af = *(bf16x8*)&S->As[am][ks * 32 + aq * 8];
            const unsigned short* base = Wao + ((size_t)ks * 8 + 2 * wv) * 512 + lane * 8;
            bf16x8 bb0 = *(const bf16x8*)(base);
            bf16x8 bb1 = *(const bf16x8*)(base + 512);
            acc0 = __builtin_amdgcn_mfma_f32_16x16x32_bf16(af, bb0, acc0, 0, 0, 0);
            acc1 = __builtin_amdgcn_mfma_f32_16x16x32_bf16(af, bb1, acc1, 0, 0, 0);
        }
        #pragma unroll
        for (int t = 0; t < 2; ++t) {
            int n = wv * 32 + t * 16 + col;
            float bv = bao[n];
            floatx4 acc = t ? acc1 : acc0;
            #pragma unroll
            for (int rg = 0; rg < 4; ++rg)
                ov[t][rg] = acc[rg] + bv + resid[(size_t)(m0 + rowb + rg) * 128 + n];
        }
    }
    #pragma unroll
    for (int rg = 0; rg < 4; ++rg) {
        float s = ov[0][rg] + ov[1][rg];
        float q = ov[0][rg] * ov[0][rg] + ov[1][rg] * ov[1][rg];
        #pragma unroll
        for (int off = 8; off >= 1; off >>= 1) {
            s += __shfl_xor(s, off);
            q += __shfl_xor(q, off);
        }
        if ((lane & 15) == 0) { S->redS[wv][g][rg] = s; S->redQ[wv][g][rg] = q; }
    }
    __syncthreads();
    if (tid < 16) {
        int gg = tid >> 2, rg = tid & 3;
        float s = S->redS[0][gg][rg] + S->redS[1][gg][rg] + S->redS[2][gg][rg] + S->redS[3][gg][rg];
        float q = S->redQ[0][gg][rg] + S->redQ[1][gg][rg] + S->redQ[2][gg][rg] + S->redQ[3][gg][rg];
        float mean = s * 0.0078125f;
        float var = q * 0.0078125f - mean * mean;
        S->smean[tid] = mean;
        S->sinv[tid] = rsqrtf(var + 1e-5f);
    }
    __syncthreads();
    #pragma unroll
    for (int t = 0; t < 2; ++t) {
        int n = wv * 32 + t * 16 + col;
        float gm = g1[n], bb = b1ln[n];
        #pragma unroll
        for (int rg = 0; rg < 4; ++rg) {
            int row = rowb + rg;
            float val = (ov[t][rg] - S->smean[row]) * S->sinv[row] * gm + bb;
            S->Xs[row][n] = val;
            S->As[row][n] = f2u(val);
        }
    }
    __syncthreads();

    {
        floatx4 acc0 = {0.f, 0.f, 0.f, 0.f}, acc1 = acc0;
        #pragma unroll
        for (int ks = 0; ks < 4; ++ks) {
            bf16x8 af = *(bf16x8*)&S->As[am][ks * 32 + aq * 8];
            const unsigned short* base = W1 + ((size_t)ks * 8 + 2 * wv) * 512 + lane * 8;
            bf16x8 bb0 = *(const bf16x8*)(base);
            bf16x8 bb1 = *(const bf16x8*)(base + 512);
            acc0 = __builtin_amdgcn_mfma_f32_16x16x32_bf16(af, bb0, acc0, 0, 0, 0);
            acc1 = __builtin_amdgcn_mfma_f32_16x16x32_bf16(af, bb1, acc1, 0, 0, 0);
        }
        #pragma unroll
        for (int t = 0; t < 2; ++t) {
            int n = wv * 32 + t * 16 + col;
            float bv = fb1[n];
            floatx4 acc = t ? acc1 : acc0;
            #pragma unroll
            for (int rg = 0; rg < 4; ++rg)
                S->Hs[rowb + rg][n] = f2u(fmaxf(acc[rg] + bv, 0.f));
        }
    }
    __syncthreads();

    floatx4 acc0 = {0.f, 0.f, 0.f, 0.f}, acc1 = acc0;
    #pragma unroll
    for (int ks = 0; ks < 4; ++ks) {
        bf16x8 af = *(bf16x8*)&S->Hs[am][ks * 32 + aq * 8];
        const unsigned short* base = W2 + ((size_t)ks * 8 + 2 * wv) * 512 + lane * 8;
        bf16x8 bb0 = *(const bf16x8*)(base);
        bf16x8 bb1 = *(const bf16x8*)(base + 512);
        acc0 = __builtin_amdgcn_mfma_f32_16x16x32_bf16(af, bb0, acc0, 0, 0, 0);
        acc1 = __builtin_amdgcn_mfma_f32_16x16x32_bf16(af, bb1, acc1, 0, 0, 0);
    }
    #pragma unroll
    for (int t = 0; t < 2; ++t) {
        int n = wv * 32 + t * 16 + col;
        float bv = fb2[n];
        floatx4 acc = t ? acc1 : acc0;
        #pragma unroll
        for (int rg = 0; rg < 4; ++rg)
            ov[t][rg] = acc[rg] + bv + S->Xs[rowb + rg][n];
    }
    #pragma unroll
    for (int rg = 0; rg < 4; ++rg) {
        float s = ov[0][rg] + ov[1][rg];
        float q = ov[0][rg] * ov[0][rg] + ov[1][rg] * ov[1][rg];
        #pragma unroll
        for (int off = 8; off >= 1; off >>= 1) {
            s += __shfl_xor(s, off);
            q += __shfl_xor(q, off);
        }
        if ((lane & 15) == 0) { S->redS[wv][g][rg] = s; S->redQ[wv][g][rg] = q; }
    }
    __syncthreads();
    if (tid < 16) {
        int gg = tid >> 2, rg = tid & 3;
        float s = S->redS[0][gg][rg] + S->redS[1][gg][rg] + S->redS[2][gg][rg] + S->redS[3][gg][rg];
        float q = S->redQ[0][gg][rg] + S->redQ[1][gg][rg] + S->redQ[2][gg][rg] + S->redQ[3][gg][rg];
        float mean = s * 0.0078125f;
        float var = q * 0.0078125f - mean * mean;
        S->smean[tid] = mean;
        S->sinv[tid] = rsqrtf(var + 1e-5f);
    }
    __syncthreads();
    #pragma unroll
    for (int t = 0; t < 2; ++t) {
        int n = wv * 32 + t * 16 + col;
        float gm = g2[n], bb = b2ln[n];
        #pragma unroll
        for (int rg = 0; rg < 4; ++rg) {
            int row = rowb + rg;
            int mm = m0 + row;
            float val = (ov[t][rg] - S->smean[row]) * S->sinv[row] * gm + bb;
            if (mm < NM_) {
                int b = mm / 513, r = mm - b * 513;
                if (r >= 1)
                    dout[1024 + (size_t)b * 65536 + (size_t)(r - 1) * 128 + n] = val;
            } else {
                int mc = mm - NM_;
                int b = mc / 129, r = mc - b * 129;
                if (r == 0) {
                    S->x2row[n] = val;
                    if (n == 0) S->poolb = b;
                }
            }
        }
    }
    __syncthreads();
    if (S->poolb >= 0 && tid < 128) {
        float acc = pb[tid];
        for (int k = 0; k < 128; ++k) acc = fmaf(S->x2row[k], pW[(size_t)k * 128 + tid], acc);
        dout[(size_t)S->poolb * 128 + tid] = tanhf(acc);
    }
}

__global__ void __launch_bounds__(256)
attnout_ffn_kernel(const unsigned short* A, const unsigned short* Wao, const float* bao,
                   const float* resid, const float* g1, const float* b1ln,
                   const unsigned short* W1, const float* fb1,
                   const unsigned short* W2, const float* fb2,
                   const float* g2, const float* b2ln,
                   const float* pW, const float* pb, float* dout) {
    __shared__ AoS S;
    attnout_body(A, Wao, bao, resid, g1, b1ln, W1, fb1, W2, fb2, g2, b2ln,
                 pW, pb, dout, blockIdx.x * 16, threadIdx.x, &S);
}

// ---------------------------------------------------------------------------
// Fused cooperative kernel: all six phases, grid.sync between phases.
struct FusedArgs {
    PrepAll pa;
    float* wbase;
    int prep_nblk;
    const unsigned short* gA[3]; const unsigned short* gW[3];
    const float* gBias[3]; unsigned short* gC[3]; float gbs[3];
    const unsigned short* qp_cls; const unsigned short* qp_main;
    const unsigned short* kp; const unsigned short* btg;
    float* att_cls; float* att_mn;
    const float* att; const float* Wo; const float* bo;
    const float* cls_emb; const float* pos; float* xin;
    const unsigned short* Wq; const unsigned short* Wk; const unsigned short* Wv;
    const float* bq; const float* bk; const float* bv;
    unsigned short* outq; unsigned short* outk; unsigned short* vT;
    unsigned short* tba;
    const unsigned short* Wao; const float* bao;
    const float* g1; const float* b1ln;
    const unsigned short* W1; const float* fb1;
    const unsigned short* W2; const float* fb2;
    const float* g2; const float* b2ln;
    const float* pW; const float* pb; float* dout;
};

__global__ void __launch_bounds__(256, 2)
fused_kernel(FusedArgs fa) {
    __shared__ SMem sm;
    cg::grid_group gg = cg::this_grid();
    int tid = threadIdx.x;

    {   // phase 1: prep
        int flag = (fa.pa.det[0] == 0x3F80u) ? 1 : 0;
        for (int blk = blockIdx.x; blk < fa.prep_nblk; blk += gridDim.x)
            prep_body(fa.pa, fa.wbase, blk, tid, flag);
    }
    gg.sync();
    // phase 2: mta projections (256 + 256 + 8 = 520 tiles)
    for (int vb = blockIdx.x; vb < 520; vb += gridDim.x) {
        int y = (vb < 256) ? 0 : ((vb < 512) ? 1 : 2);
        int bx = vb - ((y == 0) ? 0 : ((y == 1) ? 256 : 512));
        gemm_body(fa.gA[y], fa.gW[y], fa.gBias[y], fa.gC[y], fa.gbs[y], bx * 16, tid);
    }
    gg.sync();
    // phase 3: mta attention (40 x 2 x 8 = 640 virtual blocks)
    for (int vb = blockIdx.x; vb < 640; vb += gridDim.x) {
        int xx = vb % 40, h = (vb / 40) & 1, b = vb / 80;
        mta_att_body(fa.qp_cls, fa.qp_main, fa.kp, fa.btg, fa.att_cls, fa.att_mn,
                     xx >= 32, (xx >= 32) ? xx - 32 : xx, h, b, tid, &sm.ma);
    }
    gg.sync();
    // phase 4: mta-out + assemble + QKV (321 tiles)
    for (int vb = blockIdx.x; vb < 321; vb += gridDim.x)
        mta_qkv_body(fa.att, fa.Wo, fa.bo, fa.cls_emb, fa.pos, fa.xin,
                     fa.Wq, fa.Wk, fa.Wv, fa.bq, fa.bk, fa.bv,
                     fa.outq, fa.outk, fa.vT, vb * 16, tid, &sm.mq);
    gg.sync();
    // phase 5: tblock attention (42 x 2 x 8 = 672 virtual blocks)
    for (int vb = blockIdx.x; vb < 672; vb += gridDim.x) {
        int xx = vb % 42, h = (vb / 42) & 1, b = vb / 84;
        tb_att_body(fa.outq, fa.outk, fa.vT, fa.tba,
                    xx >= 33, (xx >= 33) ? xx - 33 : xx, h, b, tid, &sm.tb);
    }
    gg.sync();
    // phase 6: attnout + LN + FFN + LN + pool (321 tiles)
    for (int vb = blockIdx.x; vb < 321; vb += gridDim.x)
        attnout_body(fa.tba, fa.Wao, fa.bao, fa.xin, fa.g1, fa.b1ln,
                     fa.W1, fa.fb1, fa.W2, fa.fb2, fa.g2, fa.b2ln,
                     fa.pW, fa.pb, fa.dout, vb * 16, tid, &sm.ao);
}

// ---------------------------------------------------------------------------
extern "C" void kernel_launch(void* const* d_in, const int* in_sizes, int n_in,
                              void* d_out, int out_size, void* d_ws, size_t ws_size,
                              hipStream_t stream) {
    float* w = (float*)d_ws;
    size_t off = 0;
    auto alloc = [&](size_t n) {
        float* p = w + off;
        off += (n + 3) & ~(size_t)3;
        return p;
    };
    auto allocU = [&](size_t n) { return (unsigned short*)alloc((n + 1) / 2); };

    PrepAll pa{};
    int nn = n_in < 32 ? n_in : 32;
    float* fin[32];
    const int needconv[32] = {0,0,0,0,0,0, 0,1, 0,1, 1,1, 1,1, 0,1, 0,1, 0,1,
                              0,1, 1,1, 0,1, 0,1, 1,1, 1,1};
    int ncv = 0;
    for (int i = 0; i < nn; ++i) {
        pa.src[i] = d_in[i];
        pa.n[i] = in_sizes[i];
        fin[i] = alloc(in_sizes[i]);
        pa.dstoff[i] = (int)(fin[i] - w);
        if (needconv[i]) {
            int nb = (in_sizes[i] + 255) / 256;
            pa.cstart[i] = ncv;
            pa.cnum[i] = nb;
            ncv += nb;
        } else { pa.cstart[i] = -1; pa.cnum[i] = 0; }
    }
    for (int i = nn; i < 32; ++i) {
        pa.src[i] = nullptr; pa.n[i] = 0; pa.dstoff[i] = 0;
        pa.cstart[i] = -1; pa.cnum[i] = 0;
    }
    pa.ncv = ncv;

    const float* bq_t    = fin[7];
    const float* bk_t    = fin[9];
    const float* Wo_t    = fin[10]; const float* bo_t = fin[11];
    const float* pos_emb = fin[12]; const float* cls_emb = fin[13];
    const float* tbq = fin[15]; const float* tbk = fin[17]; const float* tbv = fin[19];
    const float* tbo = fin[21];
    const float* ln1_g = fin[22]; const float* ln1_b = fin[23];
    const float* fb1 = fin[25]; const float* fb2 = fin[27];
    const float* ln2_g = fin[28]; const float* ln2_b = fin[29];
    const float* pW = fin[30]; const float* pb = fin[31];

    const int widx[8] = {8, 6, 14, 16, 18, 20, 24, 26};
    unsigned short* wsw[8];
    for (int i = 0; i < 8; ++i) {
        wsw[i] = allocU(16384);
        pa.wsrc[i] = d_in[widx[i]];
        pa.wdst[i] = wsw[i];
        pa.wscale[i] = (i == 1 || i == 2) ? 0.125f : 1.0f;
    }
    pa.ts = d_in[1]; pa.w_per = d_in[2]; pa.b_per = d_in[3];
    pa.w_lin = d_in[4]; pa.b_lin = d_in[5];
    pa.xsrc = d_in[0];
    pa.det = (const unsigned short*)d_in[22];

    unsigned short* key_e16 = allocU(4224 * 128);
    unsigned short* cls_e16 = key_e16 + 4096 * 128;
    pa.key_e16 = key_e16;
    unsigned short* btg = allocU(8 * 16 * 512);
    pa.btg = btg;

    unsigned short* qp_main16 = allocU(4096 * 128);
    unsigned short* kp_main16 = allocU(4096 * 128);
    unsigned short* qp_cls16  = allocU(128 * 128);
    float* att_all = alloc(5120 * 32);
    float* att_cls = att_all;
    float* att_mn  = att_all + 1024 * 32;
    float* xin     = alloc((size_t)NT_ * 128);
    unsigned short* tbq16 = allocU((size_t)NT_ * 128);
    unsigned short* tbk16 = allocU((size_t)NT_ * 128);
    unsigned short* vT    = allocU((size_t)128 * VTS_);
    unsigned short* tba16 = allocU((size_t)NT_ * 128);
    pa.vt = vT;
    (void)ws_size;

    float* outf = (float*)d_out;
    int prep_nblk = ncv + 512 + 2112 + 32 + 7;

    FusedArgs fa{};
    fa.pa = pa; fa.wbase = w; fa.prep_nblk = prep_nblk;
    fa.gA[0] = key_e16; fa.gW[0] = wsw[0]; fa.gBias[0] = bk_t; fa.gC[0] = kp_main16; fa.gbs[0] = 1.f;
    fa.gA[1] = key_e16; fa.gW[1] = wsw[1]; fa.gBias[1] = bq_t; fa.gC[1] = qp_main16; fa.gbs[1] = 0.125f;
    fa.gA[2] = cls_e16; fa.gW[2] = wsw[1]; fa.gBias[2] = bq_t; fa.gC[2] = qp_cls16;  fa.gbs[2] = 0.125f;
    fa.qp_cls = qp_cls16; fa.qp_main = qp_main16; fa.kp = kp_main16; fa.btg = btg;
    fa.att_cls = att_cls; fa.att_mn = att_mn;
    fa.att = att_all; fa.Wo = Wo_t; fa.bo = bo_t; fa.cls_emb = cls_emb; fa.pos = pos_emb;
    fa.xin = xin;
    fa.Wq = wsw[2]; fa.Wk = wsw[3]; fa.Wv = wsw[4];
    fa.bq = tbq; fa.bk = tbk; fa.bv = tbv;
    fa.outq = tbq16; fa.outk = tbk16; fa.vT = vT; fa.tba = tba16;
    fa.Wao = wsw[5]; fa.bao = tbo; fa.g1 = ln1_g; fa.b1ln = ln1_b;
    fa.W1 = wsw[6]; fa.fb1 = fb1; fa.W2 = wsw[7]; fa.fb2 = fb2;
    fa.g2 = ln2_g; fa.b2ln = ln2_b; fa.pW = pW; fa.pb = pb; fa.dout = outf;

    bool launched = false;
    int dev = 0;
    (void)hipGetDevice(&dev);
    int coop = 0;
    (void)hipDeviceGetAttribute(&coop, hipDeviceAttributeCooperativeLaunch, dev);
    if (coop) {
        int occ = 0, ncu = 0;
        (void)hipOccupancyMaxActiveBlocksPerMultiprocessor(&occ, (const void*)fused_kernel, 256, 0);
        (void)hipDeviceGetAttribute(&ncu, hipDeviceAttributeMultiprocessorCount, dev);
        int G = occ * ncu;
        if (G > 672) G = 672;
        if (G >= 64) {
            void* params[1] = { (void*)&fa };
            if (hipLaunchCooperativeKernel((const void*)fused_kernel, dim3(G), dim3(256),
                                           params, 0, stream) == hipSuccess)
                launched = true;
        }
    }

    if (!launched) {
        // Fallback: six separate launches (R18-identical path).
        prep_all_kernel<<<prep_nblk, 256, 0, stream>>>(pa, w);
        {
            GemmM p{};
            p.A[0] = key_e16; p.W[0] = wsw[0]; p.bias[0] = bk_t; p.C[0] = kp_main16;
            p.M[0] = 4096; p.bscale[0] = 1.f;
            p.A[1] = key_e16; p.W[1] = wsw[1]; p.bias[1] = bq_t; p.C[1] = qp_main16;
            p.M[1] = 4096; p.bscale[1] = 0.125f;
            p.A[2] = cls_e16; p.W[2] = wsw[1]; p.bias[2] = bq_t; p.C[2] = qp_cls16;
            p.M[2] = 128; p.bscale[2] = 0.125f;
            gemm_mfma_kernel<<<dim3(256, 3), 256, 0, stream>>>(p);
        }
        mta_att_kernel<<<dim3(40, 2, 8), 256, 0, stream>>>(qp_cls16, qp_main16, kp_main16,
                                                           btg, att_cls, att_mn);
        mta_qkv_kernel<<<321, 256, 0, stream>>>(att_all, Wo_t, bo_t, cls_emb, pos_emb, xin,
                                                wsw[2], wsw[3], wsw[4], tbq, tbk, tbv,
                                                tbq16, tbk16, vT);
        tb_att_kernel<<<dim3(42, 2, 8), 256, 0, stream>>>(tbq16, tbk16, vT, tba16);
        attnout_ffn_kernel<<<321, 256, 0, stream>>>(tba16, wsw[5], tbo, xin, ln1_g, ln1_b,
                                                    wsw[6], fb1, wsw[7], fb2, ln2_g, ln2_b,
                                                    pW, pb, outf);
    }
}

// Round 3
// 207.306 us; speedup vs baseline: 2.0725x; 2.0725x over previous
//
#include <hip/hip_runtime.h>
#include <hip/hip_bf16.h>
#include <math.h>

// TimeBERT forward on MI355X. Inputs fp32 (runtime bf16 detector, inline).
// OUTPUT FP32: [cls_pooling (8,128) | last_hidden (8,512,128)].
//
// R20: 4-kernel pipeline. R19's cooperative mega-kernel regressed 2.4x
// (grid.sync ~60-90us each on 8 non-coherent XCDs). Instead, fuse where the
// dependency is ROW-LOCAL by computing BOTH heads per block:
//  - mta_fused = mta_att(2 heads) + mta-out matvec + QKV projections.
//    att stays in LDS (att_all buffer deleted). 321 blocks (256 main tiles +
//    64 cls tiles + 1 special block for the 16 per-segment CLS rows).
//  - tb_fused = tb_att(2 heads) + attnout + LN1 + FFN + LN2 + pool.
//    A tile stays in LDS (tba16 buffer deleted). (33+9)x8 = 336 blocks;
//    padded rows masked on write, resid reads clamped.

static constexpr int NM_ = 8 * 513;           // 4104 main rows
static constexpr int NC_ = 8 * 129;           // 1032 cls rows
static constexpr int NT_ = NM_ + NC_;         // 5136 total
static constexpr int VTS_ = 5248;             // vT row stride (16-mult, >= 5198)

using bf = __hip_bfloat16;
typedef __attribute__((ext_vector_type(8))) short bf16x8;
typedef __attribute__((ext_vector_type(4))) short bf16x4;
typedef __attribute__((ext_vector_type(4))) float floatx4;
typedef __attribute__((ext_vector_type(8))) unsigned short ushortx8;

__device__ __forceinline__ float wave_reduce_sum(float v) {
    #pragma unroll
    for (int off = 32; off >= 1; off >>= 1) v += __shfl_xor(v, off);
    return v;
}
__device__ __forceinline__ float wave_reduce_max(float v) {
    #pragma unroll
    for (int off = 32; off >= 1; off >>= 1) v = fmaxf(v, __shfl_xor(v, off));
    return v;
}
__device__ __forceinline__ float u2f(unsigned short u) {
    return __uint_as_float(((unsigned)u) << 16);
}
__device__ __forceinline__ unsigned short f2u(float f) {   // RNE, finite
    unsigned u = __float_as_uint(f);
    return (unsigned short)((u + 0x7FFF + ((u >> 16) & 1)) >> 16);
}
__device__ __forceinline__ bf16x8 join8(bf16x4 lo, bf16x4 hi) {
    return __builtin_shufflevector(lo, hi, 0, 1, 2, 3, 4, 5, 6, 7);
}
__device__ __forceinline__ float rdin(const void* p, int i, int flag) {
    return flag ? u2f(((const unsigned short*)p)[i]) : ((const float*)p)[i];
}

// ---------------------------------------------------------------------------
// prep: [0,ncv) dense conversion; [ncv,+512) weight swizzle; [+2112) time emb;
// [+32) Bt build; [+7) vT tail zero.
struct PrepAll {
    const void* src[32]; int n[32]; int dstoff[32];
    int cstart[32]; int cnum[32];
    int ncv;
    const void* wsrc[8]; unsigned short* wdst[8]; float wscale[8];
    const void* ts; const void* w_per; const void* b_per;
    const void* w_lin; const void* b_lin;
    unsigned short* key_e16;
    unsigned short* btg;            // [b][c(16)][k(512)] bf16: c<8 -> x*m, else m
    const void* xsrc;               // raw x input (B,512,16)
    unsigned short* vt;             // transposed V buffer (tail-zeroed here)
    const unsigned short* det;
};
__global__ void prep_all_kernel(PrepAll a, float* dst) {
    int flag = (a.det[0] == 0x3F80u) ? 1 : 0;
    int blk = blockIdx.x, tid = threadIdx.x;
    if (blk < a.ncv) {
        int which = -1, bi = 0;
        #pragma unroll
        for (int i = 0; i < 32; ++i)
            if (blk >= a.cstart[i] && blk < a.cstart[i] + a.cnum[i]) { which = i; bi = blk - a.cstart[i]; }
        if (which < 0) return;
        int i = bi * 256 + tid;
        if (i < a.n[which]) dst[a.dstoff[which] + i] = rdin(a.src[which], i, flag);
    } else if (blk < a.ncv + 512) {
        int p = blk - a.ncv;
        int m = p >> 6;
        int idx = (p & 63) * 256 + tid;
        int c = idx >> 9;
        int l = (idx >> 3) & 63;
        int j = idx & 7;
        int k = (c >> 3) * 32 + (l >> 4) * 8 + j;
        int n = (c & 7) * 16 + (l & 15);
        a.wdst[m][idx] = f2u(rdin(a.wsrc[m], k * 128 + n, flag) * a.wscale[m]);
    } else if (blk < a.ncv + 512 + 2112) {
        int p = blk - a.ncv - 512;
        int row = p * 2 + (tid >> 7), j = tid & 127;
        float t = (row < 4096) ? rdin(a.ts, row, flag)
                               : (float)(row - 4096) * (1.0f / 127.0f);
        float v;
        if (j == 0) v = t * rdin(a.w_lin, 0, flag) + rdin(a.b_lin, 0, flag);
        else        v = sinf(t * rdin(a.w_per, j - 1, flag) + rdin(a.b_per, j - 1, flag));
        a.key_e16[row * 128 + j] = f2u(v);
    } else if (blk < a.ncv + 512 + 2112 + 32) {
        int p = blk - a.ncv - 512 - 2112;
        int e0 = (p * 256 + tid) * 8;
        int b = e0 >> 13;
        int c = (e0 >> 9) & 15;
        int k0 = e0 & 511;
        unsigned short out[8];
        #pragma unroll
        for (int j = 0; j < 8; ++j) {
            int k = k0 + j;
            float m = rdin(a.xsrc, (b * 512 + k) * 16 + 8 + (c & 7), flag);
            float val = (c < 8) ? rdin(a.xsrc, (b * 512 + k) * 16 + c, flag) * m : m;
            out[j] = f2u(val);
        }
        *(ushortx8*)(a.btg + e0) = *(ushortx8*)out;
    } else {
        int p = blk - a.ncv - 512 - 2112 - 32;
        int idx = p * 256 + tid;            // 0..1791 = 128*14
        if (idx < 128 * 14) {
            int n = idx / 14, c8 = idx - n * 14;
            ushortx8 z = {0, 0, 0, 0, 0, 0, 0, 0};
            *(ushortx8*)(a.vt + (size_t)n * VTS_ + 5136 + c8 * 8) = z;
        }
    }
}

// ---------------------------------------------------------------------------
// MFMA GEMM (projections): C16 = bf16(A16@W + bias*bscale). A-frags direct
// from global (tiles 16-row aligned), no LDS, no barrier.
struct GemmM {
    const void* A[3]; const unsigned short* W[3]; const float* bias[3];
    unsigned short* C[3];
    int M[3]; float bscale[3];
};
__global__ void __launch_bounds__(256)
gemm_mfma_kernel(GemmM p) {
    int y = blockIdx.y;
    const unsigned short* Wsw = p.W[y];
    const float* bias = p.bias[y];
    unsigned short* C = p.C[y];
    int M = p.M[y];
    float bscale = p.bscale[y];
    int m0 = blockIdx.x * 16;
    if (m0 >= M) return;
    int tid = threadIdx.x;
    int wv = tid >> 6, lane = tid & 63;
    int am = lane & 15, aq = lane >> 4;
    const unsigned short* A = (const unsigned short*)p.A[y];
    const unsigned short* Arow = A + (size_t)(m0 + am) * 128;
    floatx4 acc0 = {0.f, 0.f, 0.f, 0.f}, acc1 = acc0;
    #pragma unroll
    for (int ks = 0; ks < 4; ++ks) {
        bf16x8 af = *(const bf16x8*)(Arow + ks * 32 + aq * 8);
        const unsigned short* base = Wsw + ((size_t)ks * 8 + 2 * wv) * 512 + lane * 8;
        bf16x8 b0 = *(const bf16x8*)(base);
        bf16x8 b1 = *(const bf16x8*)(base + 512);
        acc0 = __builtin_amdgcn_mfma_f32_16x16x32_bf16(af, b0, acc0, 0, 0, 0);
        acc1 = __builtin_amdgcn_mfma_f32_16x16x32_bf16(af, b1, acc1, 0, 0, 0);
    }
    int col = lane & 15, rowb = (lane >> 4) * 4;
    #pragma unroll
    for (int t = 0; t < 2; ++t) {
        floatx4 acc = t ? acc1 : acc0;
        int n = wv * 32 + t * 16 + col;
        float bv = bias[n] * bscale;
        #pragma unroll
        for (int rg = 0; rg < 4; ++rg)
            C[(size_t)(m0 + rowb + rg) * 128 + n] = f2u(acc[rg] + bv);
    }
}

// ---------------------------------------------------------------------------
// mta_fused: both-heads mta attention (att kept in LDS) + mta-out matvec +
// assemble + QKV projections. Grid: 321 blocks.
//   vb <  256: main, b=vb>>5, qt=vb&31  -> R rows b*513 + 1+16qt .. +16
//   vb <  320: cls,  b=(vb-256)>>3, qt=(vb-256)&7 -> NM_+b*129 + 1+16qt .. +16
//   vb == 320: special: the 16 per-segment CLS rows (srow<0).
struct MaU_att { unsigned short sp[16][520]; float red[1280]; };
struct MaU_qkv { unsigned short As[16][136]; };
union MaU { MaU_att att; MaU_qkv qkv; };

__global__ void __launch_bounds__(256)
mta_fused_kernel(const unsigned short* qp_cls, const unsigned short* qp_main,
                 const unsigned short* kp, const unsigned short* btg,
                 const float* Wo, const float* bo, const float* cls_emb, const float* pos,
                 float* xin,
                 const unsigned short* Wq, const unsigned short* Wk, const unsigned short* Wv,
                 const float* bq, const float* bk, const float* bv_,
                 unsigned short* outq, unsigned short* outk, unsigned short* vT) {
    __shared__ MaU U;
    __shared__ float As32[16][36];
    int vb = blockIdx.x, tid = threadIdx.x;
    int lane = tid & 63, wv = tid >> 6;
    int m = lane & 15, g = lane >> 4;
    bool special = (vb == 320);
    int is_cls = 0, qt = 0, b = 0;
    if (!special) {
        if (vb < 256) { b = vb >> 5; qt = vb & 31; }
        else { int t = vb - 256; b = t >> 3; qt = t & 7; is_cls = 1; }
    }
    int q0 = qt * 16;

    if (!special) {
        for (int h = 0; h < 2; ++h) {
            const unsigned short* qrow = is_cls
                ? (qp_cls + (size_t)(q0 + m) * 128 + h * 64)
                : (qp_main + (size_t)(b * 512 + q0 + m) * 128 + h * 64);
            bf16x8 qf0 = *(const bf16x8*)(qrow + g * 8);
            bf16x8 qf1 = *(const bf16x8*)(qrow + 32 + g * 8);

            const unsigned short* kbase = kp + ((size_t)b * 512) * 128 + h * 64;
            #pragma unroll
            for (int kt = 0; kt < 8; ++kt) {
                int colk = kt * 64 + wv * 16 + m;
                const unsigned short* kb = kbase + (size_t)colk * 128;
                bf16x8 b0 = *(const bf16x8*)(kb + g * 8);
                bf16x8 b1 = *(const bf16x8*)(kb + 32 + g * 8);
                floatx4 acc = {0.f, 0.f, 0.f, 0.f};
                acc = __builtin_amdgcn_mfma_f32_16x16x32_bf16(qf0, b0, acc, 0, 0, 0);
                acc = __builtin_amdgcn_mfma_f32_16x16x32_bf16(qf1, b1, acc, 0, 0, 0);
                #pragma unroll
                for (int rg = 0; rg < 4; ++rg) U.att.sp[g * 4 + rg][colk] = f2u(acc[rg]);
            }
            __syncthreads();

            for (int rr = wv; rr < 16; rr += 4) {
                float mx = -1e30f;
                for (int k = lane; k < 512; k += 64) mx = fmaxf(mx, u2f(U.att.sp[rr][k]));
                mx = wave_reduce_max(mx);
                for (int k = lane; k < 512; k += 64)
                    U.att.sp[rr][k] = f2u(expf(u2f(U.att.sp[rr][k]) - mx));
            }
            __syncthreads();

            floatx4 macc = {0.f, 0.f, 0.f, 0.f};
            {
                const unsigned short* bbase = btg + ((size_t)(b * 16 + m)) * 512 + g * 8;
                #pragma unroll
                for (int cc = 0; cc < 4; ++cc) {
                    int koff = (wv + cc * 4) * 32;
                    bf16x8 af = *(const bf16x8*)&U.att.sp[m][koff + g * 8];
                    bf16x8 bfv = *(const bf16x8*)(bbase + koff);
                    macc = __builtin_amdgcn_mfma_f32_16x16x32_bf16(af, bfv, macc, 0, 0, 0);
                }
            }
            float* redC = U.att.red;
            float* Cfull = U.att.red + 1024;
            #pragma unroll
            for (int rg = 0; rg < 4; ++rg) redC[tid * 4 + rg] = macc[rg];
            __syncthreads();
            {
                int l = tid >> 2, rg = tid & 3;
                float s = redC[l * 4 + rg] + redC[(64 + l) * 4 + rg]
                        + redC[(128 + l) * 4 + rg] + redC[(192 + l) * 4 + rg];
                int row = (l >> 4) * 4 + rg, c = l & 15;
                Cfull[row * 16 + c] = s;
            }
            __syncthreads();
            if (tid < 128) {
                int r = tid >> 3, c = tid & 7;
                float num = Cfull[r * 16 + c];
                float den = Cfull[r * 16 + 8 + c];
                As32[r][h * 16 + c] = num / den;
                As32[r][h * 16 + 8 + c] = 1.0f;
            }
            __syncthreads();            // before next head reuses sp/red
        }
    }

    // ---- mta-out matvec + assemble ----
    int r = tid >> 4, gi = tid & 15, c0 = gi * 8;
    // row mapping (tile-local rr -> global R)
    int segbase = is_cls ? (NM_ + b * 129) : (b * 513);
    auto Rof = [&](int rr) -> int {
        if (special) return (rr < 8) ? rr * 513 : NM_ + (rr - 8) * 129;
        return segbase + 1 + q0 + rr;
    };
    int R = Rof(r);
    int prow;
    if (special) prow = (r < 8) ? 0 : -1;
    else prow = is_cls ? -1 : (1 + q0 + r);

    float acc[8];
    if (special) {
        #pragma unroll
        for (int j = 0; j < 8; ++j) acc[j] = cls_emb[c0 + j];
    } else {
        #pragma unroll
        for (int j = 0; j < 8; ++j) acc[j] = bo[c0 + j];
        #pragma unroll 8
        for (int k = 0; k < 32; ++k) {
            float a = As32[r][k];
            const float4 w0 = *(const float4*)(Wo + (size_t)k * 128 + c0);
            const float4 w1 = *(const float4*)(Wo + (size_t)k * 128 + c0 + 4);
            acc[0] = fmaf(a, w0.x, acc[0]); acc[1] = fmaf(a, w0.y, acc[1]);
            acc[2] = fmaf(a, w0.z, acc[2]); acc[3] = fmaf(a, w0.w, acc[3]);
            acc[4] = fmaf(a, w1.x, acc[4]); acc[5] = fmaf(a, w1.y, acc[5]);
            acc[6] = fmaf(a, w1.z, acc[6]); acc[7] = fmaf(a, w1.w, acc[7]);
        }
    }
    if (prow >= 0) {
        const float* pr = pos + (size_t)prow * 128 + c0;
        float4 p0 = *(const float4*)(pr);
        float4 p1 = *(const float4*)(pr + 4);
        acc[0] += p0.x; acc[1] += p0.y; acc[2] += p0.z; acc[3] += p0.w;
        acc[4] += p1.x; acc[5] += p1.y; acc[6] += p1.z; acc[7] += p1.w;
    }
    *(float4*)(xin + (size_t)R * 128 + c0) = make_float4(acc[0], acc[1], acc[2], acc[3]);
    *(float4*)(xin + (size_t)R * 128 + c0 + 4) = make_float4(acc[4], acc[5], acc[6], acc[7]);
    *(ushort4*)&U.qkv.As[r][c0] = make_ushort4(f2u(acc[0]), f2u(acc[1]), f2u(acc[2]), f2u(acc[3]));
    *(ushort4*)&U.qkv.As[r][c0 + 4] = make_ushort4(f2u(acc[4]), f2u(acc[5]), f2u(acc[6]), f2u(acc[7]));
    __syncthreads();

    int am = lane & 15, aq = lane >> 4;
    int col = lane & 15, rowb = (lane >> 4) * 4;
    const unsigned short* Ws[3] = {Wq, Wk, Wv};
    const float* bs[3] = {bq, bk, bv_};
    float bsc[3] = {0.125f, 1.f, 1.f};
    unsigned short* Cs[2] = {outq, outk};
    #pragma unroll
    for (int y = 0; y < 3; ++y) {
        floatx4 acc0 = {0.f, 0.f, 0.f, 0.f}, acc1 = acc0;
        #pragma unroll
        for (int ks = 0; ks < 4; ++ks) {
            bf16x8 af = *(bf16x8*)&U.qkv.As[am][ks * 32 + aq * 8];
            const unsigned short* base = Ws[y] + ((size_t)ks * 8 + 2 * wv) * 512 + lane * 8;
            bf16x8 b0 = *(const bf16x8*)(base);
            bf16x8 b1 = *(const bf16x8*)(base + 512);
            acc0 = __builtin_amdgcn_mfma_f32_16x16x32_bf16(af, b0, acc0, 0, 0, 0);
            acc1 = __builtin_amdgcn_mfma_f32_16x16x32_bf16(af, b1, acc1, 0, 0, 0);
        }
        #pragma unroll
        for (int t = 0; t < 2; ++t) {
            floatx4 a2 = t ? acc1 : acc0;
            int n = wv * 32 + t * 16 + col;
            float bvv = bs[y][n] * bsc[y];
            #pragma unroll
            for (int rg = 0; rg < 4; ++rg) {
                unsigned short val = f2u(a2[rg] + bvv);
                int R2 = Rof(rowb + rg);
                if (y < 2) Cs[y][(size_t)R2 * 128 + n] = val;
                else       vT[(size_t)n * VTS_ + R2] = val;
            }
        }
    }
}

// ---------------------------------------------------------------------------
// tb_fused: both-heads tblock attention (A tile kept in LDS) + attnout + LN1
// + FFN + LN2 + pool. Grid (42, 8) = 336 blocks.
struct TbU_att { unsigned short sp[16][588]; };
struct TbU_ffn { float Xs[16][128]; unsigned short Hs[16][136]; };
union TbU { TbU_att att; TbU_ffn ffn; };

__global__ void __launch_bounds__(256)
tb_fused_kernel(const unsigned short* qp, const unsigned short* kp,
                const unsigned short* vT, const float* resid,
                const unsigned short* Wao, const float* bao,
                const float* g1, const float* b1ln,
                const unsigned short* W1, const float* fb1,
                const unsigned short* W2, const float* fb2,
                const float* g2, const float* b2ln,
                const float* pW, const float* pb, float* dout) {
    __shared__ TbU U;
    __shared__ unsigned short As[16][136];
    __shared__ float rinv[16];
    __shared__ float redS[4][4][4], redQ[4][4][4], smean[16], sinv[16], x2row[128];
    __shared__ int poolb;

    int xx = blockIdx.x, b = blockIdx.y, tid = threadIdx.x;
    int is_cls = (xx >= 33);
    int qt = is_cls ? xx - 33 : xx;
    int Lq = is_cls ? 129 : 513;
    int base = is_cls ? (NM_ + b * 129) : (b * 513);
    int nkt = is_cls ? 3 : 9;
    int lane = tid & 63, wv = tid >> 6;
    int q0 = qt * 16, m = lane & 15, g = lane >> 4;
    if (tid == 0) poolb = -1;

    for (int h = 0; h < 2; ++h) {
        int qr = q0 + m; if (qr >= Lq) qr = Lq - 1;   // padded rows: dup, discarded
        const unsigned short* qrow = qp + (size_t)(base + qr) * 128 + h * 64;
        bf16x8 qf0 = *(const bf16x8*)(qrow + g * 8);
        bf16x8 qf1 = *(const bf16x8*)(qrow + 32 + g * 8);

        for (int kt = 0; kt < nkt; ++kt) {
            int colk = kt * 64 + wv * 16 + m;
            int krow = (colk < Lq) ? colk : (Lq - 1);
            const unsigned short* kb = kp + (size_t)(base + krow) * 128 + h * 64;
            bf16x8 b0 = *(const bf16x8*)(kb + g * 8);
            bf16x8 b1 = *(const bf16x8*)(kb + 32 + g * 8);
            floatx4 acc = {0.f, 0.f, 0.f, 0.f};
            acc = __builtin_amdgcn_mfma_f32_16x16x32_bf16(qf0, b0, acc, 0, 0, 0);
            acc = __builtin_amdgcn_mfma_f32_16x16x32_bf16(qf1, b1, acc, 0, 0, 0);
            #pragma unroll
            for (int rg = 0; rg < 4; ++rg)
                U.att.sp[g * 4 + rg][colk] = f2u((colk < Lq) ? acc[rg] : -1e30f);
        }
        __syncthreads();

        int kend = nkt * 64;
        for (int rr = wv; rr < 16; rr += 4) {
            float mx = -1e30f;
            for (int k = lane; k < kend; k += 64) mx = fmaxf(mx, u2f(U.att.sp[rr][k]));
            mx = wave_reduce_max(mx);
            float sum = 0.f;
            for (int k = lane; k < kend; k += 64) {
                float e = expf(u2f(U.att.sp[rr][k]) - mx);
                U.att.sp[rr][k] = f2u(e);
                sum += e;
            }
            sum = wave_reduce_sum(sum);
            if (lane == 0) rinv[rr] = 1.f / sum;
        }
        __syncthreads();

        floatx4 oacc = {0.f, 0.f, 0.f, 0.f};
        const unsigned short* vbase = vT + (size_t)(h * 64 + wv * 16 + m) * VTS_ + base;
        for (int kt = 0; kt < nkt; ++kt) {
            int k0 = kt * 64;
            #pragma unroll
            for (int c = 0; c < 2; ++c) {
                bf16x4 plo = *(const bf16x4*)&U.att.sp[m][k0 + c * 32 + g * 8];
                bf16x4 phi = *(const bf16x4*)&U.att.sp[m][k0 + c * 32 + g * 8 + 4];
                bf16x8 vf = *(const bf16x8*)(vbase + k0 + c * 32 + g * 8);
                oacc = __builtin_amdgcn_mfma_f32_16x16x32_bf16(join8(plo, phi), vf, oacc, 0, 0, 0);
            }
        }
        int dcol = wv * 16 + m;
        #pragma unroll
        for (int rg = 0; rg < 4; ++rg) {
            int q = g * 4 + rg;
            As[q][h * 64 + dcol] = f2u(oacc[rg] * rinv[q]);
        }
        __syncthreads();          // before next head overwrites sp; before ffn aliases sp
    }

    // ---- attnout + LN1 + FFN + LN2 + pool on rows base+q0 .. base+q0+15 ----
    int am = lane & 15, aq = lane >> 4;
    int col = lane & 15, rowb = g * 4;

    float ov[2][4];
    {
        floatx4 acc0 = {0.f, 0.f, 0.f, 0.f}, acc1 = acc0;
        #pragma unroll
        for (int ks = 0; ks < 4; ++ks) {
            bf16x8 af = *(bf16x8*)&As[am][ks * 32 + aq * 8];
            const unsigned short* wb = Wao + ((size_t)ks * 8 + 2 * wv) * 512 + lane * 8;
            bf16x8 bb0 = *(const bf16x8*)(wb);
            bf16x8 bb1 = *(const bf16x8*)(wb + 512);
            acc0 = __builtin_amdgcn_mfma_f32_16x16x32_bf16(af, bb0, acc0, 0, 0, 0);
            acc1 = __builtin_amdgcn_mfma_f32_16x16x32_bf16(af, bb1, acc1, 0, 0, 0);
        }
        #pragma unroll
        for (int t = 0; t < 2; ++t) {
            int n = wv * 32 + t * 16 + col;
            float bv = bao[n];
            floatx4 acc = t ? acc1 : acc0;
            #pragma unroll
            for (int rg = 0; rg < 4; ++rg) {
                int qo = q0 + rowb + rg;
                int rc = (qo < Lq) ? qo : (Lq - 1);
                ov[t][rg] = acc[rg] + bv + resid[(size_t)(base + rc) * 128 + n];
            }
        }
    }
    #pragma unroll
    for (int rg = 0; rg < 4; ++rg) {
        float s = ov[0][rg] + ov[1][rg];
        float q = ov[0][rg] * ov[0][rg] + ov[1][rg] * ov[1][rg];
        #pragma unroll
        for (int off = 8; off >= 1; off >>= 1) {
            s += __shfl_xor(s, off);
            q += __shfl_xor(q, off);
        }
        if ((lane & 15) == 0) { redS[wv][g][rg] = s; redQ[wv][g][rg] = q; }
    }
    __syncthreads();
    if (tid < 16) {
        int gg = tid >> 2, rg = tid & 3;
        float s = redS[0][gg][rg] + redS[1][gg][rg] + redS[2][gg][rg] + redS[3][gg][rg];
        float q = redQ[0][gg][rg] + redQ[1][gg][rg] + redQ[2][gg][rg] + redQ[3][gg][rg];
        float mean = s * 0.0078125f;
        float var = q * 0.0078125f - mean * mean;
        smean[tid] = mean;
        sinv[tid] = rsqrtf(var + 1e-5f);
    }
    __syncthreads();
    #pragma unroll
    for (int t = 0; t < 2; ++t) {
        int n = wv * 32 + t * 16 + col;
        float gm = g1[n], bb = b1ln[n];
        #pragma unroll
        for (int rg = 0; rg < 4; ++rg) {
            int row = rowb + rg;
            float val = (ov[t][rg] - smean[row]) * sinv[row] * gm + bb;
            U.ffn.Xs[row][n] = val;
            As[row][n] = f2u(val);
        }
    }
    __syncthreads();

    {
        floatx4 acc0 = {0.f, 0.f, 0.f, 0.f}, acc1 = acc0;
        #pragma unroll
        for (int ks = 0; ks < 4; ++ks) {
            bf16x8 af = *(bf16x8*)&As[am][ks * 32 + aq * 8];
            const unsigned short* wb = W1 + ((size_t)ks * 8 + 2 * wv) * 512 + lane * 8;
            bf16x8 bb0 = *(const bf16x8*)(wb);
            bf16x8 bb1 = *(const bf16x8*)(wb + 512);
            acc0 = __builtin_amdgcn_mfma_f32_16x16x32_bf16(af, bb0, acc0, 0, 0, 0);
            acc1 = __builtin_amdgcn_mfma_f32_16x16x32_bf16(af, bb1, acc1, 0, 0, 0);
        }
        #pragma unroll
        for (int t = 0; t < 2; ++t) {
            int n = wv * 32 + t * 16 + col;
            float bv = fb1[n];
            floatx4 acc = t ? acc1 : acc0;
            #pragma unroll
            for (int rg = 0; rg < 4; ++rg)
                U.ffn.Hs[rowb + rg][n] = f2u(fmaxf(acc[rg] + bv, 0.f));
        }
    }
    __syncthreads();

    floatx4 acc0 = {0.f, 0.f, 0.f, 0.f}, acc1 = acc0;
    #pragma unroll
    for (int ks = 0; ks < 4; ++ks) {
        bf16x8 af = *(bf16x8*)&U.ffn.Hs[am][ks * 32 + aq * 8];
        const unsigned short* wb = W2 + ((size_t)ks * 8 + 2 * wv) * 512 + lane * 8;
        bf16x8 bb0 = *(const bf16x8*)(wb);
        bf16x8 bb1 = *(const bf16x8*)(wb + 512);
        acc0 = __builtin_amdgcn_mfma_f32_16x16x32_bf16(af, bb0, acc0, 0, 0, 0);
        acc1 = __builtin_amdgcn_mfma_f32_16x16x32_bf16(af, bb1, acc1, 0, 0, 0);
    }
    #pragma unroll
    for (int t = 0; t < 2; ++t) {
        int n = wv * 32 + t * 16 + col;
        float bv = fb2[n];
        floatx4 acc = t ? acc1 : acc0;
        #pragma unroll
        for (int rg = 0; rg < 4; ++rg)
            ov[t][rg] = acc[rg] + bv + U.ffn.Xs[rowb + rg][n];
    }
    #pragma unroll
    for (int rg = 0; rg < 4; ++rg) {
        float s = ov[0][rg] + ov[1][rg];
        float q = ov[0][rg] * ov[0][rg] + ov[1][rg] * ov[1][rg];
        #pragma unroll
        for (int off = 8; off >= 1; off >>= 1) {
            s += __shfl_xor(s, off);
            q += __shfl_xor(q, off);
        }
        if ((lane & 15) == 0) { redS[wv][g][rg] = s; redQ[wv][g][rg] = q; }
    }
    __syncthreads();
    if (tid < 16) {
        int gg = tid >> 2, rg = tid & 3;
        float s = redS[0][gg][rg] + redS[1][gg][rg] + redS[2][gg][rg] + redS[3][gg][rg];
        float q = redQ[0][gg][rg] + redQ[1][gg][rg] + redQ[2][gg][rg] + redQ[3][gg][rg];
        float mean = s * 0.0078125f;
        float var = q * 0.0078125f - mean * mean;
        smean[tid] = mean;
        sinv[tid] = rsqrtf(var + 1e-5f);
    }
    __syncthreads();
    #pragma unroll
    for (int t = 0; t < 2; ++t) {
        int n = wv * 32 + t * 16 + col;
        float gm = g2[n], bb = b2ln[n];
        #pragma unroll
        for (int rg = 0; rg < 4; ++rg) {
            int row = rowb + rg;
            int qout = q0 + row;
            float val = (ov[t][rg] - smean[row]) * sinv[row] * gm + bb;
            if (!is_cls) {
                if (qout >= 1 && qout < Lq)
                    dout[1024 + (size_t)b * 65536 + (size_t)(qout - 1) * 128 + n] = val;
            } else {
                if (qout == 0) {
                    x2row[n] = val;
                    if (n == 0) poolb = b;
                }
            }
        }
    }
    __syncthreads();
    if (poolb >= 0 && tid < 128) {
        float acc = pb[tid];
        for (int k = 0; k < 128; ++k) acc = fmaf(x2row[k], pW[(size_t)k * 128 + tid], acc);
        dout[(size_t)poolb * 128 + tid] = tanhf(acc);
    }
}

// ---------------------------------------------------------------------------
extern "C" void kernel_launch(void* const* d_in, const int* in_sizes, int n_in,
                              void* d_out, int out_size, void* d_ws, size_t ws_size,
                              hipStream_t stream) {
    float* w = (float*)d_ws;
    size_t off = 0;
    auto alloc = [&](size_t n) {
        float* p = w + off;
        off += (n + 3) & ~(size_t)3;
        return p;
    };
    auto allocU = [&](size_t n) { return (unsigned short*)alloc((n + 1) / 2); };

    PrepAll pa{};
    int nn = n_in < 32 ? n_in : 32;
    float* fin[32];
    const int needconv[32] = {0,0,0,0,0,0, 0,1, 0,1, 1,1, 1,1, 0,1, 0,1, 0,1,
                              0,1, 1,1, 0,1, 0,1, 1,1, 1,1};
    int ncv = 0;
    for (int i = 0; i < nn; ++i) {
        pa.src[i] = d_in[i];
        pa.n[i] = in_sizes[i];
        fin[i] = alloc(in_sizes[i]);
        pa.dstoff[i] = (int)(fin[i] - w);
        if (needconv[i]) {
            int nb = (in_sizes[i] + 255) / 256;
            pa.cstart[i] = ncv;
            pa.cnum[i] = nb;
            ncv += nb;
        } else { pa.cstart[i] = -1; pa.cnum[i] = 0; }
    }
    for (int i = nn; i < 32; ++i) {
        pa.src[i] = nullptr; pa.n[i] = 0; pa.dstoff[i] = 0;
        pa.cstart[i] = -1; pa.cnum[i] = 0;
    }
    pa.ncv = ncv;

    const float* bq_t    = fin[7];
    const float* bk_t    = fin[9];
    const float* Wo_t    = fin[10]; const float* bo_t = fin[11];
    const float* pos_emb = fin[12]; const float* cls_emb = fin[13];
    const float* tbq = fin[15]; const float* tbk = fin[17]; const float* tbv = fin[19];
    const float* tbo = fin[21];
    const float* ln1_g = fin[22]; const float* ln1_b = fin[23];
    const float* fb1 = fin[25]; const float* fb2 = fin[27];
    const float* ln2_g = fin[28]; const float* ln2_b = fin[29];
    const float* pW = fin[30]; const float* pb = fin[31];

    const int widx[8] = {8, 6, 14, 16, 18, 20, 24, 26};
    unsigned short* wsw[8];
    for (int i = 0; i < 8; ++i) {
        wsw[i] = allocU(16384);
        pa.wsrc[i] = d_in[widx[i]];
        pa.wdst[i] = wsw[i];
        pa.wscale[i] = (i == 1 || i == 2) ? 0.125f : 1.0f;
    }
    pa.ts = d_in[1]; pa.w_per = d_in[2]; pa.b_per = d_in[3];
    pa.w_lin = d_in[4]; pa.b_lin = d_in[5];
    pa.xsrc = d_in[0];
    pa.det = (const unsigned short*)d_in[22];

    unsigned short* key_e16 = allocU(4224 * 128);
    unsigned short* cls_e16 = key_e16 + 4096 * 128;
    pa.key_e16 = key_e16;
    unsigned short* btg = allocU(8 * 16 * 512);
    pa.btg = btg;

    unsigned short* qp_main16 = allocU(4096 * 128);
    unsigned short* kp_main16 = allocU(4096 * 128);
    unsigned short* qp_cls16  = allocU(128 * 128);
    float* xin     = alloc((size_t)NT_ * 128);
    unsigned short* tbq16 = allocU((size_t)NT_ * 128);
    unsigned short* tbk16 = allocU((size_t)NT_ * 128);
    unsigned short* vT    = allocU((size_t)128 * VTS_);
    pa.vt = vT;
    (void)ws_size;

    float* outf = (float*)d_out;
    int prep_nblk = ncv + 512 + 2112 + 32 + 7;

    // 1: convert + weight swizzle + time embedding + Bt build + vT tail zero
    prep_all_kernel<<<prep_nblk, 256, 0, stream>>>(pa, w);

    // 2: mta projections
    {
        GemmM p{};
        p.A[0] = key_e16; p.W[0] = wsw[0]; p.bias[0] = bk_t; p.C[0] = kp_main16;
        p.M[0] = 4096; p.bscale[0] = 1.f;
        p.A[1] = key_e16; p.W[1] = wsw[1]; p.bias[1] = bq_t; p.C[1] = qp_main16;
        p.M[1] = 4096; p.bscale[1] = 0.125f;
        p.A[2] = cls_e16; p.W[2] = wsw[1]; p.bias[2] = bq_t; p.C[2] = qp_cls16;
        p.M[2] = 128; p.bscale[2] = 0.125f;
        gemm_mfma_kernel<<<dim3(256, 3), 256, 0, stream>>>(p);
    }

    // 3: fused mta attention (both heads) + mta-out + assemble + QKV
    mta_fused_kernel<<<321, 256, 0, stream>>>(qp_cls16, qp_main16, kp_main16, btg,
                                              Wo_t, bo_t, cls_emb, pos_emb, xin,
                                              wsw[2], wsw[3], wsw[4], tbq, tbk, tbv,
                                              tbq16, tbk16, vT);

    // 4: fused tblock attention (both heads) + attnout + LN + FFN + LN + pool
    tb_fused_kernel<<<dim3(42, 8), 256, 0, stream>>>(tbq16, tbk16, vT, xin,
                                                     wsw[5], tbo, ln1_g, ln1_b,
                                                     wsw[6], fb1, wsw[7], fb2,
                                                     ln2_g, ln2_b, pW, pb, outf);
}

// Round 4
// 203.909 us; speedup vs baseline: 2.1070x; 1.0167x over previous
//
#include <hip/hip_runtime.h>
#include <hip/hip_bf16.h>
#include <math.h>

// TimeBERT forward on MI355X. Inputs fp32 (runtime bf16 detector, inline).
// OUTPUT FP32: [cls_pooling (8,128) | last_hidden (8,512,128)].
//
// R21: latency attack on the fused kernels (R20 counters: tb_fused 61us,
// MfmaUtil 1%, VALUBusy 10%, Occ 8% -> pure latency-bound).
//  - Both heads processed in ONE pass per phase (QK/softmax/PV): halves the
//    serial phase count, doubles ILP (2 independent MFMA/load chains).
//  - tb attention phase templated on NKT (9 main / 3 cls): compile-time trip
//    counts -> full unroll -> compiler hoists independent loads (R20's VGPR=40
//    showed zero pipelining).
//  - __launch_bounds__(256,2): grid <= 2 blocks/CU anyway; let VGPRs grow.
//  - LDS unions: tb ~43KB, mta ~46KB -> 3 blocks/CU by LDS.

static constexpr int NM_ = 8 * 513;           // 4104 main rows
static constexpr int NC_ = 8 * 129;           // 1032 cls rows
static constexpr int NT_ = NM_ + NC_;         // 5136 total
static constexpr int VTS_ = 5248;             // vT row stride (16-mult)

using bf = __hip_bfloat16;
typedef __attribute__((ext_vector_type(8))) short bf16x8;
typedef __attribute__((ext_vector_type(4))) short bf16x4;
typedef __attribute__((ext_vector_type(4))) float floatx4;
typedef __attribute__((ext_vector_type(8))) unsigned short ushortx8;

__device__ __forceinline__ float wave_reduce_sum(float v) {
    #pragma unroll
    for (int off = 32; off >= 1; off >>= 1) v += __shfl_xor(v, off);
    return v;
}
__device__ __forceinline__ float wave_reduce_max(float v) {
    #pragma unroll
    for (int off = 32; off >= 1; off >>= 1) v = fmaxf(v, __shfl_xor(v, off));
    return v;
}
__device__ __forceinline__ float u2f(unsigned short u) {
    return __uint_as_float(((unsigned)u) << 16);
}
__device__ __forceinline__ unsigned short f2u(float f) {   // RNE, finite
    unsigned u = __float_as_uint(f);
    return (unsigned short)((u + 0x7FFF + ((u >> 16) & 1)) >> 16);
}
__device__ __forceinline__ bf16x8 join8(bf16x4 lo, bf16x4 hi) {
    return __builtin_shufflevector(lo, hi, 0, 1, 2, 3, 4, 5, 6, 7);
}
__device__ __forceinline__ float rdin(const void* p, int i, int flag) {
    return flag ? u2f(((const unsigned short*)p)[i]) : ((const float*)p)[i];
}

// ---------------------------------------------------------------------------
// prep: [0,ncv) dense conversion; [ncv,+512) weight swizzle; [+2112) time emb;
// [+32) Bt build; [+7) vT tail zero.
struct PrepAll {
    const void* src[32]; int n[32]; int dstoff[32];
    int cstart[32]; int cnum[32];
    int ncv;
    const void* wsrc[8]; unsigned short* wdst[8]; float wscale[8];
    const void* ts; const void* w_per; const void* b_per;
    const void* w_lin; const void* b_lin;
    unsigned short* key_e16;
    unsigned short* btg;            // [b][c(16)][k(512)] bf16: c<8 -> x*m, else m
    const void* xsrc;               // raw x input (B,512,16)
    unsigned short* vt;             // transposed V buffer (tail-zeroed here)
    const unsigned short* det;
};
__global__ void prep_all_kernel(PrepAll a, float* dst) {
    int flag = (a.det[0] == 0x3F80u) ? 1 : 0;
    int blk = blockIdx.x, tid = threadIdx.x;
    if (blk < a.ncv) {
        int which = -1, bi = 0;
        #pragma unroll
        for (int i = 0; i < 32; ++i)
            if (blk >= a.cstart[i] && blk < a.cstart[i] + a.cnum[i]) { which = i; bi = blk - a.cstart[i]; }
        if (which < 0) return;
        int i = bi * 256 + tid;
        if (i < a.n[which]) dst[a.dstoff[which] + i] = rdin(a.src[which], i, flag);
    } else if (blk < a.ncv + 512) {
        int p = blk - a.ncv;
        int m = p >> 6;
        int idx = (p & 63) * 256 + tid;
        int c = idx >> 9;
        int l = (idx >> 3) & 63;
        int j = idx & 7;
        int k = (c >> 3) * 32 + (l >> 4) * 8 + j;
        int n = (c & 7) * 16 + (l & 15);
        a.wdst[m][idx] = f2u(rdin(a.wsrc[m], k * 128 + n, flag) * a.wscale[m]);
    } else if (blk < a.ncv + 512 + 2112) {
        int p = blk - a.ncv - 512;
        int row = p * 2 + (tid >> 7), j = tid & 127;
        float t = (row < 4096) ? rdin(a.ts, row, flag)
                               : (float)(row - 4096) * (1.0f / 127.0f);
        float v;
        if (j == 0) v = t * rdin(a.w_lin, 0, flag) + rdin(a.b_lin, 0, flag);
        else        v = sinf(t * rdin(a.w_per, j - 1, flag) + rdin(a.b_per, j - 1, flag));
        a.key_e16[row * 128 + j] = f2u(v);
    } else if (blk < a.ncv + 512 + 2112 + 32) {
        int p = blk - a.ncv - 512 - 2112;
        int e0 = (p * 256 + tid) * 8;
        int b = e0 >> 13;
        int c = (e0 >> 9) & 15;
        int k0 = e0 & 511;
        unsigned short out[8];
        #pragma unroll
        for (int j = 0; j < 8; ++j) {
            int k = k0 + j;
            float m = rdin(a.xsrc, (b * 512 + k) * 16 + 8 + (c & 7), flag);
            float val = (c < 8) ? rdin(a.xsrc, (b * 512 + k) * 16 + c, flag) * m : m;
            out[j] = f2u(val);
        }
        *(ushortx8*)(a.btg + e0) = *(ushortx8*)out;
    } else {
        int p = blk - a.ncv - 512 - 2112 - 32;
        int idx = p * 256 + tid;            // 0..1791 = 128*14
        if (idx < 128 * 14) {
            int n = idx / 14, c8 = idx - n * 14;
            ushortx8 z = {0, 0, 0, 0, 0, 0, 0, 0};
            *(ushortx8*)(a.vt + (size_t)n * VTS_ + 5136 + c8 * 8) = z;
        }
    }
}

// ---------------------------------------------------------------------------
// MFMA GEMM (projections): C16 = bf16(A16@W + bias*bscale).
struct GemmM {
    const void* A[3]; const unsigned short* W[3]; const float* bias[3];
    unsigned short* C[3];
    int M[3]; float bscale[3];
};
__global__ void __launch_bounds__(256)
gemm_mfma_kernel(GemmM p) {
    int y = blockIdx.y;
    const unsigned short* Wsw = p.W[y];
    const float* bias = p.bias[y];
    unsigned short* C = p.C[y];
    int M = p.M[y];
    float bscale = p.bscale[y];
    int m0 = blockIdx.x * 16;
    if (m0 >= M) return;
    int tid = threadIdx.x;
    int wv = tid >> 6, lane = tid & 63;
    int am = lane & 15, aq = lane >> 4;
    const unsigned short* A = (const unsigned short*)p.A[y];
    const unsigned short* Arow = A + (size_t)(m0 + am) * 128;
    floatx4 acc0 = {0.f, 0.f, 0.f, 0.f}, acc1 = acc0;
    #pragma unroll
    for (int ks = 0; ks < 4; ++ks) {
        bf16x8 af = *(const bf16x8*)(Arow + ks * 32 + aq * 8);
        const unsigned short* base = Wsw + ((size_t)ks * 8 + 2 * wv) * 512 + lane * 8;
        bf16x8 b0 = *(const bf16x8*)(base);
        bf16x8 b1 = *(const bf16x8*)(base + 512);
        acc0 = __builtin_amdgcn_mfma_f32_16x16x32_bf16(af, b0, acc0, 0, 0, 0);
        acc1 = __builtin_amdgcn_mfma_f32_16x16x32_bf16(af, b1, acc1, 0, 0, 0);
    }
    int col = lane & 15, rowb = (lane >> 4) * 4;
    #pragma unroll
    for (int t = 0; t < 2; ++t) {
        floatx4 acc = t ? acc1 : acc0;
        int n = wv * 32 + t * 16 + col;
        float bv = bias[n] * bscale;
        #pragma unroll
        for (int rg = 0; rg < 4; ++rg)
            C[(size_t)(m0 + rowb + rg) * 128 + n] = f2u(acc[rg] + bv);
    }
}

// ---------------------------------------------------------------------------
// mta_fused: both-heads mta attention in ONE pass + mta-out matvec +
// assemble + QKV projections. Grid: 321 blocks.
struct MaAtt { unsigned short sp[2][16][520]; float red[2][1280]; };
union MaU { MaAtt att; unsigned short qAs[16][136]; };

__global__ void __launch_bounds__(256, 2)
mta_fused_kernel(const unsigned short* qp_cls, const unsigned short* qp_main,
                 const unsigned short* kp, const unsigned short* btg,
                 const float* Wo, const float* bo, const float* cls_emb, const float* pos,
                 float* xin,
                 const unsigned short* Wq, const unsigned short* Wk, const unsigned short* Wv,
                 const float* bq, const float* bk, const float* bv_,
                 unsigned short* outq, unsigned short* outk, unsigned short* vT) {
    __shared__ MaU U;
    __shared__ float As32[16][36];
    int vb = blockIdx.x, tid = threadIdx.x;
    int lane = tid & 63, wv = tid >> 6;
    int m = lane & 15, g = lane >> 4;
    bool special = (vb == 320);
    int is_cls = 0, qt = 0, b = 0;
    if (!special) {
        if (vb < 256) { b = vb >> 5; qt = vb & 31; }
        else { int t = vb - 256; b = t >> 3; qt = t & 7; is_cls = 1; }
    }
    int q0 = qt * 16;

    if (!special) {
        // ---- QK^T, both heads, one pass ----
        const unsigned short* qrow = is_cls
            ? (qp_cls + (size_t)(q0 + m) * 128)
            : (qp_main + (size_t)(b * 512 + q0 + m) * 128);
        bf16x8 qf[2][2];
        #pragma unroll
        for (int h = 0; h < 2; ++h) {
            qf[h][0] = *(const bf16x8*)(qrow + h * 64 + g * 8);
            qf[h][1] = *(const bf16x8*)(qrow + h * 64 + 32 + g * 8);
        }
        const unsigned short* kbase = kp + ((size_t)b * 512) * 128;
        #pragma unroll
        for (int kt = 0; kt < 8; ++kt) {
            int colk = kt * 64 + wv * 16 + m;
            const unsigned short* kb = kbase + (size_t)colk * 128;
            #pragma unroll
            for (int h = 0; h < 2; ++h) {
                bf16x8 b0 = *(const bf16x8*)(kb + h * 64 + g * 8);
                bf16x8 b1 = *(const bf16x8*)(kb + h * 64 + 32 + g * 8);
                floatx4 acc = {0.f, 0.f, 0.f, 0.f};
                acc = __builtin_amdgcn_mfma_f32_16x16x32_bf16(qf[h][0], b0, acc, 0, 0, 0);
                acc = __builtin_amdgcn_mfma_f32_16x16x32_bf16(qf[h][1], b1, acc, 0, 0, 0);
                #pragma unroll
                for (int rg = 0; rg < 4; ++rg)
                    U.att.sp[h][g * 4 + rg][colk] = f2u(acc[rg]);
            }
        }
        __syncthreads();

        // ---- exp(x - rowmax), 32 rows / 4 waves ----
        for (int rr2 = wv; rr2 < 32; rr2 += 4) {
            int h = rr2 >> 4, rr = rr2 & 15;
            float mx = -1e30f;
            #pragma unroll
            for (int k = 0; k < 8; ++k) mx = fmaxf(mx, u2f(U.att.sp[h][rr][k * 64 + lane]));
            mx = wave_reduce_max(mx);
            #pragma unroll
            for (int k = 0; k < 8; ++k)
                U.att.sp[h][rr][k * 64 + lane] = f2u(expf(u2f(U.att.sp[h][rr][k * 64 + lane]) - mx));
        }
        __syncthreads();

        // ---- P@Bt, both heads (shared Bt loads) ----
        floatx4 macc[2] = {{0.f,0.f,0.f,0.f},{0.f,0.f,0.f,0.f}};
        {
            const unsigned short* bbase = btg + ((size_t)(b * 16 + m)) * 512 + g * 8;
            #pragma unroll
            for (int cc = 0; cc < 4; ++cc) {
                int koff = (wv + cc * 4) * 32;
                bf16x8 bfv = *(const bf16x8*)(bbase + koff);
                #pragma unroll
                for (int h = 0; h < 2; ++h) {
                    bf16x8 af = *(const bf16x8*)&U.att.sp[h][m][koff + g * 8];
                    macc[h] = __builtin_amdgcn_mfma_f32_16x16x32_bf16(af, bfv, macc[h], 0, 0, 0);
                }
            }
        }
        #pragma unroll
        for (int h = 0; h < 2; ++h)
            #pragma unroll
            for (int rg = 0; rg < 4; ++rg)
                U.att.red[h][tid * 4 + rg] = macc[h][rg];
        __syncthreads();
        {
            int l = tid >> 2, rg = tid & 3;
            int row = (l >> 4) * 4 + rg, c = l & 15;
            #pragma unroll
            for (int h = 0; h < 2; ++h) {
                const float* rc = U.att.red[h];
                float s = rc[l * 4 + rg] + rc[(64 + l) * 4 + rg]
                        + rc[(128 + l) * 4 + rg] + rc[(192 + l) * 4 + rg];
                U.att.red[h][1024 + row * 16 + c] = s;
            }
        }
        __syncthreads();
        if (tid < 128) {
            int r = tid >> 3, c = tid & 7;
            #pragma unroll
            for (int h = 0; h < 2; ++h) {
                float num = U.att.red[h][1024 + r * 16 + c];
                float den = U.att.red[h][1024 + r * 16 + 8 + c];
                As32[r][h * 16 + c] = num / den;
                As32[r][h * 16 + 8 + c] = 1.0f;
            }
        }
        __syncthreads();
    }

    // ---- mta-out matvec + assemble ----
    int r = tid >> 4, gi = tid & 15, c0 = gi * 8;
    int segbase = is_cls ? (NM_ + b * 129) : (b * 513);
    auto Rof = [&](int rr) -> int {
        if (special) return (rr < 8) ? rr * 513 : NM_ + (rr - 8) * 129;
        return segbase + 1 + q0 + rr;
    };
    int R = Rof(r);
    int prow;
    if (special) prow = (r < 8) ? 0 : -1;
    else prow = is_cls ? -1 : (1 + q0 + r);

    float acc[8];
    if (special) {
        #pragma unroll
        for (int j = 0; j < 8; ++j) acc[j] = cls_emb[c0 + j];
    } else {
        #pragma unroll
        for (int j = 0; j < 8; ++j) acc[j] = bo[c0 + j];
        #pragma unroll 8
        for (int k = 0; k < 32; ++k) {
            float a = As32[r][k];
            const float4 w0 = *(const float4*)(Wo + (size_t)k * 128 + c0);
            const float4 w1 = *(const float4*)(Wo + (size_t)k * 128 + c0 + 4);
            acc[0] = fmaf(a, w0.x, acc[0]); acc[1] = fmaf(a, w0.y, acc[1]);
            acc[2] = fmaf(a, w0.z, acc[2]); acc[3] = fmaf(a, w0.w, acc[3]);
            acc[4] = fmaf(a, w1.x, acc[4]); acc[5] = fmaf(a, w1.y, acc[5]);
            acc[6] = fmaf(a, w1.z, acc[6]); acc[7] = fmaf(a, w1.w, acc[7]);
        }
    }
    if (prow >= 0) {
        const float* pr = pos + (size_t)prow * 128 + c0;
        float4 p0 = *(const float4*)(pr);
        float4 p1 = *(const float4*)(pr + 4);
        acc[0] += p0.x; acc[1] += p0.y; acc[2] += p0.z; acc[3] += p0.w;
        acc[4] += p1.x; acc[5] += p1.y; acc[6] += p1.z; acc[7] += p1.w;
    }
    __syncthreads();            // att-phase LDS (aliased by qAs) fully consumed
    *(float4*)(xin + (size_t)R * 128 + c0) = make_float4(acc[0], acc[1], acc[2], acc[3]);
    *(float4*)(xin + (size_t)R * 128 + c0 + 4) = make_float4(acc[4], acc[5], acc[6], acc[7]);
    *(ushort4*)&U.qAs[r][c0] = make_ushort4(f2u(acc[0]), f2u(acc[1]), f2u(acc[2]), f2u(acc[3]));
    *(ushort4*)&U.qAs[r][c0 + 4] = make_ushort4(f2u(acc[4]), f2u(acc[5]), f2u(acc[6]), f2u(acc[7]));
    __syncthreads();

    int am = lane & 15, aq = lane >> 4;
    int col = lane & 15, rowb = (lane >> 4) * 4;
    const unsigned short* Ws[3] = {Wq, Wk, Wv};
    const float* bs[3] = {bq, bk, bv_};
    float bsc[3] = {0.125f, 1.f, 1.f};
    unsigned short* Cs[2] = {outq, outk};
    #pragma unroll
    for (int y = 0; y < 3; ++y) {
        floatx4 acc0 = {0.f, 0.f, 0.f, 0.f}, acc1 = acc0;
        #pragma unroll
        for (int ks = 0; ks < 4; ++ks) {
            bf16x8 af = *(bf16x8*)&U.qAs[am][ks * 32 + aq * 8];
            const unsigned short* base = Ws[y] + ((size_t)ks * 8 + 2 * wv) * 512 + lane * 8;
            bf16x8 b0 = *(const bf16x8*)(base);
            bf16x8 b1 = *(const bf16x8*)(base + 512);
            acc0 = __builtin_amdgcn_mfma_f32_16x16x32_bf16(af, b0, acc0, 0, 0, 0);
            acc1 = __builtin_amdgcn_mfma_f32_16x16x32_bf16(af, b1, acc1, 0, 0, 0);
        }
        #pragma unroll
        for (int t = 0; t < 2; ++t) {
            floatx4 a2 = t ? acc1 : acc0;
            int n = wv * 32 + t * 16 + col;
            float bvv = bs[y][n] * bsc[y];
            #pragma unroll
            for (int rg = 0; rg < 4; ++rg) {
                unsigned short val = f2u(a2[rg] + bvv);
                int R2 = Rof(rowb + rg);
                if (y < 2) Cs[y][(size_t)R2 * 128 + n] = val;
                else       vT[(size_t)n * VTS_ + R2] = val;
            }
        }
    }
}

// ---------------------------------------------------------------------------
// tb_fused: both-heads tblock attention (one pass, NKT compile-time) +
// attnout + LN1 + FFN + LN2 + pool. Grid (42, 8) = 336 blocks.
union TbU {
    unsigned short sp[2][16][588];
    struct { float Xs[16][128]; unsigned short Hs[16][136]; } ffn;
};

template<int NKT>
__device__ __forceinline__ void tb_attn_phase(
    const unsigned short* qp, const unsigned short* kp, const unsigned short* vT,
    int Lq, int base, int q0, int tid,
    unsigned short (&sp)[2][16][588], float (&rinv)[2][16],
    unsigned short (&As)[16][136])
{
    int lane = tid & 63, wv = tid >> 6;
    int m = lane & 15, g = lane >> 4;

    int qr = q0 + m; if (qr >= Lq) qr = Lq - 1;     // padded rows: dup, discarded
    const unsigned short* qrow = qp + (size_t)(base + qr) * 128;
    bf16x8 qf[2][2];
    #pragma unroll
    for (int h = 0; h < 2; ++h) {
        qf[h][0] = *(const bf16x8*)(qrow + h * 64 + g * 8);
        qf[h][1] = *(const bf16x8*)(qrow + h * 64 + 32 + g * 8);
    }

    #pragma unroll
    for (int kt = 0; kt < NKT; ++kt) {
        int colk = kt * 64 + wv * 16 + m;
        int krow = (colk < Lq) ? colk : (Lq - 1);
        const unsigned short* kb = kp + (size_t)(base + krow) * 128;
        #pragma unroll
        for (int h = 0; h < 2; ++h) {
            bf16x8 b0 = *(const bf16x8*)(kb + h * 64 + g * 8);
            bf16x8 b1 = *(const bf16x8*)(kb + h * 64 + 32 + g * 8);
            floatx4 acc = {0.f, 0.f, 0.f, 0.f};
            acc = __builtin_amdgcn_mfma_f32_16x16x32_bf16(qf[h][0], b0, acc, 0, 0, 0);
            acc = __builtin_amdgcn_mfma_f32_16x16x32_bf16(qf[h][1], b1, acc, 0, 0, 0);
            #pragma unroll
            for (int rg = 0; rg < 4; ++rg)
                sp[h][g * 4 + rg][colk] = f2u((colk < Lq) ? acc[rg] : -1e30f);
        }
    }
    __syncthreads();

    // softmax: 32 rows / 4 waves
    for (int rr2 = wv; rr2 < 32; rr2 += 4) {
        int h = rr2 >> 4, rr = rr2 & 15;
        float mx = -1e30f;
        #pragma unroll
        for (int k = 0; k < NKT; ++k) mx = fmaxf(mx, u2f(sp[h][rr][k * 64 + lane]));
        mx = wave_reduce_max(mx);
        float sum = 0.f;
        #pragma unroll
        for (int k = 0; k < NKT; ++k) {
            float e = expf(u2f(sp[h][rr][k * 64 + lane]) - mx);
            sp[h][rr][k * 64 + lane] = f2u(e);
            sum += e;
        }
        sum = wave_reduce_sum(sum);
        if (lane == 0) rinv[h][rr] = 1.f / sum;
    }
    __syncthreads();

    // PV, both heads, interleaved acc chains
    floatx4 oacc[2] = {{0.f,0.f,0.f,0.f},{0.f,0.f,0.f,0.f}};
    #pragma unroll
    for (int kt = 0; kt < NKT; ++kt) {
        int k0 = kt * 64;
        #pragma unroll
        for (int h = 0; h < 2; ++h) {
            const unsigned short* vbase = vT + (size_t)(h * 64 + wv * 16 + m) * VTS_ + base;
            #pragma unroll
            for (int c = 0; c < 2; ++c) {
                bf16x4 plo = *(const bf16x4*)&sp[h][m][k0 + c * 32 + g * 8];
                bf16x4 phi = *(const bf16x4*)&sp[h][m][k0 + c * 32 + g * 8 + 4];
                bf16x8 vf = *(const bf16x8*)(vbase + k0 + c * 32 + g * 8);
                oacc[h] = __builtin_amdgcn_mfma_f32_16x16x32_bf16(join8(plo, phi), vf, oacc[h], 0, 0, 0);
            }
        }
    }
    int dcol = wv * 16 + m;
    #pragma unroll
    for (int h = 0; h < 2; ++h)
        #pragma unroll
        for (int rg = 0; rg < 4; ++rg) {
            int q = g * 4 + rg;
            As[q][h * 64 + dcol] = f2u(oacc[h][rg] * rinv[h][q]);
        }
    __syncthreads();
}

__global__ void __launch_bounds__(256, 2)
tb_fused_kernel(const unsigned short* qp, const unsigned short* kp,
                const unsigned short* vT, const float* resid,
                const unsigned short* Wao, const float* bao,
                const float* g1, const float* b1ln,
                const unsigned short* W1, const float* fb1,
                const unsigned short* W2, const float* fb2,
                const float* g2, const float* b2ln,
                const float* pW, const float* pb, float* dout) {
    __shared__ TbU U;
    __shared__ unsigned short As[16][136];
    __shared__ float rinv[2][16];
    __shared__ float redS[4][4][4], redQ[4][4][4], smean[16], sinv[16], x2row[128];
    __shared__ int poolb;

    int xx = blockIdx.x, b = blockIdx.y, tid = threadIdx.x;
    int is_cls = (xx >= 33);
    int qt = is_cls ? xx - 33 : xx;
    int Lq = is_cls ? 129 : 513;
    int base = is_cls ? (NM_ + b * 129) : (b * 513);
    int lane = tid & 63, wv = tid >> 6;
    int q0 = qt * 16, g = lane >> 4;
    if (tid == 0) poolb = -1;

    if (is_cls) tb_attn_phase<3>(qp, kp, vT, Lq, base, q0, tid, U.sp, rinv, As);
    else        tb_attn_phase<9>(qp, kp, vT, Lq, base, q0, tid, U.sp, rinv, As);

    // ---- attnout + LN1 + FFN + LN2 + pool on rows base+q0 .. base+q0+15 ----
    int am = lane & 15, aq = lane >> 4;
    int col = lane & 15, rowb = g * 4;

    float ov[2][4];
    {
        floatx4 acc0 = {0.f, 0.f, 0.f, 0.f}, acc1 = acc0;
        #pragma unroll
        for (int ks = 0; ks < 4; ++ks) {
            bf16x8 af = *(bf16x8*)&As[am][ks * 32 + aq * 8];
            const unsigned short* wb = Wao + ((size_t)ks * 8 + 2 * wv) * 512 + lane * 8;
            bf16x8 bb0 = *(const bf16x8*)(wb);
            bf16x8 bb1 = *(const bf16x8*)(wb + 512);
            acc0 = __builtin_amdgcn_mfma_f32_16x16x32_bf16(af, bb0, acc0, 0, 0, 0);
            acc1 = __builtin_amdgcn_mfma_f32_16x16x32_bf16(af, bb1, acc1, 0, 0, 0);
        }
        #pragma unroll
        for (int t = 0; t < 2; ++t) {
            int n = wv * 32 + t * 16 + col;
            float bv = bao[n];
            floatx4 acc = t ? acc1 : acc0;
            #pragma unroll
            for (int rg = 0; rg < 4; ++rg) {
                int qo = q0 + rowb + rg;
                int rc = (qo < Lq) ? qo : (Lq - 1);
                ov[t][rg] = acc[rg] + bv + resid[(size_t)(base + rc) * 128 + n];
            }
        }
    }
    #pragma unroll
    for (int rg = 0; rg < 4; ++rg) {
        float s = ov[0][rg] + ov[1][rg];
        float q = ov[0][rg] * ov[0][rg] + ov[1][rg] * ov[1][rg];
        #pragma unroll
        for (int off = 8; off >= 1; off >>= 1) {
            s += __shfl_xor(s, off);
            q += __shfl_xor(q, off);
        }
        if ((lane & 15) == 0) { redS[wv][g][rg] = s; redQ[wv][g][rg] = q; }
    }
    __syncthreads();
    if (tid < 16) {
        int gg = tid >> 2, rg = tid & 3;
        float s = redS[0][gg][rg] + redS[1][gg][rg] + redS[2][gg][rg] + redS[3][gg][rg];
        float q = redQ[0][gg][rg] + redQ[1][gg][rg] + redQ[2][gg][rg] + redQ[3][gg][rg];
        float mean = s * 0.0078125f;
        float var = q * 0.0078125f - mean * mean;
        smean[tid] = mean;
        sinv[tid] = rsqrtf(var + 1e-5f);
    }
    __syncthreads();
    #pragma unroll
    for (int t = 0; t < 2; ++t) {
        int n = wv * 32 + t * 16 + col;
        float gm = g1[n], bb = b1ln[n];
        #pragma unroll
        for (int rg = 0; rg < 4; ++rg) {
            int row = rowb + rg;
            float val = (ov[t][rg] - smean[row]) * sinv[row] * gm + bb;
            U.ffn.Xs[row][n] = val;
            As[row][n] = f2u(val);
        }
    }
    __syncthreads();

    {
        floatx4 acc0 = {0.f, 0.f, 0.f, 0.f}, acc1 = acc0;
        #pragma unroll
        for (int ks = 0; ks < 4; ++ks) {
            bf16x8 af = *(bf16x8*)&As[am][ks * 32 + aq * 8];
            const unsigned short* wb = W1 + ((size_t)ks * 8 + 2 * wv) * 512 + lane * 8;
            bf16x8 bb0 = *(const bf16x8*)(wb);
            bf16x8 bb1 = *(const bf16x8*)(wb + 512);
            acc0 = __builtin_amdgcn_mfma_f32_16x16x32_bf16(af, bb0, acc0, 0, 0, 0);
            acc1 = __builtin_amdgcn_mfma_f32_16x16x32_bf16(af, bb1, acc1, 0, 0, 0);
        }
        #pragma unroll
        for (int t = 0; t < 2; ++t) {
            int n = wv * 32 + t * 16 + col;
            float bv = fb1[n];
            floatx4 acc = t ? acc1 : acc0;
            #pragma unroll
            for (int rg = 0; rg < 4; ++rg)
                U.ffn.Hs[rowb + rg][n] = f2u(fmaxf(acc[rg] + bv, 0.f));
        }
    }
    __syncthreads();

    floatx4 acc0 = {0.f, 0.f, 0.f, 0.f}, acc1 = acc0;
    #pragma unroll
    for (int ks = 0; ks < 4; ++ks) {
        bf16x8 af = *(bf16x8*)&U.ffn.Hs[am][ks * 32 + aq * 8];
        const unsigned short* wb = W2 + ((size_t)ks * 8 + 2 * wv) * 512 + lane * 8;
        bf16x8 bb0 = *(const bf16x8*)(wb);
        bf16x8 bb1 = *(const bf16x8*)(wb + 512);
        acc0 = __builtin_amdgcn_mfma_f32_16x16x32_bf16(af, bb0, acc0, 0, 0, 0);
        acc1 = __builtin_amdgcn_mfma_f32_16x16x32_bf16(af, bb1, acc1, 0, 0, 0);
    }
    #pragma unroll
    for (int t = 0; t < 2; ++t) {
        int n = wv * 32 + t * 16 + col;
        float bv = fb2[n];
        floatx4 acc = t ? acc1 : acc0;
        #pragma unroll
        for (int rg = 0; rg < 4; ++rg)
            ov[t][rg] = acc[rg] + bv + U.ffn.Xs[rowb + rg][n];
    }
    #pragma unroll
    for (int rg = 0; rg < 4; ++rg) {
        float s = ov[0][rg] + ov[1][rg];
        float q = ov[0][rg] * ov[0][rg] + ov[1][rg] * ov[1][rg];
        #pragma unroll
        for (int off = 8; off >= 1; off >>= 1) {
            s += __shfl_xor(s, off);
            q += __shfl_xor(q, off);
        }
        if ((lane & 15) == 0) { redS[wv][g][rg] = s; redQ[wv][g][rg] = q; }
    }
    __syncthreads();
    if (tid < 16) {
        int gg = tid >> 2, rg = tid & 3;
        float s = redS[0][gg][rg] + redS[1][gg][rg] + redS[2][gg][rg] + redS[3][gg][rg];
        float q = redQ[0][gg][rg] + redQ[1][gg][rg] + redQ[2][gg][rg] + redQ[3][gg][rg];
        float mean = s * 0.0078125f;
        float var = q * 0.0078125f - mean * mean;
        smean[tid] = mean;
        sinv[tid] = rsqrtf(var + 1e-5f);
    }
    __syncthreads();
    #pragma unroll
    for (int t = 0; t < 2; ++t) {
        int n = wv * 32 + t * 16 + col;
        float gm = g2[n], bb = b2ln[n];
        #pragma unroll
        for (int rg = 0; rg < 4; ++rg) {
            int row = rowb + rg;
            int qout = q0 + row;
            float val = (ov[t][rg] - smean[row]) * sinv[row] * gm + bb;
            if (!is_cls) {
                if (qout >= 1 && qout < Lq)
                    dout[1024 + (size_t)b * 65536 + (size_t)(qout - 1) * 128 + n] = val;
            } else {
                if (qout == 0) {
                    x2row[n] = val;
                    if (n == 0) poolb = b;
                }
            }
        }
    }
    __syncthreads();
    if (poolb >= 0 && tid < 128) {
        float acc = pb[tid];
        for (int k = 0; k < 128; ++k) acc = fmaf(x2row[k], pW[(size_t)k * 128 + tid], acc);
        dout[(size_t)poolb * 128 + tid] = tanhf(acc);
    }
}

// ---------------------------------------------------------------------------
extern "C" void kernel_launch(void* const* d_in, const int* in_sizes, int n_in,
                              void* d_out, int out_size, void* d_ws, size_t ws_size,
                              hipStream_t stream) {
    float* w = (float*)d_ws;
    size_t off = 0;
    auto alloc = [&](size_t n) {
        float* p = w + off;
        off += (n + 3) & ~(size_t)3;
        return p;
    };
    auto allocU = [&](size_t n) { return (unsigned short*)alloc((n + 1) / 2); };

    PrepAll pa{};
    int nn = n_in < 32 ? n_in : 32;
    float* fin[32];
    const int needconv[32] = {0,0,0,0,0,0, 0,1, 0,1, 1,1, 1,1, 0,1, 0,1, 0,1,
                              0,1, 1,1, 0,1, 0,1, 1,1, 1,1};
    int ncv = 0;
    for (int i = 0; i < nn; ++i) {
        pa.src[i] = d_in[i];
        pa.n[i] = in_sizes[i];
        fin[i] = alloc(in_sizes[i]);
        pa.dstoff[i] = (int)(fin[i] - w);
        if (needconv[i]) {
            int nb = (in_sizes[i] + 255) / 256;
            pa.cstart[i] = ncv;
            pa.cnum[i] = nb;
            ncv += nb;
        } else { pa.cstart[i] = -1; pa.cnum[i] = 0; }
    }
    for (int i = nn; i < 32; ++i) {
        pa.src[i] = nullptr; pa.n[i] = 0; pa.dstoff[i] = 0;
        pa.cstart[i] = -1; pa.cnum[i] = 0;
    }
    pa.ncv = ncv;

    const float* bq_t    = fin[7];
    const float* bk_t    = fin[9];
    const float* Wo_t    = fin[10]; const float* bo_t = fin[11];
    const float* pos_emb = fin[12]; const float* cls_emb = fin[13];
    const float* tbq = fin[15]; const float* tbk = fin[17]; const float* tbv = fin[19];
    const float* tbo = fin[21];
    const float* ln1_g = fin[22]; const float* ln1_b = fin[23];
    const float* fb1 = fin[25]; const float* fb2 = fin[27];
    const float* ln2_g = fin[28]; const float* ln2_b = fin[29];
    const float* pW = fin[30]; const float* pb = fin[31];

    const int widx[8] = {8, 6, 14, 16, 18, 20, 24, 26};
    unsigned short* wsw[8];
    for (int i = 0; i < 8; ++i) {
        wsw[i] = allocU(16384);
        pa.wsrc[i] = d_in[widx[i]];
        pa.wdst[i] = wsw[i];
        pa.wscale[i] = (i == 1 || i == 2) ? 0.125f : 1.0f;
    }
    pa.ts = d_in[1]; pa.w_per = d_in[2]; pa.b_per = d_in[3];
    pa.w_lin = d_in[4]; pa.b_lin = d_in[5];
    pa.xsrc = d_in[0];
    pa.det = (const unsigned short*)d_in[22];

    unsigned short* key_e16 = allocU(4224 * 128);
    unsigned short* cls_e16 = key_e16 + 4096 * 128;
    pa.key_e16 = key_e16;
    unsigned short* btg = allocU(8 * 16 * 512);
    pa.btg = btg;

    unsigned short* qp_main16 = allocU(4096 * 128);
    unsigned short* kp_main16 = allocU(4096 * 128);
    unsigned short* qp_cls16  = allocU(128 * 128);
    float* xin     = alloc((size_t)NT_ * 128);
    unsigned short* tbq16 = allocU((size_t)NT_ * 128);
    unsigned short* tbk16 = allocU((size_t)NT_ * 128);
    unsigned short* vT    = allocU((size_t)128 * VTS_);
    pa.vt = vT;
    (void)ws_size;

    float* outf = (float*)d_out;
    int prep_nblk = ncv + 512 + 2112 + 32 + 7;

    // 1: convert + weight swizzle + time embedding + Bt build + vT tail zero
    prep_all_kernel<<<prep_nblk, 256, 0, stream>>>(pa, w);

    // 2: mta projections
    {
        GemmM p{};
        p.A[0] = key_e16; p.W[0] = wsw[0]; p.bias[0] = bk_t; p.C[0] = kp_main16;
        p.M[0] = 4096; p.bscale[0] = 1.f;
        p.A[1] = key_e16; p.W[1] = wsw[1]; p.bias[1] = bq_t; p.C[1] = qp_main16;
        p.M[1] = 4096; p.bscale[1] = 0.125f;
        p.A[2] = cls_e16; p.W[2] = wsw[1]; p.bias[2] = bq_t; p.C[2] = qp_cls16;
        p.M[2] = 128; p.bscale[2] = 0.125f;
        gemm_mfma_kernel<<<dim3(256, 3), 256, 0, stream>>>(p);
    }

    // 3: fused mta attention (both heads, one pass) + mta-out + assemble + QKV
    mta_fused_kernel<<<321, 256, 0, stream>>>(qp_cls16, qp_main16, kp_main16, btg,
                                              Wo_t, bo_t, cls_emb, pos_emb, xin,
                                              wsw[2], wsw[3], wsw[4], tbq, tbk, tbv,
                                              tbq16, tbk16, vT);

    // 4: fused tblock attention (both heads, one pass) + attnout + FFN + pool
    tb_fused_kernel<<<dim3(42, 8), 256, 0, stream>>>(tbq16, tbk16, vT, xin,
                                                     wsw[5], tbo, ln1_g, ln1_b,
                                                     wsw[6], fb1, wsw[7], fb2,
                                                     ln2_g, ln2_b, pW, pb, outf);
}

// Round 5
// 200.344 us; speedup vs baseline: 2.1445x; 1.0178x over previous
//
#include <hip/hip_runtime.h>
#include <hip/hip_bf16.h>
#include <math.h>

// TimeBERT forward on MI355X. Inputs fp32 (runtime bf16 detector, inline).
// OUTPUT FP32: [cls_pooling (8,128) | last_hidden (8,512,128)].
//
// R22: manual software pipelining. R21 counters (MfmaUtil 1.2%, VALUBusy 8%,
// Occ 7.7% ~= 1.3 waves/SIMD, VGPR=68) showed latency-bound serial chains with
// NO compiler load hoisting. This round batches independent loads into named
// registers before consuming:
//  - QK/PV loops: group-of-3/4 k-tile frag preloads (12-16 loads in flight).
//  - Cross-phase prefetch: Wao+resid at kernel start; W1 under attnout MFMAs;
//    W2 under FFN1; mta: Bt at start, Wq under Wo-matvec, Wk/Wv rolling.
//  - Wo matvec grouped 8-wide (16 float4 in flight).
//  - gemm_mfma: all 12 loads hoisted.

static constexpr int NM_ = 8 * 513;           // 4104 main rows
static constexpr int NC_ = 8 * 129;           // 1032 cls rows
static constexpr int NT_ = NM_ + NC_;         // 5136 total
static constexpr int VTS_ = 5248;             // vT row stride (16-mult)

using bf = __hip_bfloat16;
typedef __attribute__((ext_vector_type(8))) short bf16x8;
typedef __attribute__((ext_vector_type(4))) short bf16x4;
typedef __attribute__((ext_vector_type(4))) float floatx4;
typedef __attribute__((ext_vector_type(8))) unsigned short ushortx8;

__device__ __forceinline__ float wave_reduce_sum(float v) {
    #pragma unroll
    for (int off = 32; off >= 1; off >>= 1) v += __shfl_xor(v, off);
    return v;
}
__device__ __forceinline__ float wave_reduce_max(float v) {
    #pragma unroll
    for (int off = 32; off >= 1; off >>= 1) v = fmaxf(v, __shfl_xor(v, off));
    return v;
}
__device__ __forceinline__ float u2f(unsigned short u) {
    return __uint_as_float(((unsigned)u) << 16);
}
__device__ __forceinline__ unsigned short f2u(float f) {   // RNE, finite
    unsigned u = __float_as_uint(f);
    return (unsigned short)((u + 0x7FFF + ((u >> 16) & 1)) >> 16);
}
__device__ __forceinline__ bf16x8 join8(bf16x4 lo, bf16x4 hi) {
    return __builtin_shufflevector(lo, hi, 0, 1, 2, 3, 4, 5, 6, 7);
}
__device__ __forceinline__ float rdin(const void* p, int i, int flag) {
    return flag ? u2f(((const unsigned short*)p)[i]) : ((const float*)p)[i];
}

// ---------------------------------------------------------------------------
// prep: [0,ncv) dense conversion; [ncv,+512) weight swizzle; [+2112) time emb;
// [+32) Bt build; [+7) vT tail zero.
struct PrepAll {
    const void* src[32]; int n[32]; int dstoff[32];
    int cstart[32]; int cnum[32];
    int ncv;
    const void* wsrc[8]; unsigned short* wdst[8]; float wscale[8];
    const void* ts; const void* w_per; const void* b_per;
    const void* w_lin; const void* b_lin;
    unsigned short* key_e16;
    unsigned short* btg;            // [b][c(16)][k(512)] bf16: c<8 -> x*m, else m
    const void* xsrc;               // raw x input (B,512,16)
    unsigned short* vt;             // transposed V buffer (tail-zeroed here)
    const unsigned short* det;
};
__global__ void prep_all_kernel(PrepAll a, float* dst) {
    int flag = (a.det[0] == 0x3F80u) ? 1 : 0;
    int blk = blockIdx.x, tid = threadIdx.x;
    if (blk < a.ncv) {
        int which = -1, bi = 0;
        #pragma unroll
        for (int i = 0; i < 32; ++i)
            if (blk >= a.cstart[i] && blk < a.cstart[i] + a.cnum[i]) { which = i; bi = blk - a.cstart[i]; }
        if (which < 0) return;
        int i = bi * 256 + tid;
        if (i < a.n[which]) dst[a.dstoff[which] + i] = rdin(a.src[which], i, flag);
    } else if (blk < a.ncv + 512) {
        int p = blk - a.ncv;
        int m = p >> 6;
        int idx = (p & 63) * 256 + tid;
        int c = idx >> 9;
        int l = (idx >> 3) & 63;
        int j = idx & 7;
        int k = (c >> 3) * 32 + (l >> 4) * 8 + j;
        int n = (c & 7) * 16 + (l & 15);
        a.wdst[m][idx] = f2u(rdin(a.wsrc[m], k * 128 + n, flag) * a.wscale[m]);
    } else if (blk < a.ncv + 512 + 2112) {
        int p = blk - a.ncv - 512;
        int row = p * 2 + (tid >> 7), j = tid & 127;
        float t = (row < 4096) ? rdin(a.ts, row, flag)
                               : (float)(row - 4096) * (1.0f / 127.0f);
        float v;
        if (j == 0) v = t * rdin(a.w_lin, 0, flag) + rdin(a.b_lin, 0, flag);
        else        v = sinf(t * rdin(a.w_per, j - 1, flag) + rdin(a.b_per, j - 1, flag));
        a.key_e16[row * 128 + j] = f2u(v);
    } else if (blk < a.ncv + 512 + 2112 + 32) {
        int p = blk - a.ncv - 512 - 2112;
        int e0 = (p * 256 + tid) * 8;
        int b = e0 >> 13;
        int c = (e0 >> 9) & 15;
        int k0 = e0 & 511;
        unsigned short out[8];
        #pragma unroll
        for (int j = 0; j < 8; ++j) {
            int k = k0 + j;
            float m = rdin(a.xsrc, (b * 512 + k) * 16 + 8 + (c & 7), flag);
            float val = (c < 8) ? rdin(a.xsrc, (b * 512 + k) * 16 + c, flag) * m : m;
            out[j] = f2u(val);
        }
        *(ushortx8*)(a.btg + e0) = *(ushortx8*)out;
    } else {
        int p = blk - a.ncv - 512 - 2112 - 32;
        int idx = p * 256 + tid;            // 0..1791 = 128*14
        if (idx < 128 * 14) {
            int n = idx / 14, c8 = idx - n * 14;
            ushortx8 z = {0, 0, 0, 0, 0, 0, 0, 0};
            *(ushortx8*)(a.vt + (size_t)n * VTS_ + 5136 + c8 * 8) = z;
        }
    }
}

// ---------------------------------------------------------------------------
// MFMA GEMM (projections): C16 = bf16(A16@W + bias*bscale). All loads hoisted.
struct GemmM {
    const void* A[3]; const unsigned short* W[3]; const float* bias[3];
    unsigned short* C[3];
    int M[3]; float bscale[3];
};
__global__ void __launch_bounds__(256)
gemm_mfma_kernel(GemmM p) {
    int y = blockIdx.y;
    const unsigned short* Wsw = p.W[y];
    const float* bias = p.bias[y];
    unsigned short* C = p.C[y];
    int M = p.M[y];
    float bscale = p.bscale[y];
    int m0 = blockIdx.x * 16;
    if (m0 >= M) return;
    int tid = threadIdx.x;
    int wv = tid >> 6, lane = tid & 63;
    int am = lane & 15, aq = lane >> 4;
    const unsigned short* A = (const unsigned short*)p.A[y];
    const unsigned short* Arow = A + (size_t)(m0 + am) * 128;
    bf16x8 af[4], b0[4], b1[4];
    #pragma unroll
    for (int ks = 0; ks < 4; ++ks) {
        af[ks] = *(const bf16x8*)(Arow + ks * 32 + aq * 8);
        const unsigned short* base = Wsw + ((size_t)ks * 8 + 2 * wv) * 512 + lane * 8;
        b0[ks] = *(const bf16x8*)(base);
        b1[ks] = *(const bf16x8*)(base + 512);
    }
    floatx4 acc0 = {0.f, 0.f, 0.f, 0.f}, acc1 = acc0;
    #pragma unroll
    for (int ks = 0; ks < 4; ++ks) {
        acc0 = __builtin_amdgcn_mfma_f32_16x16x32_bf16(af[ks], b0[ks], acc0, 0, 0, 0);
        acc1 = __builtin_amdgcn_mfma_f32_16x16x32_bf16(af[ks], b1[ks], acc1, 0, 0, 0);
    }
    int col = lane & 15, rowb = (lane >> 4) * 4;
    #pragma unroll
    for (int t = 0; t < 2; ++t) {
        floatx4 acc = t ? acc1 : acc0;
        int n = wv * 32 + t * 16 + col;
        float bv = bias[n] * bscale;
        #pragma unroll
        for (int rg = 0; rg < 4; ++rg)
            C[(size_t)(m0 + rowb + rg) * 128 + n] = f2u(acc[rg] + bv);
    }
}

// ---------------------------------------------------------------------------
// mta_fused: both-heads mta attention + mta-out matvec + assemble + QKV.
// Grid: 321 blocks. Deep load batching throughout.
struct MaAtt { unsigned short sp[2][16][520]; float red[2][1280]; };
union MaU { MaAtt att; unsigned short qAs[16][136]; };

__global__ void __launch_bounds__(256, 2)
mta_fused_kernel(const unsigned short* qp_cls, const unsigned short* qp_main,
                 const unsigned short* kp, const unsigned short* btg,
                 const float* Wo, const float* bo, const float* cls_emb, const float* pos,
                 float* xin,
                 const unsigned short* Wq, const unsigned short* Wk, const unsigned short* Wv,
                 const float* bq, const float* bk, const float* bv_,
                 unsigned short* outq, unsigned short* outk, unsigned short* vT) {
    __shared__ MaU U;
    __shared__ float As32[16][36];
    int vb = blockIdx.x, tid = threadIdx.x;
    int lane = tid & 63, wv = tid >> 6;
    int m = lane & 15, g = lane >> 4;
    bool special = (vb == 320);
    int is_cls = 0, qt = 0, b = 0;
    if (!special) {
        if (vb < 256) { b = vb >> 5; qt = vb & 31; }
        else { int t = vb - 256; b = t >> 3; qt = t & 7; is_cls = 1; }
    }
    int q0 = qt * 16;

    if (!special) {
        // early preloads: Q frags + Bt frags (consumed much later)
        const unsigned short* qrow = is_cls
            ? (qp_cls + (size_t)(q0 + m) * 128)
            : (qp_main + (size_t)(b * 512 + q0 + m) * 128);
        bf16x8 qf[2][2];
        #pragma unroll
        for (int h = 0; h < 2; ++h) {
            qf[h][0] = *(const bf16x8*)(qrow + h * 64 + g * 8);
            qf[h][1] = *(const bf16x8*)(qrow + h * 64 + 32 + g * 8);
        }
        bf16x8 btf[4];
        {
            const unsigned short* bbase = btg + ((size_t)(b * 16 + m)) * 512 + g * 8;
            #pragma unroll
            for (int cc = 0; cc < 4; ++cc)
                btf[cc] = *(const bf16x8*)(bbase + (wv + cc * 4) * 32);
        }

        // ---- QK^T: 2 groups of 4 k-tiles, 16 frag loads in flight ----
        const unsigned short* kbase = kp + ((size_t)b * 512) * 128;
        #pragma unroll
        for (int grp = 0; grp < 8; grp += 4) {
            bf16x8 kf[4][2][2];
            #pragma unroll
            for (int gi = 0; gi < 4; ++gi) {
                int colk = (grp + gi) * 64 + wv * 16 + m;
                const unsigned short* kb = kbase + (size_t)colk * 128;
                #pragma unroll
                for (int h = 0; h < 2; ++h) {
                    kf[gi][h][0] = *(const bf16x8*)(kb + h * 64 + g * 8);
                    kf[gi][h][1] = *(const bf16x8*)(kb + h * 64 + 32 + g * 8);
                }
            }
            #pragma unroll
            for (int gi = 0; gi < 4; ++gi) {
                int colk = (grp + gi) * 64 + wv * 16 + m;
                #pragma unroll
                for (int h = 0; h < 2; ++h) {
                    floatx4 acc = {0.f, 0.f, 0.f, 0.f};
                    acc = __builtin_amdgcn_mfma_f32_16x16x32_bf16(qf[h][0], kf[gi][h][0], acc, 0, 0, 0);
                    acc = __builtin_amdgcn_mfma_f32_16x16x32_bf16(qf[h][1], kf[gi][h][1], acc, 0, 0, 0);
                    #pragma unroll
                    for (int rg = 0; rg < 4; ++rg)
                        U.att.sp[h][g * 4 + rg][colk] = f2u(acc[rg]);
                }
            }
        }
        __syncthreads();

        // ---- exp(x - rowmax), 32 rows / 4 waves ----
        for (int rr2 = wv; rr2 < 32; rr2 += 4) {
            int h = rr2 >> 4, rr = rr2 & 15;
            float mx = -1e30f;
            #pragma unroll
            for (int k = 0; k < 8; ++k) mx = fmaxf(mx, u2f(U.att.sp[h][rr][k * 64 + lane]));
            mx = wave_reduce_max(mx);
            #pragma unroll
            for (int k = 0; k < 8; ++k)
                U.att.sp[h][rr][k * 64 + lane] = f2u(expf(u2f(U.att.sp[h][rr][k * 64 + lane]) - mx));
        }
        __syncthreads();

        // ---- P@Bt, both heads (Bt preloaded at start) ----
        floatx4 macc[2] = {{0.f,0.f,0.f,0.f},{0.f,0.f,0.f,0.f}};
        #pragma unroll
        for (int cc = 0; cc < 4; ++cc) {
            int koff = (wv + cc * 4) * 32;
            #pragma unroll
            for (int h = 0; h < 2; ++h) {
                bf16x8 af = *(const bf16x8*)&U.att.sp[h][m][koff + g * 8];
                macc[h] = __builtin_amdgcn_mfma_f32_16x16x32_bf16(af, btf[cc], macc[h], 0, 0, 0);
            }
        }
        #pragma unroll
        for (int h = 0; h < 2; ++h)
            #pragma unroll
            for (int rg = 0; rg < 4; ++rg)
                U.att.red[h][tid * 4 + rg] = macc[h][rg];
        __syncthreads();
        {
            int l = tid >> 2, rg = tid & 3;
            int row = (l >> 4) * 4 + rg, c = l & 15;
            #pragma unroll
            for (int h = 0; h < 2; ++h) {
                const float* rc = U.att.red[h];
                float s = rc[l * 4 + rg] + rc[(64 + l) * 4 + rg]
                        + rc[(128 + l) * 4 + rg] + rc[(192 + l) * 4 + rg];
                U.att.red[h][1024 + row * 16 + c] = s;
            }
        }
        __syncthreads();
        if (tid < 128) {
            int r = tid >> 3, c = tid & 7;
            #pragma unroll
            for (int h = 0; h < 2; ++h) {
                float num = U.att.red[h][1024 + r * 16 + c];
                float den = U.att.red[h][1024 + r * 16 + 8 + c];
                As32[r][h * 16 + c] = num / den;
                As32[r][h * 16 + 8 + c] = 1.0f;
            }
        }
        __syncthreads();
    }

    // ---- mta-out matvec (grouped 8-wide) + assemble ----
    int r = tid >> 4, gi2 = tid & 15, c0 = gi2 * 8;
    int segbase = is_cls ? (NM_ + b * 129) : (b * 513);
    auto Rof = [&](int rr) -> int {
        if (special) return (rr < 8) ? rr * 513 : NM_ + (rr - 8) * 129;
        return segbase + 1 + q0 + rr;
    };
    int R = Rof(r);
    int prow;
    if (special) prow = (r < 8) ? 0 : -1;
    else prow = is_cls ? -1 : (1 + q0 + r);

    // preload Wq frags (consumed in QKV y=0) under the matvec
    bf16x8 wfq[4][2];
    #pragma unroll
    for (int ks = 0; ks < 4; ++ks) {
        const unsigned short* base = Wq + ((size_t)ks * 8 + 2 * wv) * 512 + lane * 8;
        wfq[ks][0] = *(const bf16x8*)(base);
        wfq[ks][1] = *(const bf16x8*)(base + 512);
    }

    float acc[8];
    if (special) {
        #pragma unroll
        for (int j = 0; j < 8; ++j) acc[j] = cls_emb[c0 + j];
    } else {
        #pragma unroll
        for (int j = 0; j < 8; ++j) acc[j] = bo[c0 + j];
        #pragma unroll
        for (int kb0 = 0; kb0 < 32; kb0 += 8) {
            float4 w0[8], w1[8];
            #pragma unroll
            for (int j = 0; j < 8; ++j) {
                w0[j] = *(const float4*)(Wo + (size_t)(kb0 + j) * 128 + c0);
                w1[j] = *(const float4*)(Wo + (size_t)(kb0 + j) * 128 + c0 + 4);
            }
            #pragma unroll
            for (int j = 0; j < 8; ++j) {
                float a = As32[r][kb0 + j];
                acc[0] = fmaf(a, w0[j].x, acc[0]); acc[1] = fmaf(a, w0[j].y, acc[1]);
                acc[2] = fmaf(a, w0[j].z, acc[2]); acc[3] = fmaf(a, w0[j].w, acc[3]);
                acc[4] = fmaf(a, w1[j].x, acc[4]); acc[5] = fmaf(a, w1[j].y, acc[5]);
                acc[6] = fmaf(a, w1[j].z, acc[6]); acc[7] = fmaf(a, w1[j].w, acc[7]);
            }
        }
    }
    if (prow >= 0) {
        const float* pr = pos + (size_t)prow * 128 + c0;
        float4 p0 = *(const float4*)(pr);
        float4 p1 = *(const float4*)(pr + 4);
        acc[0] += p0.x; acc[1] += p0.y; acc[2] += p0.z; acc[3] += p0.w;
        acc[4] += p1.x; acc[5] += p1.y; acc[6] += p1.z; acc[7] += p1.w;
    }
    __syncthreads();            // att-phase LDS (aliased by qAs) fully consumed
    *(float4*)(xin + (size_t)R * 128 + c0) = make_float4(acc[0], acc[1], acc[2], acc[3]);
    *(float4*)(xin + (size_t)R * 128 + c0 + 4) = make_float4(acc[4], acc[5], acc[6], acc[7]);
    *(ushort4*)&U.qAs[r][c0] = make_ushort4(f2u(acc[0]), f2u(acc[1]), f2u(acc[2]), f2u(acc[3]));
    *(ushort4*)&U.qAs[r][c0 + 4] = make_ushort4(f2u(acc[4]), f2u(acc[5]), f2u(acc[6]), f2u(acc[7]));
    __syncthreads();

    int am = lane & 15, aq = lane >> 4;
    int col = lane & 15, rowb = (lane >> 4) * 4;
    const unsigned short* Wnext[2] = {Wk, Wv};
    const float* bs[3] = {bq, bk, bv_};
    float bsc[3] = {0.125f, 1.f, 1.f};
    unsigned short* Cs[2] = {outq, outk};
    bf16x8 wf[4][2];
    #pragma unroll
    for (int ks = 0; ks < 4; ++ks) { wf[ks][0] = wfq[ks][0]; wf[ks][1] = wfq[ks][1]; }
    #pragma unroll
    for (int y = 0; y < 3; ++y) {
        bf16x8 wfn[4][2];
        if (y < 2) {                       // rolling preload of next W under MFMAs
            #pragma unroll
            for (int ks = 0; ks < 4; ++ks) {
                const unsigned short* base = Wnext[y] + ((size_t)ks * 8 + 2 * wv) * 512 + lane * 8;
                wfn[ks][0] = *(const bf16x8*)(base);
                wfn[ks][1] = *(const bf16x8*)(base + 512);
            }
        }
        floatx4 acc0 = {0.f, 0.f, 0.f, 0.f}, acc1 = acc0;
        #pragma unroll
        for (int ks = 0; ks < 4; ++ks) {
            bf16x8 af = *(bf16x8*)&U.qAs[am][ks * 32 + aq * 8];
            acc0 = __builtin_amdgcn_mfma_f32_16x16x32_bf16(af, wf[ks][0], acc0, 0, 0, 0);
            acc1 = __builtin_amdgcn_mfma_f32_16x16x32_bf16(af, wf[ks][1], acc1, 0, 0, 0);
        }
        #pragma unroll
        for (int t = 0; t < 2; ++t) {
            floatx4 a2 = t ? acc1 : acc0;
            int n = wv * 32 + t * 16 + col;
            float bvv = bs[y][n] * bsc[y];
            #pragma unroll
            for (int rg = 0; rg < 4; ++rg) {
                unsigned short val = f2u(a2[rg] + bvv);
                int R2 = Rof(rowb + rg);
                if (y < 2) Cs[y][(size_t)R2 * 128 + n] = val;
                else       vT[(size_t)n * VTS_ + R2] = val;
            }
        }
        if (y < 2) {
            #pragma unroll
            for (int ks = 0; ks < 4; ++ks) { wf[ks][0] = wfn[ks][0]; wf[ks][1] = wfn[ks][1]; }
        }
    }
}

// ---------------------------------------------------------------------------
// tb_fused: both-heads tblock attention (NKT compile-time, grouped preloads) +
// attnout + LN1 + FFN + LN2 + pool. Grid (42, 8) = 336 blocks.
union TbU {
    unsigned short sp[2][16][588];
    struct { float Xs[16][128]; unsigned short Hs[16][136]; } ffn;
};

template<int NKT>
__device__ __forceinline__ void tb_attn_phase(
    const unsigned short* qp, const unsigned short* kp, const unsigned short* vT,
    int Lq, int base, int q0, int tid,
    unsigned short (&sp)[2][16][588], float (&rinv)[2][16],
    unsigned short (&As)[16][136])
{
    int lane = tid & 63, wv = tid >> 6;
    int m = lane & 15, g = lane >> 4;

    int qr = q0 + m; if (qr >= Lq) qr = Lq - 1;     // padded rows: dup, discarded
    const unsigned short* qrow = qp + (size_t)(base + qr) * 128;
    bf16x8 qf[2][2];
    #pragma unroll
    for (int h = 0; h < 2; ++h) {
        qf[h][0] = *(const bf16x8*)(qrow + h * 64 + g * 8);
        qf[h][1] = *(const bf16x8*)(qrow + h * 64 + 32 + g * 8);
    }

    // ---- QK^T: groups of 3 k-tiles (12 frag loads in flight) ----
    #pragma unroll
    for (int grp = 0; grp < NKT; grp += 3) {
        bf16x8 kf[3][2][2];
        #pragma unroll
        for (int gi = 0; gi < 3; ++gi) {
            int colk = (grp + gi) * 64 + wv * 16 + m;
            int krow = (colk < Lq) ? colk : (Lq - 1);
            const unsigned short* kb = kp + (size_t)(base + krow) * 128;
            #pragma unroll
            for (int h = 0; h < 2; ++h) {
                kf[gi][h][0] = *(const bf16x8*)(kb + h * 64 + g * 8);
                kf[gi][h][1] = *(const bf16x8*)(kb + h * 64 + 32 + g * 8);
            }
        }
        #pragma unroll
        for (int gi = 0; gi < 3; ++gi) {
            int colk = (grp + gi) * 64 + wv * 16 + m;
            #pragma unroll
            for (int h = 0; h < 2; ++h) {
                floatx4 acc = {0.f, 0.f, 0.f, 0.f};
                acc = __builtin_amdgcn_mfma_f32_16x16x32_bf16(qf[h][0], kf[gi][h][0], acc, 0, 0, 0);
                acc = __builtin_amdgcn_mfma_f32_16x16x32_bf16(qf[h][1], kf[gi][h][1], acc, 0, 0, 0);
                #pragma unroll
                for (int rg = 0; rg < 4; ++rg)
                    sp[h][g * 4 + rg][colk] = f2u((colk < Lq) ? acc[rg] : -1e30f);
            }
        }
    }
    __syncthreads();

    // ---- softmax: 32 rows / 4 waves ----
    for (int rr2 = wv; rr2 < 32; rr2 += 4) {
        int h = rr2 >> 4, rr = rr2 & 15;
        float mx = -1e30f;
        #pragma unroll
        for (int k = 0; k < NKT; ++k) mx = fmaxf(mx, u2f(sp[h][rr][k * 64 + lane]));
        mx = wave_reduce_max(mx);
        float sum = 0.f;
        #pragma unroll
        for (int k = 0; k < NKT; ++k) {
            float e = expf(u2f(sp[h][rr][k * 64 + lane]) - mx);
            sp[h][rr][k * 64 + lane] = f2u(e);
            sum += e;
        }
        sum = wave_reduce_sum(sum);
        if (lane == 0) rinv[h][rr] = 1.f / sum;
    }
    __syncthreads();

    // ---- PV: groups of 3 k-tiles, V frags preloaded (12 loads in flight) ----
    floatx4 oacc[2] = {{0.f,0.f,0.f,0.f},{0.f,0.f,0.f,0.f}};
    const unsigned short* vbase0 = vT + (size_t)(0 * 64 + wv * 16 + m) * VTS_ + base;
    const unsigned short* vbase1 = vT + (size_t)(1 * 64 + wv * 16 + m) * VTS_ + base;
    #pragma unroll
    for (int grp = 0; grp < NKT; grp += 3) {
        bf16x8 vf[3][2][2];
        #pragma unroll
        for (int gi = 0; gi < 3; ++gi) {
            int k0 = (grp + gi) * 64;
            #pragma unroll
            for (int c = 0; c < 2; ++c) {
                vf[gi][0][c] = *(const bf16x8*)(vbase0 + k0 + c * 32 + g * 8);
                vf[gi][1][c] = *(const bf16x8*)(vbase1 + k0 + c * 32 + g * 8);
            }
        }
        #pragma unroll
        for (int gi = 0; gi < 3; ++gi) {
            int k0 = (grp + gi) * 64;
            #pragma unroll
            for (int h = 0; h < 2; ++h) {
                #pragma unroll
                for (int c = 0; c < 2; ++c) {
                    bf16x4 plo = *(const bf16x4*)&sp[h][m][k0 + c * 32 + g * 8];
                    bf16x4 phi = *(const bf16x4*)&sp[h][m][k0 + c * 32 + g * 8 + 4];
                    oacc[h] = __builtin_amdgcn_mfma_f32_16x16x32_bf16(join8(plo, phi), vf[gi][h][c], oacc[h], 0, 0, 0);
                }
            }
        }
    }
    int dcol = wv * 16 + m;
    #pragma unroll
    for (int h = 0; h < 2; ++h)
        #pragma unroll
        for (int rg = 0; rg < 4; ++rg) {
            int q = g * 4 + rg;
            As[q][h * 64 + dcol] = f2u(oacc[h][rg] * rinv[h][q]);
        }
    __syncthreads();
}

__global__ void __launch_bounds__(256, 2)
tb_fused_kernel(const unsigned short* qp, const unsigned short* kp,
                const unsigned short* vT, const float* resid,
                const unsigned short* Wao, const float* bao,
                const float* g1, const float* b1ln,
                const unsigned short* W1, const float* fb1,
                const unsigned short* W2, const float* fb2,
                const float* g2, const float* b2ln,
                const float* pW, const float* pb, float* dout) {
    __shared__ TbU U;
    __shared__ unsigned short As[16][136];
    __shared__ float rinv[2][16];
    __shared__ float redS[4][4][4], redQ[4][4][4], smean[16], sinv[16], x2row[128];
    __shared__ int poolb;

    int xx = blockIdx.x, b = blockIdx.y, tid = threadIdx.x;
    int is_cls = (xx >= 33);
    int qt = is_cls ? xx - 33 : xx;
    int Lq = is_cls ? 129 : 513;
    int base = is_cls ? (NM_ + b * 129) : (b * 513);
    int lane = tid & 63, wv = tid >> 6;
    int q0 = qt * 16, g = lane >> 4;
    if (tid == 0) poolb = -1;

    int am = lane & 15, aq = lane >> 4;
    int col = lane & 15, rowb = g * 4;

    // ---- early preloads: Wao frags + resid values (fly under attention) ----
    bf16x8 waof[4][2];
    #pragma unroll
    for (int ks = 0; ks < 4; ++ks) {
        const unsigned short* wb = Wao + ((size_t)ks * 8 + 2 * wv) * 512 + lane * 8;
        waof[ks][0] = *(const bf16x8*)(wb);
        waof[ks][1] = *(const bf16x8*)(wb + 512);
    }
    float rres[2][4];
    #pragma unroll
    for (int t = 0; t < 2; ++t) {
        int n = wv * 32 + t * 16 + col;
        #pragma unroll
        for (int rg = 0; rg < 4; ++rg) {
            int qo = q0 + rowb + rg;
            int rc = (qo < Lq) ? qo : (Lq - 1);
            rres[t][rg] = resid[(size_t)(base + rc) * 128 + n];
        }
    }

    if (is_cls) tb_attn_phase<3>(qp, kp, vT, Lq, base, q0, tid, U.sp, rinv, As);
    else        tb_attn_phase<9>(qp, kp, vT, Lq, base, q0, tid, U.sp, rinv, As);

    // ---- attnout (Wao preloaded) ----
    float ov[2][4];
    bf16x8 w1f[4][2];
    {
        floatx4 acc0 = {0.f, 0.f, 0.f, 0.f}, acc1 = acc0;
        #pragma unroll
        for (int ks = 0; ks < 4; ++ks) {
            bf16x8 af = *(bf16x8*)&As[am][ks * 32 + aq * 8];
            acc0 = __builtin_amdgcn_mfma_f32_16x16x32_bf16(af, waof[ks][0], acc0, 0, 0, 0);
            acc1 = __builtin_amdgcn_mfma_f32_16x16x32_bf16(af, waof[ks][1], acc1, 0, 0, 0);
        }
        // preload W1 under the MFMA drain + LN1 reduction
        #pragma unroll
        for (int ks = 0; ks < 4; ++ks) {
            const unsigned short* wb = W1 + ((size_t)ks * 8 + 2 * wv) * 512 + lane * 8;
            w1f[ks][0] = *(const bf16x8*)(wb);
            w1f[ks][1] = *(const bf16x8*)(wb + 512);
        }
        #pragma unroll
        for (int t = 0; t < 2; ++t) {
            int n = wv * 32 + t * 16 + col;
            float bv = bao[n];
            floatx4 acc = t ? acc1 : acc0;
            #pragma unroll
            for (int rg = 0; rg < 4; ++rg)
                ov[t][rg] = acc[rg] + bv + rres[t][rg];
        }
    }
    #pragma unroll
    for (int rg = 0; rg < 4; ++rg) {
        float s = ov[0][rg] + ov[1][rg];
        float q = ov[0][rg] * ov[0][rg] + ov[1][rg] * ov[1][rg];
        #pragma unroll
        for (int off = 8; off >= 1; off >>= 1) {
            s += __shfl_xor(s, off);
            q += __shfl_xor(q, off);
        }
        if ((lane & 15) == 0) { redS[wv][g][rg] = s; redQ[wv][g][rg] = q; }
    }
    __syncthreads();
    if (tid < 16) {
        int gg = tid >> 2, rg = tid & 3;
        float s = redS[0][gg][rg] + redS[1][gg][rg] + redS[2][gg][rg] + redS[3][gg][rg];
        float q = redQ[0][gg][rg] + redQ[1][gg][rg] + redQ[2][gg][rg] + redQ[3][gg][rg];
        float mean = s * 0.0078125f;
        float var = q * 0.0078125f - mean * mean;
        smean[tid] = mean;
        sinv[tid] = rsqrtf(var + 1e-5f);
    }
    __syncthreads();
    #pragma unroll
    for (int t = 0; t < 2; ++t) {
        int n = wv * 32 + t * 16 + col;
        float gm = g1[n], bb = b1ln[n];
        #pragma unroll
        for (int rg = 0; rg < 4; ++rg) {
            int row = rowb + rg;
            float val = (ov[t][rg] - smean[row]) * sinv[row] * gm + bb;
            U.ffn.Xs[row][n] = val;
            As[row][n] = f2u(val);
        }
    }
    __syncthreads();

    // ---- FFN1 (W1 preloaded; W2 preloads under the MFMAs) ----
    bf16x8 w2f[4][2];
    {
        floatx4 acc0 = {0.f, 0.f, 0.f, 0.f}, acc1 = acc0;
        #pragma unroll
        for (int ks = 0; ks < 4; ++ks) {
            bf16x8 af = *(bf16x8*)&As[am][ks * 32 + aq * 8];
            acc0 = __builtin_amdgcn_mfma_f32_16x16x32_bf16(af, w1f[ks][0], acc0, 0, 0, 0);
            acc1 = __builtin_amdgcn_mfma_f32_16x16x32_bf16(af, w1f[ks][1], acc1, 0, 0, 0);
        }
        #pragma unroll
        for (int ks = 0; ks < 4; ++ks) {
            const unsigned short* wb = W2 + ((size_t)ks * 8 + 2 * wv) * 512 + lane * 8;
            w2f[ks][0] = *(const bf16x8*)(wb);
            w2f[ks][1] = *(const bf16x8*)(wb + 512);
        }
        #pragma unroll
        for (int t = 0; t < 2; ++t) {
            int n = wv * 32 + t * 16 + col;
            float bv = fb1[n];
            floatx4 acc = t ? acc1 : acc0;
            #pragma unroll
            for (int rg = 0; rg < 4; ++rg)
                U.ffn.Hs[rowb + rg][n] = f2u(fmaxf(acc[rg] + bv, 0.f));
        }
    }
    __syncthreads();

    // ---- FFN2 (W2 preloaded) ----
    floatx4 acc0 = {0.f, 0.f, 0.f, 0.f}, acc1 = acc0;
    #pragma unroll
    for (int ks = 0; ks < 4; ++ks) {
        bf16x8 af = *(bf16x8*)&U.ffn.Hs[am][ks * 32 + aq * 8];
        acc0 = __builtin_amdgcn_mfma_f32_16x16x32_bf16(af, w2f[ks][0], acc0, 0, 0, 0);
        acc1 = __builtin_amdgcn_mfma_f32_16x16x32_bf16(af, w2f[ks][1], acc1, 0, 0, 0);
    }
    #pragma unroll
    for (int t = 0; t < 2; ++t) {
        int n = wv * 32 + t * 16 + col;
        float bv = fb2[n];
        floatx4 acc = t ? acc1 : acc0;
        #pragma unroll
        for (int rg = 0; rg < 4; ++rg)
            ov[t][rg] = acc[rg] + bv + U.ffn.Xs[rowb + rg][n];
    }
    #pragma unroll
    for (int rg = 0; rg < 4; ++rg) {
        float s = ov[0][rg] + ov[1][rg];
        float q = ov[0][rg] * ov[0][rg] + ov[1][rg] * ov[1][rg];
        #pragma unroll
        for (int off = 8; off >= 1; off >>= 1) {
            s += __shfl_xor(s, off);
            q += __shfl_xor(q, off);
        }
        if ((lane & 15) == 0) { redS[wv][g][rg] = s; redQ[wv][g][rg] = q; }
    }
    __syncthreads();
    if (tid < 16) {
        int gg = tid >> 2, rg = tid & 3;
        float s = redS[0][gg][rg] + redS[1][gg][rg] + redS[2][gg][rg] + redS[3][gg][rg];
        float q = redQ[0][gg][rg] + redQ[1][gg][rg] + redQ[2][gg][rg] + redQ[3][gg][rg];
        float mean = s * 0.0078125f;
        float var = q * 0.0078125f - mean * mean;
        smean[tid] = mean;
        sinv[tid] = rsqrtf(var + 1e-5f);
    }
    __syncthreads();
    #pragma unroll
    for (int t = 0; t < 2; ++t) {
        int n = wv * 32 + t * 16 + col;
        float gm = g2[n], bb = b2ln[n];
        #pragma unroll
        for (int rg = 0; rg < 4; ++rg) {
            int row = rowb + rg;
            int qout = q0 + row;
            float val = (ov[t][rg] - smean[row]) * sinv[row] * gm + bb;
            if (!is_cls) {
                if (qout >= 1 && qout < Lq)
                    dout[1024 + (size_t)b * 65536 + (size_t)(qout - 1) * 128 + n] = val;
            } else {
                if (qout == 0) {
                    x2row[n] = val;
                    if (n == 0) poolb = b;
                }
            }
        }
    }
    __syncthreads();
    if (poolb >= 0 && tid < 128) {
        float acc = pb[tid];
        for (int k = 0; k < 128; ++k) acc = fmaf(x2row[k], pW[(size_t)k * 128 + tid], acc);
        dout[(size_t)poolb * 128 + tid] = tanhf(acc);
    }
}

// ---------------------------------------------------------------------------
extern "C" void kernel_launch(void* const* d_in, const int* in_sizes, int n_in,
                              void* d_out, int out_size, void* d_ws, size_t ws_size,
                              hipStream_t stream) {
    float* w = (float*)d_ws;
    size_t off = 0;
    auto alloc = [&](size_t n) {
        float* p = w + off;
        off += (n + 3) & ~(size_t)3;
        return p;
    };
    auto allocU = [&](size_t n) { return (unsigned short*)alloc((n + 1) / 2); };

    PrepAll pa{};
    int nn = n_in < 32 ? n_in : 32;
    float* fin[32];
    const int needconv[32] = {0,0,0,0,0,0, 0,1, 0,1, 1,1, 1,1, 0,1, 0,1, 0,1,
                              0,1, 1,1, 0,1, 0,1, 1,1, 1,1};
    int ncv = 0;
    for (int i = 0; i < nn; ++i) {
        pa.src[i] = d_in[i];
        pa.n[i] = in_sizes[i];
        fin[i] = alloc(in_sizes[i]);
        pa.dstoff[i] = (int)(fin[i] - w);
        if (needconv[i]) {
            int nb = (in_sizes[i] + 255) / 256;
            pa.cstart[i] = ncv;
            pa.cnum[i] = nb;
            ncv += nb;
        } else { pa.cstart[i] = -1; pa.cnum[i] = 0; }
    }
    for (int i = nn; i < 32; ++i) {
        pa.src[i] = nullptr; pa.n[i] = 0; pa.dstoff[i] = 0;
        pa.cstart[i] = -1; pa.cnum[i] = 0;
    }
    pa.ncv = ncv;

    const float* bq_t    = fin[7];
    const float* bk_t    = fin[9];
    const float* Wo_t    = fin[10]; const float* bo_t = fin[11];
    const float* pos_emb = fin[12]; const float* cls_emb = fin[13];
    const float* tbq = fin[15]; const float* tbk = fin[17]; const float* tbv = fin[19];
    const float* tbo = fin[21];
    const float* ln1_g = fin[22]; const float* ln1_b = fin[23];
    const float* fb1 = fin[25]; const float* fb2 = fin[27];
    const float* ln2_g = fin[28]; const float* ln2_b = fin[29];
    const float* pW = fin[30]; const float* pb = fin[31];

    const int widx[8] = {8, 6, 14, 16, 18, 20, 24, 26};
    unsigned short* wsw[8];
    for (int i = 0; i < 8; ++i) {
        wsw[i] = allocU(16384);
        pa.wsrc[i] = d_in[widx[i]];
        pa.wdst[i] = wsw[i];
        pa.wscale[i] = (i == 1 || i == 2) ? 0.125f : 1.0f;
    }
    pa.ts = d_in[1]; pa.w_per = d_in[2]; pa.b_per = d_in[3];
    pa.w_lin = d_in[4]; pa.b_lin = d_in[5];
    pa.xsrc = d_in[0];
    pa.det = (const unsigned short*)d_in[22];

    unsigned short* key_e16 = allocU(4224 * 128);
    unsigned short* cls_e16 = key_e16 + 4096 * 128;
    pa.key_e16 = key_e16;
    unsigned short* btg = allocU(8 * 16 * 512);
    pa.btg = btg;

    unsigned short* qp_main16 = allocU(4096 * 128);
    unsigned short* kp_main16 = allocU(4096 * 128);
    unsigned short* qp_cls16  = allocU(128 * 128);
    float* xin     = alloc((size_t)NT_ * 128);
    unsigned short* tbq16 = allocU((size_t)NT_ * 128);
    unsigned short* tbk16 = allocU((size_t)NT_ * 128);
    unsigned short* vT    = allocU((size_t)128 * VTS_);
    pa.vt = vT;
    (void)ws_size;

    float* outf = (float*)d_out;
    int prep_nblk = ncv + 512 + 2112 + 32 + 7;

    // 1: convert + weight swizzle + time embedding + Bt build + vT tail zero
    prep_all_kernel<<<prep_nblk, 256, 0, stream>>>(pa, w);

    // 2: mta projections
    {
        GemmM p{};
        p.A[0] = key_e16; p.W[0] = wsw[0]; p.bias[0] = bk_t; p.C[0] = kp_main16;
        p.M[0] = 4096; p.bscale[0] = 1.f;
        p.A[1] = key_e16; p.W[1] = wsw[1]; p.bias[1] = bq_t; p.C[1] = qp_main16;
        p.M[1] = 4096; p.bscale[1] = 0.125f;
        p.A[2] = cls_e16; p.W[2] = wsw[1]; p.bias[2] = bq_t; p.C[2] = qp_cls16;
        p.M[2] = 128; p.bscale[2] = 0.125f;
        gemm_mfma_kernel<<<dim3(256, 3), 256, 0, stream>>>(p);
    }

    // 3: fused mta attention + mta-out + assemble + QKV (pipelined)
    mta_fused_kernel<<<321, 256, 0, stream>>>(qp_cls16, qp_main16, kp_main16, btg,
                                              Wo_t, bo_t, cls_emb, pos_emb, xin,
                                              wsw[2], wsw[3], wsw[4], tbq, tbk, tbv,
                                              tbq16, tbk16, vT);

    // 4: fused tblock attention + attnout + FFN + pool (pipelined)
    tb_fused_kernel<<<dim3(42, 8), 256, 0, stream>>>(tbq16, tbk16, vT, xin,
                                                     wsw[5], tbo, ln1_g, ln1_b,
                                                     wsw[6], fb1, wsw[7], fb2,
                                                     ln2_g, ln2_b, pW, pb, outf);
}

// Round 6
// 192.727 us; speedup vs baseline: 2.2293x; 1.0395x over previous
//
#include <hip/hip_runtime.h>
#include <hip/hip_bf16.h>
#include <math.h>

// TimeBERT forward on MI355X. Inputs fp32 (runtime bf16 detector, inline).
// OUTPUT FP32: [cls_pooling (8,128) | last_hidden (8,512,128)].
//
// R23: TLP attack. R22's register-preload batching was undone by the compiler
// (VGPR 72 => loads re-serialized); occupancy stuck at 8% (1.3 waves/SIMD).
// This round widens blocks to 512 threads with HEAD = WAVE-GROUP:
//  - waves 0-3 compute head 0 QK/softmax/PV, waves 4-7 head 1, concurrently
//    -> 2x waves/SIMD, halved per-wave serial chain, fusion preserved.
//  - attnout/FFN/QKV retiled to 8 waves x 16 output cols (1 acc chain/wave).
//  - mta matvec: 512 threads x 4 cols.

static constexpr int NM_ = 8 * 513;           // 4104 main rows
static constexpr int NC_ = 8 * 129;           // 1032 cls rows
static constexpr int NT_ = NM_ + NC_;         // 5136 total
static constexpr int VTS_ = 5248;             // vT row stride (16-mult)

using bf = __hip_bfloat16;
typedef __attribute__((ext_vector_type(8))) short bf16x8;
typedef __attribute__((ext_vector_type(4))) short bf16x4;
typedef __attribute__((ext_vector_type(4))) float floatx4;
typedef __attribute__((ext_vector_type(8))) unsigned short ushortx8;

__device__ __forceinline__ float wave_reduce_sum(float v) {
    #pragma unroll
    for (int off = 32; off >= 1; off >>= 1) v += __shfl_xor(v, off);
    return v;
}
__device__ __forceinline__ float wave_reduce_max(float v) {
    #pragma unroll
    for (int off = 32; off >= 1; off >>= 1) v = fmaxf(v, __shfl_xor(v, off));
    return v;
}
__device__ __forceinline__ float u2f(unsigned short u) {
    return __uint_as_float(((unsigned)u) << 16);
}
__device__ __forceinline__ unsigned short f2u(float f) {   // RNE, finite
    unsigned u = __float_as_uint(f);
    return (unsigned short)((u + 0x7FFF + ((u >> 16) & 1)) >> 16);
}
__device__ __forceinline__ bf16x8 join8(bf16x4 lo, bf16x4 hi) {
    return __builtin_shufflevector(lo, hi, 0, 1, 2, 3, 4, 5, 6, 7);
}
__device__ __forceinline__ float rdin(const void* p, int i, int flag) {
    return flag ? u2f(((const unsigned short*)p)[i]) : ((const float*)p)[i];
}

// ---------------------------------------------------------------------------
// prep: [0,ncv) dense conversion; [ncv,+512) weight swizzle; [+2112) time emb;
// [+32) Bt build; [+7) vT tail zero.
struct PrepAll {
    const void* src[32]; int n[32]; int dstoff[32];
    int cstart[32]; int cnum[32];
    int ncv;
    const void* wsrc[8]; unsigned short* wdst[8]; float wscale[8];
    const void* ts; const void* w_per; const void* b_per;
    const void* w_lin; const void* b_lin;
    unsigned short* key_e16;
    unsigned short* btg;            // [b][c(16)][k(512)] bf16: c<8 -> x*m, else m
    const void* xsrc;               // raw x input (B,512,16)
    unsigned short* vt;             // transposed V buffer (tail-zeroed here)
    const unsigned short* det;
};
__global__ void prep_all_kernel(PrepAll a, float* dst) {
    int flag = (a.det[0] == 0x3F80u) ? 1 : 0;
    int blk = blockIdx.x, tid = threadIdx.x;
    if (blk < a.ncv) {
        int which = -1, bi = 0;
        #pragma unroll
        for (int i = 0; i < 32; ++i)
            if (blk >= a.cstart[i] && blk < a.cstart[i] + a.cnum[i]) { which = i; bi = blk - a.cstart[i]; }
        if (which < 0) return;
        int i = bi * 256 + tid;
        if (i < a.n[which]) dst[a.dstoff[which] + i] = rdin(a.src[which], i, flag);
    } else if (blk < a.ncv + 512) {
        int p = blk - a.ncv;
        int m = p >> 6;
        int idx = (p & 63) * 256 + tid;
        int c = idx >> 9;
        int l = (idx >> 3) & 63;
        int j = idx & 7;
        int k = (c >> 3) * 32 + (l >> 4) * 8 + j;
        int n = (c & 7) * 16 + (l & 15);
        a.wdst[m][idx] = f2u(rdin(a.wsrc[m], k * 128 + n, flag) * a.wscale[m]);
    } else if (blk < a.ncv + 512 + 2112) {
        int p = blk - a.ncv - 512;
        int row = p * 2 + (tid >> 7), j = tid & 127;
        float t = (row < 4096) ? rdin(a.ts, row, flag)
                               : (float)(row - 4096) * (1.0f / 127.0f);
        float v;
        if (j == 0) v = t * rdin(a.w_lin, 0, flag) + rdin(a.b_lin, 0, flag);
        else        v = sinf(t * rdin(a.w_per, j - 1, flag) + rdin(a.b_per, j - 1, flag));
        a.key_e16[row * 128 + j] = f2u(v);
    } else if (blk < a.ncv + 512 + 2112 + 32) {
        int p = blk - a.ncv - 512 - 2112;
        int e0 = (p * 256 + tid) * 8;
        int b = e0 >> 13;
        int c = (e0 >> 9) & 15;
        int k0 = e0 & 511;
        unsigned short out[8];
        #pragma unroll
        for (int j = 0; j < 8; ++j) {
            int k = k0 + j;
            float m = rdin(a.xsrc, (b * 512 + k) * 16 + 8 + (c & 7), flag);
            float val = (c < 8) ? rdin(a.xsrc, (b * 512 + k) * 16 + c, flag) * m : m;
            out[j] = f2u(val);
        }
        *(ushortx8*)(a.btg + e0) = *(ushortx8*)out;
    } else {
        int p = blk - a.ncv - 512 - 2112 - 32;
        int idx = p * 256 + tid;            // 0..1791 = 128*14
        if (idx < 128 * 14) {
            int n = idx / 14, c8 = idx - n * 14;
            ushortx8 z = {0, 0, 0, 0, 0, 0, 0, 0};
            *(ushortx8*)(a.vt + (size_t)n * VTS_ + 5136 + c8 * 8) = z;
        }
    }
}

// ---------------------------------------------------------------------------
// MFMA GEMM (projections): C16 = bf16(A16@W + bias*bscale).
struct GemmM {
    const void* A[3]; const unsigned short* W[3]; const float* bias[3];
    unsigned short* C[3];
    int M[3]; float bscale[3];
};
__global__ void __launch_bounds__(256)
gemm_mfma_kernel(GemmM p) {
    int y = blockIdx.y;
    const unsigned short* Wsw = p.W[y];
    const float* bias = p.bias[y];
    unsigned short* C = p.C[y];
    int M = p.M[y];
    float bscale = p.bscale[y];
    int m0 = blockIdx.x * 16;
    if (m0 >= M) return;
    int tid = threadIdx.x;
    int wv = tid >> 6, lane = tid & 63;
    int am = lane & 15, aq = lane >> 4;
    const unsigned short* A = (const unsigned short*)p.A[y];
    const unsigned short* Arow = A + (size_t)(m0 + am) * 128;
    floatx4 acc0 = {0.f, 0.f, 0.f, 0.f}, acc1 = acc0;
    #pragma unroll
    for (int ks = 0; ks < 4; ++ks) {
        bf16x8 af = *(const bf16x8*)(Arow + ks * 32 + aq * 8);
        const unsigned short* base = Wsw + ((size_t)ks * 8 + 2 * wv) * 512 + lane * 8;
        bf16x8 b0 = *(const bf16x8*)(base);
        bf16x8 b1 = *(const bf16x8*)(base + 512);
        acc0 = __builtin_amdgcn_mfma_f32_16x16x32_bf16(af, b0, acc0, 0, 0, 0);
        acc1 = __builtin_amdgcn_mfma_f32_16x16x32_bf16(af, b1, acc1, 0, 0, 0);
    }
    int col = lane & 15, rowb = (lane >> 4) * 4;
    #pragma unroll
    for (int t = 0; t < 2; ++t) {
        floatx4 acc = t ? acc1 : acc0;
        int n = wv * 32 + t * 16 + col;
        float bv = bias[n] * bscale;
        #pragma unroll
        for (int rg = 0; rg < 4; ++rg)
            C[(size_t)(m0 + rowb + rg) * 128 + n] = f2u(acc[rg] + bv);
    }
}

// ---------------------------------------------------------------------------
// mta_fused: 512 threads, head = wave-group. QK/softmax/P@Bt per head group;
// matvec 512-thread; QKV 8 waves x 16 cols. Grid: 321 blocks.
struct MaAtt { unsigned short sp[2][16][520]; float red[2][1280]; };
union MaU { MaAtt att; unsigned short qAs[16][136]; };

__global__ void __launch_bounds__(512, 2)
mta_fused_kernel(const unsigned short* qp_cls, const unsigned short* qp_main,
                 const unsigned short* kp, const unsigned short* btg,
                 const float* Wo, const float* bo, const float* cls_emb, const float* pos,
                 float* xin,
                 const unsigned short* Wq, const unsigned short* Wk, const unsigned short* Wv,
                 const float* bq, const float* bk, const float* bv_,
                 unsigned short* outq, unsigned short* outk, unsigned short* vT) {
    __shared__ MaU U;
    __shared__ float As32[16][36];
    int vb = blockIdx.x, tid = threadIdx.x;
    int lane = tid & 63, w = tid >> 6;
    int h = w >> 2, ws = w & 3;
    int m = lane & 15, g = lane >> 4;
    bool special = (vb == 320);
    int is_cls = 0, qt = 0, b = 0;
    if (!special) {
        if (vb < 256) { b = vb >> 5; qt = vb & 31; }
        else { int t = vb - 256; b = t >> 3; qt = t & 7; is_cls = 1; }
    }
    int q0 = qt * 16;

    if (!special) {
        const unsigned short* qrow = (is_cls
            ? (qp_cls + (size_t)(q0 + m) * 128)
            : (qp_main + (size_t)(b * 512 + q0 + m) * 128)) + h * 64;
        bf16x8 qf0 = *(const bf16x8*)(qrow + g * 8);
        bf16x8 qf1 = *(const bf16x8*)(qrow + 32 + g * 8);
        bf16x8 btf[4];
        {
            const unsigned short* bbase = btg + ((size_t)(b * 16 + m)) * 512 + g * 8;
            #pragma unroll
            for (int cc = 0; cc < 4; ++cc)
                btf[cc] = *(const bf16x8*)(bbase + (ws + cc * 4) * 32);
        }

        // ---- QK^T (my head), 8 k-tiles in groups of 4 ----
        const unsigned short* kbase = kp + ((size_t)b * 512) * 128 + h * 64;
        #pragma unroll
        for (int grp = 0; grp < 8; grp += 4) {
            bf16x8 kf[4][2];
            #pragma unroll
            for (int gi = 0; gi < 4; ++gi) {
                int colk = (grp + gi) * 64 + ws * 16 + m;
                const unsigned short* kb = kbase + (size_t)colk * 128;
                kf[gi][0] = *(const bf16x8*)(kb + g * 8);
                kf[gi][1] = *(const bf16x8*)(kb + 32 + g * 8);
            }
            #pragma unroll
            for (int gi = 0; gi < 4; ++gi) {
                int colk = (grp + gi) * 64 + ws * 16 + m;
                floatx4 acc = {0.f, 0.f, 0.f, 0.f};
                acc = __builtin_amdgcn_mfma_f32_16x16x32_bf16(qf0, kf[gi][0], acc, 0, 0, 0);
                acc = __builtin_amdgcn_mfma_f32_16x16x32_bf16(qf1, kf[gi][1], acc, 0, 0, 0);
                #pragma unroll
                for (int rg = 0; rg < 4; ++rg)
                    U.att.sp[h][g * 4 + rg][colk] = f2u(acc[rg]);
            }
        }
        __syncthreads();

        // ---- exp(x - rowmax): 32 (h,row) pairs / 8 waves ----
        for (int rr2 = w; rr2 < 32; rr2 += 8) {
            int hh = rr2 >> 4, rr = rr2 & 15;
            float mx = -1e30f;
            #pragma unroll
            for (int k = 0; k < 8; ++k) mx = fmaxf(mx, u2f(U.att.sp[hh][rr][k * 64 + lane]));
            mx = wave_reduce_max(mx);
            #pragma unroll
            for (int k = 0; k < 8; ++k)
                U.att.sp[hh][rr][k * 64 + lane] = f2u(expf(u2f(U.att.sp[hh][rr][k * 64 + lane]) - mx));
        }
        __syncthreads();

        // ---- P@Bt (my head) ----
        floatx4 macc = {0.f, 0.f, 0.f, 0.f};
        #pragma unroll
        for (int cc = 0; cc < 4; ++cc) {
            int koff = (ws + cc * 4) * 32;
            bf16x8 af = *(const bf16x8*)&U.att.sp[h][m][koff + g * 8];
            macc = __builtin_amdgcn_mfma_f32_16x16x32_bf16(af, btf[cc], macc, 0, 0, 0);
        }
        #pragma unroll
        for (int rg = 0; rg < 4; ++rg)
            U.att.red[h][(ws * 64 + lane) * 4 + rg] = macc[rg];
        __syncthreads();
        {
            int hh = tid >> 8, l2 = tid & 255;
            int l = l2 >> 2, rg = l2 & 3;
            const float* rc = U.att.red[hh];
            float s = rc[l * 4 + rg] + rc[(64 + l) * 4 + rg]
                    + rc[(128 + l) * 4 + rg] + rc[(192 + l) * 4 + rg];
            int row = (l >> 4) * 4 + rg, c = l & 15;
            U.att.red[hh][1024 + row * 16 + c] = s;
        }
        __syncthreads();
        if (tid < 128) {
            int r = tid >> 3, c = tid & 7;
            #pragma unroll
            for (int hh = 0; hh < 2; ++hh) {
                float num = U.att.red[hh][1024 + r * 16 + c];
                float den = U.att.red[hh][1024 + r * 16 + 8 + c];
                As32[r][hh * 16 + c] = num / den;
                As32[r][hh * 16 + 8 + c] = 1.0f;
            }
        }
        __syncthreads();
    }

    // ---- mta-out matvec (512 thr x 4 cols) + assemble ----
    int r4 = tid >> 5, c4 = (tid & 31) * 4;
    int segbase = is_cls ? (NM_ + b * 129) : (b * 513);
    auto Rof = [&](int rr) -> int {
        if (special) return (rr < 8) ? rr * 513 : NM_ + (rr - 8) * 129;
        return segbase + 1 + q0 + rr;
    };
    int R = Rof(r4);
    int prow;
    if (special) prow = (r4 < 8) ? 0 : -1;
    else prow = is_cls ? -1 : (1 + q0 + r4);

    float a4[4];
    if (special) {
        #pragma unroll
        for (int j = 0; j < 4; ++j) a4[j] = cls_emb[c4 + j];
    } else {
        #pragma unroll
        for (int j = 0; j < 4; ++j) a4[j] = bo[c4 + j];
        #pragma unroll
        for (int kb0 = 0; kb0 < 32; kb0 += 8) {
            float4 wv4[8];
            #pragma unroll
            for (int j = 0; j < 8; ++j)
                wv4[j] = *(const float4*)(Wo + (size_t)(kb0 + j) * 128 + c4);
            #pragma unroll
            for (int j = 0; j < 8; ++j) {
                float a = As32[r4][kb0 + j];
                a4[0] = fmaf(a, wv4[j].x, a4[0]); a4[1] = fmaf(a, wv4[j].y, a4[1]);
                a4[2] = fmaf(a, wv4[j].z, a4[2]); a4[3] = fmaf(a, wv4[j].w, a4[3]);
            }
        }
    }
    if (prow >= 0) {
        float4 p0 = *(const float4*)(pos + (size_t)prow * 128 + c4);
        a4[0] += p0.x; a4[1] += p0.y; a4[2] += p0.z; a4[3] += p0.w;
    }
    __syncthreads();            // att-phase LDS (aliased by qAs) fully consumed
    *(float4*)(xin + (size_t)R * 128 + c4) = make_float4(a4[0], a4[1], a4[2], a4[3]);
    *(ushort4*)&U.qAs[r4][c4] = make_ushort4(f2u(a4[0]), f2u(a4[1]), f2u(a4[2]), f2u(a4[3]));
    __syncthreads();

    // ---- QKV: 8 waves, each owns col-group w for all three outputs ----
    int am = lane & 15, aq = lane >> 4;
    int col = lane & 15, rowb = (lane >> 4) * 4;
    int n = w * 16 + col;
    const unsigned short* Wnext[2] = {Wk, Wv};
    const float* bs[3] = {bq, bk, bv_};
    float bsc[3] = {0.125f, 1.f, 1.f};
    unsigned short* Cs[2] = {outq, outk};
    bf16x8 wf[4];
    #pragma unroll
    for (int ks = 0; ks < 4; ++ks)
        wf[ks] = *(const bf16x8*)(Wq + ((size_t)ks * 8 + w) * 512 + lane * 8);
    #pragma unroll
    for (int y = 0; y < 3; ++y) {
        bf16x8 wfn[4];
        if (y < 2) {
            #pragma unroll
            for (int ks = 0; ks < 4; ++ks)
                wfn[ks] = *(const bf16x8*)(Wnext[y] + ((size_t)ks * 8 + w) * 512 + lane * 8);
        }
        floatx4 acc = {0.f, 0.f, 0.f, 0.f};
        #pragma unroll
        for (int ks = 0; ks < 4; ++ks) {
            bf16x8 af = *(bf16x8*)&U.qAs[am][ks * 32 + aq * 8];
            acc = __builtin_amdgcn_mfma_f32_16x16x32_bf16(af, wf[ks], acc, 0, 0, 0);
        }
        float bvv = bs[y][n] * bsc[y];
        #pragma unroll
        for (int rg = 0; rg < 4; ++rg) {
            unsigned short val = f2u(acc[rg] + bvv);
            int R2 = Rof(rowb + rg);
            if (y < 2) Cs[y][(size_t)R2 * 128 + n] = val;
            else       vT[(size_t)n * VTS_ + R2] = val;
        }
        if (y < 2) {
            #pragma unroll
            for (int ks = 0; ks < 4; ++ks) wf[ks] = wfn[ks];
        }
    }
}

// ---------------------------------------------------------------------------
// tb_fused: 512 threads, head = wave-group attention + 8-wave attnout/FFN.
// Grid (42, 8) = 336 blocks.
union TbU {
    unsigned short sp[2][16][588];
    struct { float Xs[16][128]; unsigned short Hs[16][136]; } ffn;
};

template<int NKT>
__device__ __forceinline__ void tb_attn_phase(
    const unsigned short* qp, const unsigned short* kp, const unsigned short* vT,
    int Lq, int base, int q0, int tid,
    unsigned short (&sp)[2][16][588], float (&rinv)[2][16],
    unsigned short (&As)[16][136])
{
    int lane = tid & 63, w = tid >> 6;
    int h = w >> 2, ws = w & 3;
    int m = lane & 15, g = lane >> 4;

    int qr = q0 + m; if (qr >= Lq) qr = Lq - 1;     // padded rows: dup, discarded
    const unsigned short* qrow = qp + (size_t)(base + qr) * 128 + h * 64;
    bf16x8 qf0 = *(const bf16x8*)(qrow + g * 8);
    bf16x8 qf1 = *(const bf16x8*)(qrow + 32 + g * 8);

    // ---- QK^T (my head): groups of 3 k-tiles ----
    #pragma unroll
    for (int grp = 0; grp < NKT; grp += 3) {
        bf16x8 kf[3][2];
        #pragma unroll
        for (int gi = 0; gi < 3; ++gi) {
            int colk = (grp + gi) * 64 + ws * 16 + m;
            int krow = (colk < Lq) ? colk : (Lq - 1);
            const unsigned short* kb = kp + (size_t)(base + krow) * 128 + h * 64;
            kf[gi][0] = *(const bf16x8*)(kb + g * 8);
            kf[gi][1] = *(const bf16x8*)(kb + 32 + g * 8);
        }
        #pragma unroll
        for (int gi = 0; gi < 3; ++gi) {
            int colk = (grp + gi) * 64 + ws * 16 + m;
            floatx4 acc = {0.f, 0.f, 0.f, 0.f};
            acc = __builtin_amdgcn_mfma_f32_16x16x32_bf16(qf0, kf[gi][0], acc, 0, 0, 0);
            acc = __builtin_amdgcn_mfma_f32_16x16x32_bf16(qf1, kf[gi][1], acc, 0, 0, 0);
            #pragma unroll
            for (int rg = 0; rg < 4; ++rg)
                sp[h][g * 4 + rg][colk] = f2u((colk < Lq) ? acc[rg] : -1e30f);
        }
    }
    __syncthreads();

    // ---- softmax: 32 (h,row) pairs / 8 waves ----
    for (int rr2 = w; rr2 < 32; rr2 += 8) {
        int hh = rr2 >> 4, rr = rr2 & 15;
        float mx = -1e30f;
        #pragma unroll
        for (int k = 0; k < NKT; ++k) mx = fmaxf(mx, u2f(sp[hh][rr][k * 64 + lane]));
        mx = wave_reduce_max(mx);
        float sum = 0.f;
        #pragma unroll
        for (int k = 0; k < NKT; ++k) {
            float e = expf(u2f(sp[hh][rr][k * 64 + lane]) - mx);
            sp[hh][rr][k * 64 + lane] = f2u(e);
            sum += e;
        }
        sum = wave_reduce_sum(sum);
        if (lane == 0) rinv[hh][rr] = 1.f / sum;
    }
    __syncthreads();

    // ---- PV (my head): groups of 3 k-tiles ----
    floatx4 oacc = {0.f, 0.f, 0.f, 0.f};
    const unsigned short* vbase = vT + (size_t)(h * 64 + ws * 16 + m) * VTS_ + base;
    #pragma unroll
    for (int grp = 0; grp < NKT; grp += 3) {
        bf16x8 vf[3][2];
        #pragma unroll
        for (int gi = 0; gi < 3; ++gi) {
            int k0 = (grp + gi) * 64;
            vf[gi][0] = *(const bf16x8*)(vbase + k0 + g * 8);
            vf[gi][1] = *(const bf16x8*)(vbase + k0 + 32 + g * 8);
        }
        #pragma unroll
        for (int gi = 0; gi < 3; ++gi) {
            int k0 = (grp + gi) * 64;
            #pragma unroll
            for (int c = 0; c < 2; ++c) {
                bf16x4 plo = *(const bf16x4*)&sp[h][m][k0 + c * 32 + g * 8];
                bf16x4 phi = *(const bf16x4*)&sp[h][m][k0 + c * 32 + g * 8 + 4];
                oacc = __builtin_amdgcn_mfma_f32_16x16x32_bf16(join8(plo, phi), vf[gi][c], oacc, 0, 0, 0);
            }
        }
    }
    int dcol = ws * 16 + m;
    #pragma unroll
    for (int rg = 0; rg < 4; ++rg) {
        int q = g * 4 + rg;
        As[q][h * 64 + dcol] = f2u(oacc[rg] * rinv[h][q]);
    }
    __syncthreads();
}

__global__ void __launch_bounds__(512, 2)
tb_fused_kernel(const unsigned short* qp, const unsigned short* kp,
                const unsigned short* vT, const float* resid,
                const unsigned short* Wao, const float* bao,
                const float* g1, const float* b1ln,
                const unsigned short* W1, const float* fb1,
                const unsigned short* W2, const float* fb2,
                const float* g2, const float* b2ln,
                const float* pW, const float* pb, float* dout) {
    __shared__ TbU U;
    __shared__ unsigned short As[16][136];
    __shared__ float rinv[2][16];
    __shared__ float redS[8][4][4], redQ[8][4][4], smean[16], sinv[16], x2row[128];
    __shared__ int poolb;

    int xx = blockIdx.x, b = blockIdx.y, tid = threadIdx.x;
    int is_cls = (xx >= 33);
    int qt = is_cls ? xx - 33 : xx;
    int Lq = is_cls ? 129 : 513;
    int base = is_cls ? (NM_ + b * 129) : (b * 513);
    int lane = tid & 63, w = tid >> 6;
    int q0 = qt * 16, g = lane >> 4;
    if (tid == 0) poolb = -1;

    int am = lane & 15, aq = lane >> 4;
    int col = lane & 15, rowb = g * 4;
    int n = w * 16 + col;                 // this wave's 16 output cols

    // ---- early preloads: Wao frags + resid (fly under attention) ----
    bf16x8 waof[4];
    #pragma unroll
    for (int ks = 0; ks < 4; ++ks)
        waof[ks] = *(const bf16x8*)(Wao + ((size_t)ks * 8 + w) * 512 + lane * 8);
    float rres[4];
    #pragma unroll
    for (int rg = 0; rg < 4; ++rg) {
        int qo = q0 + rowb + rg;
        int rc = (qo < Lq) ? qo : (Lq - 1);
        rres[rg] = resid[(size_t)(base + rc) * 128 + n];
    }

    if (is_cls) tb_attn_phase<3>(qp, kp, vT, Lq, base, q0, tid, U.sp, rinv, As);
    else        tb_attn_phase<9>(qp, kp, vT, Lq, base, q0, tid, U.sp, rinv, As);

    // ---- attnout (Wao preloaded) ----
    float ov[4];
    bf16x8 w1f[4];
    {
        floatx4 acc = {0.f, 0.f, 0.f, 0.f};
        #pragma unroll
        for (int ks = 0; ks < 4; ++ks) {
            bf16x8 af = *(bf16x8*)&As[am][ks * 32 + aq * 8];
            acc = __builtin_amdgcn_mfma_f32_16x16x32_bf16(af, waof[ks], acc, 0, 0, 0);
        }
        #pragma unroll
        for (int ks = 0; ks < 4; ++ks)
            w1f[ks] = *(const bf16x8*)(W1 + ((size_t)ks * 8 + w) * 512 + lane * 8);
        float bv = bao[n];
        #pragma unroll
        for (int rg = 0; rg < 4; ++rg)
            ov[rg] = acc[rg] + bv + rres[rg];
    }
    #pragma unroll
    for (int rg = 0; rg < 4; ++rg) {
        float s = ov[rg];
        float q = ov[rg] * ov[rg];
        #pragma unroll
        for (int off = 8; off >= 1; off >>= 1) {
            s += __shfl_xor(s, off);
            q += __shfl_xor(q, off);
        }
        if ((lane & 15) == 0) { redS[w][g][rg] = s; redQ[w][g][rg] = q; }
    }
    __syncthreads();
    if (tid < 16) {
        int gg = tid >> 2, rg = tid & 3;
        float s = 0.f, q = 0.f;
        #pragma unroll
        for (int ww = 0; ww < 8; ++ww) { s += redS[ww][gg][rg]; q += redQ[ww][gg][rg]; }
        float mean = s * 0.0078125f;
        float var = q * 0.0078125f - mean * mean;
        smean[tid] = mean;
        sinv[tid] = rsqrtf(var + 1e-5f);
    }
    __syncthreads();
    {
        float gm = g1[n], bb = b1ln[n];
        #pragma unroll
        for (int rg = 0; rg < 4; ++rg) {
            int row = rowb + rg;
            float val = (ov[rg] - smean[row]) * sinv[row] * gm + bb;
            U.ffn.Xs[row][n] = val;
            As[row][n] = f2u(val);
        }
    }
    __syncthreads();

    // ---- FFN1 (W1 preloaded; W2 preloads under MFMAs) ----
    bf16x8 w2f[4];
    {
        floatx4 acc = {0.f, 0.f, 0.f, 0.f};
        #pragma unroll
        for (int ks = 0; ks < 4; ++ks) {
            bf16x8 af = *(bf16x8*)&As[am][ks * 32 + aq * 8];
            acc = __builtin_amdgcn_mfma_f32_16x16x32_bf16(af, w1f[ks], acc, 0, 0, 0);
        }
        #pragma unroll
        for (int ks = 0; ks < 4; ++ks)
            w2f[ks] = *(const bf16x8*)(W2 + ((size_t)ks * 8 + w) * 512 + lane * 8);
        float bv = fb1[n];
        #pragma unroll
        for (int rg = 0; rg < 4; ++rg)
            U.ffn.Hs[rowb + rg][n] = f2u(fmaxf(acc[rg] + bv, 0.f));
    }
    __syncthreads();

    // ---- FFN2 (W2 preloaded) ----
    {
        floatx4 acc = {0.f, 0.f, 0.f, 0.f};
        #pragma unroll
        for (int ks = 0; ks < 4; ++ks) {
            bf16x8 af = *(bf16x8*)&U.ffn.Hs[am][ks * 32 + aq * 8];
            acc = __builtin_amdgcn_mfma_f32_16x16x32_bf16(af, w2f[ks], acc, 0, 0, 0);
        }
        float bv = fb2[n];
        #pragma unroll
        for (int rg = 0; rg < 4; ++rg)
            ov[rg] = acc[rg] + bv + U.ffn.Xs[rowb + rg][n];
    }
    #pragma unroll
    for (int rg = 0; rg < 4; ++rg) {
        float s = ov[rg];
        float q = ov[rg] * ov[rg];
        #pragma unroll
        for (int off = 8; off >= 1; off >>= 1) {
            s += __shfl_xor(s, off);
            q += __shfl_xor(q, off);
        }
        if ((lane & 15) == 0) { redS[w][g][rg] = s; redQ[w][g][rg] = q; }
    }
    __syncthreads();
    if (tid < 16) {
        int gg = tid >> 2, rg = tid & 3;
        float s = 0.f, q = 0.f;
        #pragma unroll
        for (int ww = 0; ww < 8; ++ww) { s += redS[ww][gg][rg]; q += redQ[ww][gg][rg]; }
        float mean = s * 0.0078125f;
        float var = q * 0.0078125f - mean * mean;
        smean[tid] = mean;
        sinv[tid] = rsqrtf(var + 1e-5f);
    }
    __syncthreads();
    {
        float gm = g2[n], bb = b2ln[n];
        #pragma unroll
        for (int rg = 0; rg < 4; ++rg) {
            int row = rowb + rg;
            int qout = q0 + row;
            float val = (ov[rg] - smean[row]) * sinv[row] * gm + bb;
            if (!is_cls) {
                if (qout >= 1 && qout < Lq)
                    dout[1024 + (size_t)b * 65536 + (size_t)(qout - 1) * 128 + n] = val;
            } else {
                if (qout == 0) {
                    x2row[n] = val;
                    if (n == 0) poolb = b;
                }
            }
        }
    }
    __syncthreads();
    if (poolb >= 0 && tid < 128) {
        float acc = pb[tid];
        for (int k = 0; k < 128; ++k) acc = fmaf(x2row[k], pW[(size_t)k * 128 + tid], acc);
        dout[(size_t)poolb * 128 + tid] = tanhf(acc);
    }
}

// ---------------------------------------------------------------------------
extern "C" void kernel_launch(void* const* d_in, const int* in_sizes, int n_in,
                              void* d_out, int out_size, void* d_ws, size_t ws_size,
                              hipStream_t stream) {
    float* w = (float*)d_ws;
    size_t off = 0;
    auto alloc = [&](size_t n) {
        float* p = w + off;
        off += (n + 3) & ~(size_t)3;
        return p;
    };
    auto allocU = [&](size_t n) { return (unsigned short*)alloc((n + 1) / 2); };

    PrepAll pa{};
    int nn = n_in < 32 ? n_in : 32;
    float* fin[32];
    const int needconv[32] = {0,0,0,0,0,0, 0,1, 0,1, 1,1, 1,1, 0,1, 0,1, 0,1,
                              0,1, 1,1, 0,1, 0,1, 1,1, 1,1};
    int ncv = 0;
    for (int i = 0; i < nn; ++i) {
        pa.src[i] = d_in[i];
        pa.n[i] = in_sizes[i];
        fin[i] = alloc(in_sizes[i]);
        pa.dstoff[i] = (int)(fin[i] - w);
        if (needconv[i]) {
            int nb = (in_sizes[i] + 255) / 256;
            pa.cstart[i] = ncv;
            pa.cnum[i] = nb;
            ncv += nb;
        } else { pa.cstart[i] = -1; pa.cnum[i] = 0; }
    }
    for (int i = nn; i < 32; ++i) {
        pa.src[i] = nullptr; pa.n[i] = 0; pa.dstoff[i] = 0;
        pa.cstart[i] = -1; pa.cnum[i] = 0;
    }
    pa.ncv = ncv;

    const float* bq_t    = fin[7];
    const float* bk_t    = fin[9];
    const float* Wo_t    = fin[10]; const float* bo_t = fin[11];
    const float* pos_emb = fin[12]; const float* cls_emb = fin[13];
    const float* tbq = fin[15]; const float* tbk = fin[17]; const float* tbv = fin[19];
    const float* tbo = fin[21];
    const float* ln1_g = fin[22]; const float* ln1_b = fin[23];
    const float* fb1 = fin[25]; const float* fb2 = fin[27];
    const float* ln2_g = fin[28]; const float* ln2_b = fin[29];
    const float* pW = fin[30]; const float* pb = fin[31];

    const int widx[8] = {8, 6, 14, 16, 18, 20, 24, 26};
    unsigned short* wsw[8];
    for (int i = 0; i < 8; ++i) {
        wsw[i] = allocU(16384);
        pa.wsrc[i] = d_in[widx[i]];
        pa.wdst[i] = wsw[i];
        pa.wscale[i] = (i == 1 || i == 2) ? 0.125f : 1.0f;
    }
    pa.ts = d_in[1]; pa.w_per = d_in[2]; pa.b_per = d_in[3];
    pa.w_lin = d_in[4]; pa.b_lin = d_in[5];
    pa.xsrc = d_in[0];
    pa.det = (const unsigned short*)d_in[22];

    unsigned short* key_e16 = allocU(4224 * 128);
    unsigned short* cls_e16 = key_e16 + 4096 * 128;
    pa.key_e16 = key_e16;
    unsigned short* btg = allocU(8 * 16 * 512);
    pa.btg = btg;

    unsigned short* qp_main16 = allocU(4096 * 128);
    unsigned short* kp_main16 = allocU(4096 * 128);
    unsigned short* qp_cls16  = allocU(128 * 128);
    float* xin     = alloc((size_t)NT_ * 128);
    unsigned short* tbq16 = allocU((size_t)NT_ * 128);
    unsigned short* tbk16 = allocU((size_t)NT_ * 128);
    unsigned short* vT    = allocU((size_t)128 * VTS_);
    pa.vt = vT;
    (void)ws_size;

    float* outf = (float*)d_out;
    int prep_nblk = ncv + 512 + 2112 + 32 + 7;

    // 1: convert + weight swizzle + time embedding + Bt build + vT tail zero
    prep_all_kernel<<<prep_nblk, 256, 0, stream>>>(pa, w);

    // 2: mta projections
    {
        GemmM p{};
        p.A[0] = key_e16; p.W[0] = wsw[0]; p.bias[0] = bk_t; p.C[0] = kp_main16;
        p.M[0] = 4096; p.bscale[0] = 1.f;
        p.A[1] = key_e16; p.W[1] = wsw[1]; p.bias[1] = bq_t; p.C[1] = qp_main16;
        p.M[1] = 4096; p.bscale[1] = 0.125f;
        p.A[2] = cls_e16; p.W[2] = wsw[1]; p.bias[2] = bq_t; p.C[2] = qp_cls16;
        p.M[2] = 128; p.bscale[2] = 0.125f;
        gemm_mfma_kernel<<<dim3(256, 3), 256, 0, stream>>>(p);
    }

    // 3: fused mta attention (head = wave-group) + mta-out + assemble + QKV
    mta_fused_kernel<<<321, 512, 0, stream>>>(qp_cls16, qp_main16, kp_main16, btg,
                                              Wo_t, bo_t, cls_emb, pos_emb, xin,
                                              wsw[2], wsw[3], wsw[4], tbq, tbk, tbv,
                                              tbq16, tbk16, vT);

    // 4: fused tblock attention (head = wave-group) + attnout + FFN + pool
    tb_fused_kernel<<<dim3(42, 8), 512, 0, stream>>>(tbq16, tbk16, vT, xin,
                                                     wsw[5], tbo, ln1_g, ln1_b,
                                                     wsw[6], fb1, wsw[7], fb2,
                                                     ln2_g, ln2_b, pW, pb, outf);
}

// Round 7
// 186.089 us; speedup vs baseline: 2.3088x; 1.0357x over previous
//
#include <hip/hip_runtime.h>
#include <hip/hip_bf16.h>
#include <math.h>

// TimeBERT forward on MI355X. Inputs fp32 (runtime bf16 detector, inline).
// OUTPUT FP32: [cls_pooling (8,128) | last_hidden (8,512,128)].
//
// R24: revert to the best-measured structure (R17, 6 kernels, LDS-staged
// attention, 180.4us) + XCD-affinity swizzle on the two attention kernels:
// grids flattened to 1D with b = blockIdx.x & 7, so all blocks sharing a
// segment's K/V land on the same XCD's L2 (round-robin block->XCD mapping).
// Eliminates per-XCD L2 duplication (R23 FETCH 13MB vs ~7MB unique) and
// converts K/V re-reads from L3 (~450-900cy) to local L2 (~200cy) hits.
// Everything else byte-identical to R17.

static constexpr int NM_ = 8 * 513;           // 4104 main rows
static constexpr int NC_ = 8 * 129;           // 1032 cls rows
static constexpr int NT_ = NM_ + NC_;         // 5136 total (= 321 * 16)

using bf = __hip_bfloat16;
typedef __attribute__((ext_vector_type(8))) short bf16x8;
typedef __attribute__((ext_vector_type(4))) short bf16x4;
typedef __attribute__((ext_vector_type(4))) float floatx4;
typedef __attribute__((ext_vector_type(8))) unsigned short ushortx8;

__device__ __forceinline__ float wave_reduce_sum(float v) {
    #pragma unroll
    for (int off = 32; off >= 1; off >>= 1) v += __shfl_xor(v, off);
    return v;
}
__device__ __forceinline__ float wave_reduce_max(float v) {
    #pragma unroll
    for (int off = 32; off >= 1; off >>= 1) v = fmaxf(v, __shfl_xor(v, off));
    return v;
}
__device__ __forceinline__ float u2f(unsigned short u) {
    return __uint_as_float(((unsigned)u) << 16);
}
__device__ __forceinline__ unsigned short f2u(float f) {   // RNE, finite
    unsigned u = __float_as_uint(f);
    return (unsigned short)((u + 0x7FFF + ((u >> 16) & 1)) >> 16);
}
__device__ __forceinline__ bf16x8 join8(bf16x4 lo, bf16x4 hi) {
    return __builtin_shufflevector(lo, hi, 0, 1, 2, 3, 4, 5, 6, 7);
}
__device__ __forceinline__ float rdin(const void* p, int i, int flag) {
    return flag ? u2f(((const unsigned short*)p)[i]) : ((const float*)p)[i];
}

// ---------------------------------------------------------------------------
// prep_all: [0,ncv) dense conversion blocks; [ncv,ncv+512) weight swizzle;
// [ncv+512, ncv+512+2112) time embedding; [.., +32) Bt build.
struct PrepAll {
    const void* src[32]; int n[32]; int dstoff[32];
    int cstart[32]; int cnum[32];
    int ncv;
    const void* wsrc[8]; unsigned short* wdst[8]; float wscale[8];
    const void* ts; const void* w_per; const void* b_per;
    const void* w_lin; const void* b_lin;
    unsigned short* key_e16;
    unsigned short* btg;            // [b][c(16)][k(512)] bf16: c<8 -> x*m, else m
    const void* xsrc;               // raw x input (B,512,16)
    const unsigned short* det;
};
__global__ void prep_all_kernel(PrepAll a, float* dst) {
    int flag = (a.det[0] == 0x3F80u) ? 1 : 0;
    int blk = blockIdx.x, tid = threadIdx.x;
    if (blk < a.ncv) {
        int which = -1, bi = 0;
        #pragma unroll
        for (int i = 0; i < 32; ++i)
            if (blk >= a.cstart[i] && blk < a.cstart[i] + a.cnum[i]) { which = i; bi = blk - a.cstart[i]; }
        if (which < 0) return;
        int i = bi * 256 + tid;
        if (i < a.n[which]) dst[a.dstoff[which] + i] = rdin(a.src[which], i, flag);
    } else if (blk < a.ncv + 512) {
        int p = blk - a.ncv;
        int m = p >> 6;
        int idx = (p & 63) * 256 + tid;
        int c = idx >> 9;
        int l = (idx >> 3) & 63;
        int j = idx & 7;
        int k = (c >> 3) * 32 + (l >> 4) * 8 + j;
        int n = (c & 7) * 16 + (l & 15);
        a.wdst[m][idx] = f2u(rdin(a.wsrc[m], k * 128 + n, flag) * a.wscale[m]);
    } else if (blk < a.ncv + 512 + 2112) {
        int p = blk - a.ncv - 512;
        int row = p * 2 + (tid >> 7), j = tid & 127;
        float t = (row < 4096) ? rdin(a.ts, row, flag)
                               : (float)(row - 4096) * (1.0f / 127.0f);
        float v;
        if (j == 0) v = t * rdin(a.w_lin, 0, flag) + rdin(a.b_lin, 0, flag);
        else        v = sinf(t * rdin(a.w_per, j - 1, flag) + rdin(a.b_per, j - 1, flag));
        a.key_e16[row * 128 + j] = f2u(v);
    } else {
        // Bt build: 32 blocks x 256 thr x 8 elems = 65536
        int p = blk - a.ncv - 512 - 2112;
        int e0 = (p * 256 + tid) * 8;
        int b = e0 >> 13;
        int c = (e0 >> 9) & 15;
        int k0 = e0 & 511;
        unsigned short out[8];
        #pragma unroll
        for (int j = 0; j < 8; ++j) {
            int k = k0 + j;
            float m = rdin(a.xsrc, (b * 512 + k) * 16 + 8 + (c & 7), flag);
            float val = (c < 8) ? rdin(a.xsrc, (b * 512 + k) * 16 + c, flag) * m : m;
            out[j] = f2u(val);
        }
        *(ushortx8*)(a.btg + e0) = *(ushortx8*)out;
    }
}

// ---------------------------------------------------------------------------
// MFMA GEMM (projections): C16 = bf16(A16@W + bias*bscale).
struct GemmM {
    const void* A[3]; const unsigned short* W[3]; const float* bias[3];
    unsigned short* C[3];
    int M[3]; float bscale[3];
};
__global__ void __launch_bounds__(256)
gemm_mfma_kernel(GemmM p) {
    int y = blockIdx.y;
    const unsigned short* Wsw = p.W[y];
    const float* bias = p.bias[y];
    unsigned short* C = p.C[y];
    int M = p.M[y];
    float bscale = p.bscale[y];
    int m0 = blockIdx.x * 16;
    if (m0 >= M) return;
    __shared__ unsigned short As[16][136];
    int tid = threadIdx.x;
    {
        const unsigned short* A = (const unsigned short*)p.A[y];
        int r = tid >> 4, c0 = (tid & 15) * 8;
        ushortx8 v = {0, 0, 0, 0, 0, 0, 0, 0};
        if (m0 + r < M) v = *(const ushortx8*)(A + (size_t)(m0 + r) * 128 + c0);
        *(ushortx8*)&As[r][c0] = v;
    }
    __syncthreads();

    int wv = tid >> 6, lane = tid & 63;
    floatx4 acc0 = {0.f, 0.f, 0.f, 0.f}, acc1 = acc0;
    int am = lane & 15, aq = lane >> 4;
    #pragma unroll
    for (int ks = 0; ks < 4; ++ks) {
        bf16x8 af = *(bf16x8*)&As[am][ks * 32 + aq * 8];
        const unsigned short* base = Wsw + ((size_t)ks * 8 + 2 * wv) * 512 + lane * 8;
        bf16x8 b0 = *(const bf16x8*)(base);
        bf16x8 b1 = *(const bf16x8*)(base + 512);
        acc0 = __builtin_amdgcn_mfma_f32_16x16x32_bf16(af, b0, acc0, 0, 0, 0);
        acc1 = __builtin_amdgcn_mfma_f32_16x16x32_bf16(af, b1, acc1, 0, 0, 0);
    }
    int col = lane & 15, rowb = (lane >> 4) * 4;
    #pragma unroll
    for (int t = 0; t < 2; ++t) {
        floatx4 acc = t ? acc1 : acc0;
        int n = wv * 32 + t * 16 + col;
        float bv = bias[n] * bscale;
        #pragma unroll
        for (int rg = 0; rg < 4; ++rg) {
            int m = m0 + rowb + rg;
            if (m < M) C[(size_t)m * 128 + n] = f2u(acc[rg] + bv);
        }
    }
}

// ---------------------------------------------------------------------------
// mta attention: MFMA QK^T + masked sums as P@Bt (Bt precomputed, global).
// Grid: 640 1D, XCD-affine: b = blockIdx.x & 7.
__global__ void __launch_bounds__(256)
mta_att_kernel(const unsigned short* qp_cls, const unsigned short* qp_main,
               const unsigned short* kp, const unsigned short* btg,
               float* att_cls, float* att_mn) {
    int F = blockIdx.x;
    int b = F & 7;                 // XCD affinity: segment b -> XCD b
    int j = F >> 3;                // 0..79
    int h = j & 1;
    int xx = j >> 1;               // 0..39
    int is_cls = (xx >= 32);
    int qt = is_cls ? (xx - 32) : xx;
    int tid = threadIdx.x, lane = tid & 63, wv = tid >> 6;
    __shared__ unsigned short Qs[16][72];
    __shared__ unsigned short KV[64][72];    // K tiles; overlay redC/Cfull later
    __shared__ unsigned short sp[16][520];
    int q0 = qt * 16;

    if (tid < 128) {
        int r = tid >> 3, c0 = (tid & 7) * 8;
        const unsigned short* qrow = is_cls ? (qp_cls + (size_t)(q0 + r) * 128 + h * 64)
                                            : (qp_main + (size_t)(b * 512 + q0 + r) * 128 + h * 64);
        *(ushortx8*)&Qs[r][c0] = *(const ushortx8*)(qrow + c0);
    }
    __syncthreads();

    bf16x8 qf0, qf1;
    {
        int m = lane & 15, g = lane >> 4;
        qf0 = *(const bf16x8*)&Qs[m][g * 8];
        qf1 = *(const bf16x8*)&Qs[m][32 + g * 8];
    }

    for (int kt = 0; kt < 8; ++kt) {
        int k0 = kt * 64;
        {
            int kk = tid >> 3, e0 = (tid & 7) * 8;
            #pragma unroll
            for (int it = 0; it < 2; ++it, kk += 32)
                *(ushortx8*)&KV[kk][e0] =
                    *(const ushortx8*)(kp + (size_t)(b * 512 + k0 + kk) * 128 + h * 64 + e0);
        }
        __syncthreads();
        int kn = lane & 15, g = lane >> 4;
        floatx4 acc = {0.f, 0.f, 0.f, 0.f};
        {
            bf16x8 b0 = *(const bf16x8*)&KV[wv * 16 + kn][g * 8];
            acc = __builtin_amdgcn_mfma_f32_16x16x32_bf16(qf0, b0, acc, 0, 0, 0);
            bf16x8 b1 = *(const bf16x8*)&KV[wv * 16 + kn][32 + g * 8];
            acc = __builtin_amdgcn_mfma_f32_16x16x32_bf16(qf1, b1, acc, 0, 0, 0);
        }
        int colk = k0 + wv * 16 + kn;
        #pragma unroll
        for (int rg = 0; rg < 4; ++rg) sp[g * 4 + rg][colk] = f2u(acc[rg]);
        __syncthreads();
    }

    for (int rr = wv; rr < 16; rr += 4) {
        float m = -1e30f;
        for (int k = lane; k < 512; k += 64) m = fmaxf(m, u2f(sp[rr][k]));
        m = wave_reduce_max(m);
        for (int k = lane; k < 512; k += 64) sp[rr][k] = f2u(expf(u2f(sp[rr][k]) - m));
    }
    __syncthreads();

    // masked sums via MFMA: B-frags straight from global Bt (L2-resident)
    floatx4 macc = {0.f, 0.f, 0.f, 0.f};
    {
        int mq = lane & 15, g = lane >> 4;
        const unsigned short* bbase = btg + ((size_t)(b * 16 + mq)) * 512 + g * 8;
        #pragma unroll
        for (int cc = 0; cc < 4; ++cc) {
            int koff = (wv + cc * 4) * 32;
            bf16x8 af = *(const bf16x8*)&sp[mq][koff + g * 8];
            bf16x8 bfv = *(const bf16x8*)(bbase + koff);
            macc = __builtin_amdgcn_mfma_f32_16x16x32_bf16(af, bfv, macc, 0, 0, 0);
        }
    }
    float* redC = (float*)&KV[0][0];
    float* Cfull = redC + 1024;
    #pragma unroll
    for (int rg = 0; rg < 4; ++rg) redC[(wv * 64 + lane) * 4 + rg] = macc[rg];
    __syncthreads();
    {
        int l = tid >> 2, rg = tid & 3;
        float s = redC[l * 4 + rg] + redC[(64 + l) * 4 + rg]
                + redC[(128 + l) * 4 + rg] + redC[(192 + l) * 4 + rg];
        int row = (l >> 4) * 4 + rg, c = l & 15;
        Cfull[row * 16 + c] = s;
    }
    __syncthreads();
    if (tid < 128) {
        int r = tid >> 3, c = tid & 7;
        float num = Cfull[r * 16 + c];
        float den = Cfull[r * 16 + 8 + c];
        int row = q0 + r;
        float* dst = is_cls ? (att_cls + (size_t)(b * 128 + row) * 32)
                            : (att_mn + (size_t)(b * 512 + row) * 32);
        dst[h * 16 + c] = num / den;
        dst[h * 16 + 8 + c] = 1.0f;
    }
}

// ---------------------------------------------------------------------------
// mta-out (K=32, inverse row map) + assemble + QKV MFMA. Grid 321 tiles.
__global__ void __launch_bounds__(256)
mta_qkv_kernel(const float* att, const float* Wo, const float* bo,
               const float* cls_emb, const float* pos, float* xin,
               const unsigned short* Wq, const unsigned short* Wk, const unsigned short* Wv,
               const float* bq, const float* bk, const float* bv_,
               unsigned short* outq, unsigned short* outk, unsigned short* outv) {
    int m0 = blockIdx.x * 16;
    __shared__ float As32[16][36];
    __shared__ unsigned short As[16][136];
    int tid = threadIdx.x;
    int r = tid >> 4, g = tid & 15, c0 = g * 8;

    int R = m0 + r;
    int srow, prow;
    if (R < NM_) {
        int b = R / 513, rr = R - b * 513;
        srow = (rr == 0) ? -1 : 1024 + b * 512 + (rr - 1);
        prow = rr;
    } else {
        int mc = R - NM_;
        int b = mc / 129, rr = mc - b * 129;
        srow = (rr == 0) ? -1 : b * 128 + (rr - 1);
        prow = -1;
    }
    if (g < 2 && srow >= 0) {
        const float* src = att + (size_t)srow * 32 + g * 16;
        *(float4*)&As32[r][g * 16]      = *(const float4*)(src);
        *(float4*)&As32[r][g * 16 + 4]  = *(const float4*)(src + 4);
        *(float4*)&As32[r][g * 16 + 8]  = *(const float4*)(src + 8);
        *(float4*)&As32[r][g * 16 + 12] = *(const float4*)(src + 12);
    }
    __syncthreads();

    float acc[8];
    if (srow < 0) {
        #pragma unroll
        for (int j = 0; j < 8; ++j) acc[j] = cls_emb[c0 + j];
    } else {
        #pragma unroll
        for (int j = 0; j < 8; ++j) acc[j] = bo[c0 + j];
        #pragma unroll 8
        for (int k = 0; k < 32; ++k) {
            float a = As32[r][k];
            const float4 w0 = *(const float4*)(Wo + (size_t)k * 128 + c0);
            const float4 w1 = *(const float4*)(Wo + (size_t)k * 128 + c0 + 4);
            acc[0] = fmaf(a, w0.x, acc[0]); acc[1] = fmaf(a, w0.y, acc[1]);
            acc[2] = fmaf(a, w0.z, acc[2]); acc[3] = fmaf(a, w0.w, acc[3]);
            acc[4] = fmaf(a, w1.x, acc[4]); acc[5] = fmaf(a, w1.y, acc[5]);
            acc[6] = fmaf(a, w1.z, acc[6]); acc[7] = fmaf(a, w1.w, acc[7]);
        }
    }
    if (prow >= 0) {
        const float* pr = pos + (size_t)prow * 128 + c0;
        float4 p0 = *(const float4*)(pr);
        float4 p1 = *(const float4*)(pr + 4);
        acc[0] += p0.x; acc[1] += p0.y; acc[2] += p0.z; acc[3] += p0.w;
        acc[4] += p1.x; acc[5] += p1.y; acc[6] += p1.z; acc[7] += p1.w;
    }
    *(float4*)(xin + (size_t)R * 128 + c0) = make_float4(acc[0], acc[1], acc[2], acc[3]);
    *(float4*)(xin + (size_t)R * 128 + c0 + 4) = make_float4(acc[4], acc[5], acc[6], acc[7]);
    *(ushort4*)&As[r][c0] = make_ushort4(f2u(acc[0]), f2u(acc[1]), f2u(acc[2]), f2u(acc[3]));
    *(ushort4*)&As[r][c0 + 4] = make_ushort4(f2u(acc[4]), f2u(acc[5]), f2u(acc[6]), f2u(acc[7]));
    __syncthreads();

    int wv = tid >> 6, lane = tid & 63;
    int am = lane & 15, aq = lane >> 4;
    int col = lane & 15, rowb = (lane >> 4) * 4;
    const unsigned short* Ws[3] = {Wq, Wk, Wv};
    const float* bs[3] = {bq, bk, bv_};
    float bsc[3] = {0.125f, 1.f, 1.f};
    unsigned short* Cs[3] = {outq, outk, outv};
    #pragma unroll
    for (int y = 0; y < 3; ++y) {
        floatx4 acc0 = {0.f, 0.f, 0.f, 0.f}, acc1 = acc0;
        #pragma unroll
        for (int ks = 0; ks < 4; ++ks) {
            bf16x8 af = *(bf16x8*)&As[am][ks * 32 + aq * 8];
            const unsigned short* base = Ws[y] + ((size_t)ks * 8 + 2 * wv) * 512 + lane * 8;
            bf16x8 b0 = *(const bf16x8*)(base);
            bf16x8 b1 = *(const bf16x8*)(base + 512);
            acc0 = __builtin_amdgcn_mfma_f32_16x16x32_bf16(af, b0, acc0, 0, 0, 0);
            acc1 = __builtin_amdgcn_mfma_f32_16x16x32_bf16(af, b1, acc1, 0, 0, 0);
        }
        #pragma unroll
        for (int t = 0; t < 2; ++t) {
            floatx4 a2 = t ? acc1 : acc0;
            int n = wv * 32 + t * 16 + col;
            float bvv = bs[y][n] * bsc[y];
            #pragma unroll
            for (int rg = 0; rg < 4; ++rg)
                Cs[y][(size_t)(m0 + rowb + rg) * 128 + n] = f2u(a2[rg] + bvv);
        }
    }
}

// ---------------------------------------------------------------------------
// tblock attention: bf16 in/out, MFMA QK^T + PV.
// Grid: 672 1D, XCD-affine: b = blockIdx.x & 7.
__global__ void __launch_bounds__(256)
tb_att_kernel(const unsigned short* qp, const unsigned short* kp,
              const unsigned short* vp, unsigned short* outp) {
    int F = blockIdx.x;
    int b = F & 7;                 // XCD affinity: segment b -> XCD b
    int j = F >> 3;                // 0..83
    int h = j & 1;
    int xx = j >> 1;               // 0..41
    int is_cls = (xx >= 33);
    int qt = is_cls ? xx - 33 : xx;
    int Lq = is_cls ? 129 : 513;
    int base = is_cls ? (4104 + b * 129) : (b * 513);
    int nkt = is_cls ? 3 : 9;
    int tid = threadIdx.x, lane = tid & 63, wv = tid >> 6;
    __shared__ unsigned short Qs[16][72];
    __shared__ unsigned short KV[64][72];
    __shared__ unsigned short sp[16][588];
    __shared__ float rinv[16];
    int q0 = qt * 16;

    if (tid < 128) {
        int r = tid >> 3, c0 = (tid & 7) * 8;
        int qr = q0 + r;
        ushortx8 v = {0, 0, 0, 0, 0, 0, 0, 0};
        if (qr < Lq) v = *(const ushortx8*)(qp + (size_t)(base + qr) * 128 + h * 64 + c0);
        *(ushortx8*)&Qs[r][c0] = v;
    }
    __syncthreads();

    bf16x8 qf0, qf1;
    {
        int m = lane & 15, g = lane >> 4;
        qf0 = *(const bf16x8*)&Qs[m][g * 8];
        qf1 = *(const bf16x8*)&Qs[m][32 + g * 8];
    }

    for (int kt = 0; kt < nkt; ++kt) {
        int k0 = kt * 64;
        {
            int kk = tid >> 3, e0 = (tid & 7) * 8;
            #pragma unroll
            for (int it = 0; it < 2; ++it, kk += 32) {
                int krow = k0 + kk;
                ushortx8 v = {0, 0, 0, 0, 0, 0, 0, 0};
                if (krow < Lq) v = *(const ushortx8*)(kp + (size_t)(base + krow) * 128 + h * 64 + e0);
                *(ushortx8*)&KV[kk][e0] = v;
            }
        }
        __syncthreads();
        int kn = lane & 15, g = lane >> 4;
        floatx4 acc = {0.f, 0.f, 0.f, 0.f};
        {
            bf16x8 b0 = *(const bf16x8*)&KV[wv * 16 + kn][g * 8];
            acc = __builtin_amdgcn_mfma_f32_16x16x32_bf16(qf0, b0, acc, 0, 0, 0);
            bf16x8 b1 = *(const bf16x8*)&KV[wv * 16 + kn][32 + g * 8];
            acc = __builtin_amdgcn_mfma_f32_16x16x32_bf16(qf1, b1, acc, 0, 0, 0);
        }
        int colk = k0 + wv * 16 + kn;
        #pragma unroll
        for (int rg = 0; rg < 4; ++rg)
            sp[g * 4 + rg][colk] = f2u((colk < Lq) ? acc[rg] : -1e30f);
        __syncthreads();
    }

    int kend = nkt * 64;
    for (int rr = wv; rr < 16; rr += 4) {
        float m = -1e30f;
        for (int k = lane; k < kend; k += 64) m = fmaxf(m, u2f(sp[rr][k]));
        m = wave_reduce_max(m);
        float sum = 0.f;
        for (int k = lane; k < kend; k += 64) {
            float e = expf(u2f(sp[rr][k]) - m);
            sp[rr][k] = f2u(e);
            sum += e;
        }
        sum = wave_reduce_sum(sum);
        if (lane == 0) rinv[rr] = 1.f / sum;
    }

    floatx4 oacc = {0.f, 0.f, 0.f, 0.f};
    for (int kt = 0; kt < nkt; ++kt) {
        int k0 = kt * 64;
        __syncthreads();
        {
            int kk = tid & 31, e0 = (tid >> 5) * 8;
            #pragma unroll
            for (int it = 0; it < 2; ++it, kk += 32) {
                int krow = k0 + kk;
                ushortx8 v = {0, 0, 0, 0, 0, 0, 0, 0};
                if (krow < Lq) v = *(const ushortx8*)(vp + (size_t)(base + krow) * 128 + h * 64 + e0);
                #pragma unroll
                for (int j2 = 0; j2 < 8; ++j2) KV[e0 + j2][kk] = v[j2];
            }
        }
        __syncthreads();
        int dn = lane & 15, g = lane >> 4;
        #pragma unroll
        for (int c = 0; c < 2; ++c) {
            bf16x4 plo = *(const bf16x4*)&sp[lane & 15][k0 + c * 32 + g * 8];
            bf16x4 phi = *(const bf16x4*)&sp[lane & 15][k0 + c * 32 + g * 8 + 4];
            bf16x8 vf = *(const bf16x8*)&KV[wv * 16 + dn][c * 32 + g * 8];
            oacc = __builtin_amdgcn_mfma_f32_16x16x32_bf16(join8(plo, phi), vf, oacc, 0, 0, 0);
        }
    }
    int dcol = wv * 16 + (lane & 15), g = lane >> 4;
    #pragma unroll
    for (int rg = 0; rg < 4; ++rg) {
        int q = g * 4 + rg;
        int qr = q0 + q;
        if (qr < Lq)
            outp[(size_t)(base + qr) * 128 + h * 64 + dcol] = f2u(oacc[rg] * rinv[q]);
    }
}

// ---------------------------------------------------------------------------
// attnout + LN1 + FFN1 + FFN2 + LN2 + pool -> d_out. Grid 321 tiles.
__global__ void __launch_bounds__(256)
attnout_ffn_kernel(const unsigned short* A, const unsigned short* Wao, const float* bao,
                   const float* resid, const float* g1, const float* b1ln,
                   const unsigned short* W1, const float* fb1,
                   const unsigned short* W2, const float* fb2,
                   const float* g2, const float* b2ln,
                   const float* pW, const float* pb, float* dout) {
    int m0 = blockIdx.x * 16;
    __shared__ unsigned short As[16][136];
    __shared__ float Xs[16][128];
    __shared__ unsigned short Hs[16][136];
    __shared__ float redS[4][4][4], redQ[4][4][4];
    __shared__ float smean[16], sinv[16];
    __shared__ float x2row[128];
    __shared__ int poolb;
    int tid = threadIdx.x;
    if (tid == 0) poolb = -1;
    {
        int r = tid >> 4, c0 = (tid & 15) * 8;
        *(ushortx8*)&As[r][c0] = *(const ushortx8*)(A + (size_t)(m0 + r) * 128 + c0);
    }
    __syncthreads();

    int wv = tid >> 6, lane = tid & 63;
    int am = lane & 15, aq = lane >> 4;
    int col = lane & 15, g = lane >> 4, rowb = g * 4;

    float ov[2][4];
    {
        floatx4 acc0 = {0.f, 0.f, 0.f, 0.f}, acc1 = acc0;
        #pragma unroll
        for (int ks = 0; ks < 4; ++ks) {
            bf16x8 af = *(bf16x8*)&As[am][ks * 32 + aq * 8];
            const unsigned short* base = Wao + ((size_t)ks * 8 + 2 * wv) * 512 + lane * 8;
            bf16x8 bb0 = *(const bf16x8*)(base);
            bf16x8 bb1 = *(const bf16x8*)(base + 512);
            acc0 = __builtin_amdgcn_mfma_f32_16x16x32_bf16(af, bb0, acc0, 0, 0, 0);
            acc1 = __builtin_amdgcn_mfma_f32_16x16x32_bf16(af, bb1, acc1, 0, 0, 0);
        }
        #pragma unroll
        for (int t = 0; t < 2; ++t) {
            int n = wv * 32 + t * 16 + col;
            float bv = bao[n];
            floatx4 acc = t ? acc1 : acc0;
            #pragma unroll
            for (int rg = 0; rg < 4; ++rg)
                ov[t][rg] = acc[rg] + bv + resid[(size_t)(m0 + rowb + rg) * 128 + n];
        }
    }
    #pragma unroll
    for (int rg = 0; rg < 4; ++rg) {
        float s = ov[0][rg] + ov[1][rg];
        float q = ov[0][rg] * ov[0][rg] + ov[1][rg] * ov[1][rg];
        #pragma unroll
        for (int off = 8; off >= 1; off >>= 1) {
            s += __shfl_xor(s, off);
            q += __shfl_xor(q, off);
        }
        if ((lane & 15) == 0) { redS[wv][g][rg] = s; redQ[wv][g][rg] = q; }
    }
    __syncthreads();
    if (tid < 16) {
        int gg = tid >> 2, rg = tid & 3;
        float s = redS[0][gg][rg] + redS[1][gg][rg] + redS[2][gg][rg] + redS[3][gg][rg];
        float q = redQ[0][gg][rg] + redQ[1][gg][rg] + redQ[2][gg][rg] + redQ[3][gg][rg];
        float mean = s * 0.0078125f;
        float var = q * 0.0078125f - mean * mean;
        smean[tid] = mean;
        sinv[tid] = rsqrtf(var + 1e-5f);
    }
    __syncthreads();
    #pragma unroll
    for (int t = 0; t < 2; ++t) {
        int n = wv * 32 + t * 16 + col;
        float gm = g1[n], bb = b1ln[n];
        #pragma unroll
        for (int rg = 0; rg < 4; ++rg) {
            int row = rowb + rg;
            float val = (ov[t][rg] - smean[row]) * sinv[row] * gm + bb;
            Xs[row][n] = val;
            As[row][n] = f2u(val);
        }
    }
    __syncthreads();

    {
        floatx4 acc0 = {0.f, 0.f, 0.f, 0.f}, acc1 = acc0;
        #pragma unroll
        for (int ks = 0; ks < 4; ++ks) {
            bf16x8 af = *(bf16x8*)&As[am][ks * 32 + aq * 8];
            const unsigned short* base = W1 + ((size_t)ks * 8 + 2 * wv) * 512 + lane * 8;
            bf16x8 bb0 = *(const bf16x8*)(base);
            bf16x8 bb1 = *(const bf16x8*)(base + 512);
            acc0 = __builtin_amdgcn_mfma_f32_16x16x32_bf16(af, bb0, acc0, 0, 0, 0);
            acc1 = __builtin_amdgcn_mfma_f32_16x16x32_bf16(af, bb1, acc1, 0, 0, 0);
        }
        #pragma unroll
        for (int t = 0; t < 2; ++t) {
            int n = wv * 32 + t * 16 + col;
            float bv = fb1[n];
            floatx4 acc = t ? acc1 : acc0;
            #pragma unroll
            for (int rg = 0; rg < 4; ++rg)
                Hs[rowb + rg][n] = f2u(fmaxf(acc[rg] + bv, 0.f));
        }
    }
    __syncthreads();

    floatx4 acc0 = {0.f, 0.f, 0.f, 0.f}, acc1 = acc0;
    #pragma unroll
    for (int ks = 0; ks < 4; ++ks) {
        bf16x8 af = *(bf16x8*)&Hs[am][ks * 32 + aq * 8];
        const unsigned short* base = W2 + ((size_t)ks * 8 + 2 * wv) * 512 + lane * 8;
        bf16x8 bb0 = *(const bf16x8*)(base);
        bf16x8 bb1 = *(const bf16x8*)(base + 512);
        acc0 = __builtin_amdgcn_mfma_f32_16x16x32_bf16(af, bb0, acc0, 0, 0, 0);
        acc1 = __builtin_amdgcn_mfma_f32_16x16x32_bf16(af, bb1, acc1, 0, 0, 0);
    }
    #pragma unroll
    for (int t = 0; t < 2; ++t) {
        int n = wv * 32 + t * 16 + col;
        float bv = fb2[n];
        floatx4 acc = t ? acc1 : acc0;
        #pragma unroll
        for (int rg = 0; rg < 4; ++rg)
            ov[t][rg] = acc[rg] + bv + Xs[rowb + rg][n];
    }
    #pragma unroll
    for (int rg = 0; rg < 4; ++rg) {
        float s = ov[0][rg] + ov[1][rg];
        float q = ov[0][rg] * ov[0][rg] + ov[1][rg] * ov[1][rg];
        #pragma unroll
        for (int off = 8; off >= 1; off >>= 1) {
            s += __shfl_xor(s, off);
            q += __shfl_xor(q, off);
        }
        if ((lane & 15) == 0) { redS[wv][g][rg] = s; redQ[wv][g][rg] = q; }
    }
    __syncthreads();
    if (tid < 16) {
        int gg = tid >> 2, rg = tid & 3;
        float s = redS[0][gg][rg] + redS[1][gg][rg] + redS[2][gg][rg] + redS[3][gg][rg];
        float q = redQ[0][gg][rg] + redQ[1][gg][rg] + redQ[2][gg][rg] + redQ[3][gg][rg];
        float mean = s * 0.0078125f;
        float var = q * 0.0078125f - mean * mean;
        smean[tid] = mean;
        sinv[tid] = rsqrtf(var + 1e-5f);
    }
    __syncthreads();
    #pragma unroll
    for (int t = 0; t < 2; ++t) {
        int n = wv * 32 + t * 16 + col;
        float gm = g2[n], bb = b2ln[n];
        #pragma unroll
        for (int rg = 0; rg < 4; ++rg) {
            int row = rowb + rg;
            int m = m0 + row;
            float val = (ov[t][rg] - smean[row]) * sinv[row] * gm + bb;
            if (m < NM_) {
                int b = m / 513, r = m - b * 513;
                if (r >= 1)
                    dout[1024 + (size_t)b * 65536 + (size_t)(r - 1) * 128 + n] = val;
            } else {
                int mc = m - NM_;
                int b = mc / 129, r = mc - b * 129;
                if (r == 0) {
                    x2row[n] = val;
                    if (n == 0) poolb = b;
                }
            }
        }
    }
    __syncthreads();
    if (poolb >= 0 && tid < 128) {
        float acc = pb[tid];
        for (int k = 0; k < 128; ++k) acc = fmaf(x2row[k], pW[(size_t)k * 128 + tid], acc);
        dout[(size_t)poolb * 128 + tid] = tanhf(acc);
    }
}

// ---------------------------------------------------------------------------
extern "C" void kernel_launch(void* const* d_in, const int* in_sizes, int n_in,
                              void* d_out, int out_size, void* d_ws, size_t ws_size,
                              hipStream_t stream) {
    float* w = (float*)d_ws;
    size_t off = 0;
    auto alloc = [&](size_t n) {
        float* p = w + off;
        off += (n + 3) & ~(size_t)3;
        return p;
    };
    auto allocU = [&](size_t n) { return (unsigned short*)alloc((n + 1) / 2); };

    PrepAll pa{};
    int nn = n_in < 32 ? n_in : 32;
    float* fin[32];
    // x (input 0) not converted: Bt built straight from raw input.
    const int needconv[32] = {0,0,0,0,0,0, 0,1, 0,1, 1,1, 1,1, 0,1, 0,1, 0,1,
                              0,1, 1,1, 0,1, 0,1, 1,1, 1,1};
    int ncv = 0;
    for (int i = 0; i < nn; ++i) {
        pa.src[i] = d_in[i];
        pa.n[i] = in_sizes[i];
        fin[i] = alloc(in_sizes[i]);
        pa.dstoff[i] = (int)(fin[i] - w);
        if (needconv[i]) {
            int nb = (in_sizes[i] + 255) / 256;
            pa.cstart[i] = ncv;
            pa.cnum[i] = nb;
            ncv += nb;
        } else { pa.cstart[i] = -1; pa.cnum[i] = 0; }
    }
    for (int i = nn; i < 32; ++i) {
        pa.src[i] = nullptr; pa.n[i] = 0; pa.dstoff[i] = 0;
        pa.cstart[i] = -1; pa.cnum[i] = 0;
    }
    pa.ncv = ncv;

    const float* bq_t    = fin[7];
    const float* bk_t    = fin[9];
    const float* Wo_t    = fin[10]; const float* bo_t = fin[11];
    const float* pos_emb = fin[12]; const float* cls_emb = fin[13];
    const float* tbq = fin[15]; const float* tbk = fin[17]; const float* tbv = fin[19];
    const float* tbo = fin[21];
    const float* ln1_g = fin[22]; const float* ln1_b = fin[23];
    const float* fb1 = fin[25]; const float* fb2 = fin[27];
    const float* ln2_g = fin[28]; const float* ln2_b = fin[29];
    const float* pW = fin[30]; const float* pb = fin[31];

    const int widx[8] = {8, 6, 14, 16, 18, 20, 24, 26};
    unsigned short* wsw[8];
    for (int i = 0; i < 8; ++i) {
        wsw[i] = allocU(16384);
        pa.wsrc[i] = d_in[widx[i]];
        pa.wdst[i] = wsw[i];
        pa.wscale[i] = (i == 1 || i == 2) ? 0.125f : 1.0f;
    }
    pa.ts = d_in[1]; pa.w_per = d_in[2]; pa.b_per = d_in[3];
    pa.w_lin = d_in[4]; pa.b_lin = d_in[5];
    pa.xsrc = d_in[0];
    pa.det = (const unsigned short*)d_in[22];

    unsigned short* key_e16 = allocU(4224 * 128);
    unsigned short* cls_e16 = key_e16 + 4096 * 128;
    pa.key_e16 = key_e16;
    unsigned short* btg = allocU(8 * 16 * 512);
    pa.btg = btg;

    unsigned short* qp_main16 = allocU(4096 * 128);
    unsigned short* kp_main16 = allocU(4096 * 128);
    unsigned short* qp_cls16  = allocU(128 * 128);
    float* att_all = alloc(5120 * 32);
    float* att_cls = att_all;
    float* att_mn  = att_all + 1024 * 32;
    float* xin     = alloc((size_t)NT_ * 128);
    unsigned short* tbq16 = allocU((size_t)NT_ * 128);
    unsigned short* tbk16 = allocU((size_t)NT_ * 128);
    unsigned short* tbv16 = allocU((size_t)NT_ * 128);
    unsigned short* tba16 = allocU((size_t)NT_ * 128);
    (void)ws_size;

    float* outf = (float*)d_out;

    // 1: convert (dense) + weight swizzle + time embedding + Bt build
    prep_all_kernel<<<ncv + 512 + 2112 + 32, 256, 0, stream>>>(pa, w);

    // 2: mta projections
    {
        GemmM p{};
        p.A[0] = key_e16; p.W[0] = wsw[0]; p.bias[0] = bk_t; p.C[0] = kp_main16;
        p.M[0] = 4096; p.bscale[0] = 1.f;
        p.A[1] = key_e16; p.W[1] = wsw[1]; p.bias[1] = bq_t; p.C[1] = qp_main16;
        p.M[1] = 4096; p.bscale[1] = 0.125f;
        p.A[2] = cls_e16; p.W[2] = wsw[1]; p.bias[2] = bq_t; p.C[2] = qp_cls16;
        p.M[2] = 128; p.bscale[2] = 0.125f;
        gemm_mfma_kernel<<<dim3(256, 3), 256, 0, stream>>>(p);
    }

    // 3: mta attention (XCD-affine 1D grid: b = blockIdx.x & 7)
    mta_att_kernel<<<640, 256, 0, stream>>>(qp_cls16, qp_main16, kp_main16,
                                            btg, att_cls, att_mn);

    // 4: mta-out + assemble + QKV
    mta_qkv_kernel<<<321, 256, 0, stream>>>(att_all, Wo_t, bo_t, cls_emb, pos_emb, xin,
                                            wsw[2], wsw[3], wsw[4], tbq, tbk, tbv,
                                            tbq16, tbk16, tbv16);

    // 5: tblock attention (XCD-affine 1D grid: b = blockIdx.x & 7)
    tb_att_kernel<<<672, 256, 0, stream>>>(tbq16, tbk16, tbv16, tba16);

    // 6: attnout + LN1 + FFN + LN2 + pool -> d_out
    attnout_ffn_kernel<<<321, 256, 0, stream>>>(tba16, wsw[5], tbo, xin, ln1_g, ln1_b,
                                                wsw[6], fb1, wsw[7], fb2, ln2_g, ln2_b,
                                                pW, pb, outf);
}

// Round 8
// 179.524 us; speedup vs baseline: 2.3932x; 1.0366x over previous
//
#include <hip/hip_runtime.h>
#include <hip/hip_bf16.h>
#include <math.h>

// TimeBERT forward on MI355X. Inputs fp32 (runtime bf16 detector, inline).
// OUTPUT FP32: [cls_pooling (8,128) | last_hidden (8,512,128)].
//
// R25: flash-style K-split of both attention kernels to fix the measured
// latency starvation (Occ 8%, ~1.3 waves/SIMD, serial 15-38-phase chains):
//  - tb_att -> tb_att_part: main q-tiles x 3 K-chunks (192 each), cls x 1.
//    Grid 672 -> 1728 blocks; chunk-local max/exp/sum + UNNORMALIZED PV;
//    f32 partials (O[16][64], m[16], l[16]) to global. Combine folded into
//    attnout's A-load stage (row-local rescale) -> no new kernel boundary.
//  - mta_att -> mta_att_part: K=512 split x 2 chunks (256). Grid 640 -> 1280.
//    Partials = chunk P@Bt (16x16 raw) + row max; combine folded into
//    mta_qkv's att-load stage.
// Everything else identical to the best-measured R17/R24 structure.

static constexpr int NM_ = 8 * 513;           // 4104 main rows
static constexpr int NC_ = 8 * 129;           // 1032 cls rows
static constexpr int NT_ = NM_ + NC_;         // 5136 total (= 321 * 16)

using bf = __hip_bfloat16;
typedef __attribute__((ext_vector_type(8))) short bf16x8;
typedef __attribute__((ext_vector_type(4))) short bf16x4;
typedef __attribute__((ext_vector_type(4))) float floatx4;
typedef __attribute__((ext_vector_type(8))) unsigned short ushortx8;

__device__ __forceinline__ float wave_reduce_sum(float v) {
    #pragma unroll
    for (int off = 32; off >= 1; off >>= 1) v += __shfl_xor(v, off);
    return v;
}
__device__ __forceinline__ float wave_reduce_max(float v) {
    #pragma unroll
    for (int off = 32; off >= 1; off >>= 1) v = fmaxf(v, __shfl_xor(v, off));
    return v;
}
__device__ __forceinline__ float u2f(unsigned short u) {
    return __uint_as_float(((unsigned)u) << 16);
}
__device__ __forceinline__ unsigned short f2u(float f) {   // RNE, finite
    unsigned u = __float_as_uint(f);
    return (unsigned short)((u + 0x7FFF + ((u >> 16) & 1)) >> 16);
}
__device__ __forceinline__ bf16x8 join8(bf16x4 lo, bf16x4 hi) {
    return __builtin_shufflevector(lo, hi, 0, 1, 2, 3, 4, 5, 6, 7);
}
__device__ __forceinline__ float rdin(const void* p, int i, int flag) {
    return flag ? u2f(((const unsigned short*)p)[i]) : ((const float*)p)[i];
}

// ---------------------------------------------------------------------------
// prep_all: [0,ncv) dense conversion blocks; [ncv,ncv+512) weight swizzle;
// [ncv+512, ncv+512+2112) time embedding; [.., +32) Bt build.
struct PrepAll {
    const void* src[32]; int n[32]; int dstoff[32];
    int cstart[32]; int cnum[32];
    int ncv;
    const void* wsrc[8]; unsigned short* wdst[8]; float wscale[8];
    const void* ts; const void* w_per; const void* b_per;
    const void* w_lin; const void* b_lin;
    unsigned short* key_e16;
    unsigned short* btg;            // [b][c(16)][k(512)] bf16: c<8 -> x*m, else m
    const void* xsrc;               // raw x input (B,512,16)
    const unsigned short* det;
};
__global__ void prep_all_kernel(PrepAll a, float* dst) {
    int flag = (a.det[0] == 0x3F80u) ? 1 : 0;
    int blk = blockIdx.x, tid = threadIdx.x;
    if (blk < a.ncv) {
        int which = -1, bi = 0;
        #pragma unroll
        for (int i = 0; i < 32; ++i)
            if (blk >= a.cstart[i] && blk < a.cstart[i] + a.cnum[i]) { which = i; bi = blk - a.cstart[i]; }
        if (which < 0) return;
        int i = bi * 256 + tid;
        if (i < a.n[which]) dst[a.dstoff[which] + i] = rdin(a.src[which], i, flag);
    } else if (blk < a.ncv + 512) {
        int p = blk - a.ncv;
        int m = p >> 6;
        int idx = (p & 63) * 256 + tid;
        int c = idx >> 9;
        int l = (idx >> 3) & 63;
        int j = idx & 7;
        int k = (c >> 3) * 32 + (l >> 4) * 8 + j;
        int n = (c & 7) * 16 + (l & 15);
        a.wdst[m][idx] = f2u(rdin(a.wsrc[m], k * 128 + n, flag) * a.wscale[m]);
    } else if (blk < a.ncv + 512 + 2112) {
        int p = blk - a.ncv - 512;
        int row = p * 2 + (tid >> 7), j = tid & 127;
        float t = (row < 4096) ? rdin(a.ts, row, flag)
                               : (float)(row - 4096) * (1.0f / 127.0f);
        float v;
        if (j == 0) v = t * rdin(a.w_lin, 0, flag) + rdin(a.b_lin, 0, flag);
        else        v = sinf(t * rdin(a.w_per, j - 1, flag) + rdin(a.b_per, j - 1, flag));
        a.key_e16[row * 128 + j] = f2u(v);
    } else {
        // Bt build: 32 blocks x 256 thr x 8 elems = 65536
        int p = blk - a.ncv - 512 - 2112;
        int e0 = (p * 256 + tid) * 8;
        int b = e0 >> 13;
        int c = (e0 >> 9) & 15;
        int k0 = e0 & 511;
        unsigned short out[8];
        #pragma unroll
        for (int j = 0; j < 8; ++j) {
            int k = k0 + j;
            float m = rdin(a.xsrc, (b * 512 + k) * 16 + 8 + (c & 7), flag);
            float val = (c < 8) ? rdin(a.xsrc, (b * 512 + k) * 16 + c, flag) * m : m;
            out[j] = f2u(val);
        }
        *(ushortx8*)(a.btg + e0) = *(ushortx8*)out;
    }
}

// ---------------------------------------------------------------------------
// MFMA GEMM (projections): C16 = bf16(A16@W + bias*bscale).
struct GemmM {
    const void* A[3]; const unsigned short* W[3]; const float* bias[3];
    unsigned short* C[3];
    int M[3]; float bscale[3];
};
__global__ void __launch_bounds__(256)
gemm_mfma_kernel(GemmM p) {
    int y = blockIdx.y;
    const unsigned short* Wsw = p.W[y];
    const float* bias = p.bias[y];
    unsigned short* C = p.C[y];
    int M = p.M[y];
    float bscale = p.bscale[y];
    int m0 = blockIdx.x * 16;
    if (m0 >= M) return;
    __shared__ unsigned short As[16][136];
    int tid = threadIdx.x;
    {
        const unsigned short* A = (const unsigned short*)p.A[y];
        int r = tid >> 4, c0 = (tid & 15) * 8;
        ushortx8 v = {0, 0, 0, 0, 0, 0, 0, 0};
        if (m0 + r < M) v = *(const ushortx8*)(A + (size_t)(m0 + r) * 128 + c0);
        *(ushortx8*)&As[r][c0] = v;
    }
    __syncthreads();

    int wv = tid >> 6, lane = tid & 63;
    floatx4 acc0 = {0.f, 0.f, 0.f, 0.f}, acc1 = acc0;
    int am = lane & 15, aq = lane >> 4;
    #pragma unroll
    for (int ks = 0; ks < 4; ++ks) {
        bf16x8 af = *(bf16x8*)&As[am][ks * 32 + aq * 8];
        const unsigned short* base = Wsw + ((size_t)ks * 8 + 2 * wv) * 512 + lane * 8;
        bf16x8 b0 = *(const bf16x8*)(base);
        bf16x8 b1 = *(const bf16x8*)(base + 512);
        acc0 = __builtin_amdgcn_mfma_f32_16x16x32_bf16(af, b0, acc0, 0, 0, 0);
        acc1 = __builtin_amdgcn_mfma_f32_16x16x32_bf16(af, b1, acc1, 0, 0, 0);
    }
    int col = lane & 15, rowb = (lane >> 4) * 4;
    #pragma unroll
    for (int t = 0; t < 2; ++t) {
        floatx4 acc = t ? acc1 : acc0;
        int n = wv * 32 + t * 16 + col;
        float bv = bias[n] * bscale;
        #pragma unroll
        for (int rg = 0; rg < 4; ++rg) {
            int m = m0 + rowb + rg;
            if (m < M) C[(size_t)m * 128 + n] = f2u(acc[rg] + bv);
        }
    }
}

// ---------------------------------------------------------------------------
// mta attention partial: K split x2 (256 each). Grid 1280 1D (b = F&7).
// Partials: mpa[pidx][16][16] raw P@Bt chunk sums, mma[pidx][16] row max.
// pidx = (((b*2+h)*40)+xx)*2+ch.
__global__ void __launch_bounds__(256)
mta_att_part_kernel(const unsigned short* qp_cls, const unsigned short* qp_main,
                    const unsigned short* kp, const unsigned short* btg,
                    float* mpa, float* mma) {
    int F = blockIdx.x;
    int b = F & 7;
    int j2 = F >> 3;               // 0..159
    int ch = j2 & 1;
    int j = j2 >> 1;               // 0..79
    int h = j & 1;
    int xx = j >> 1;               // 0..39
    int is_cls = (xx >= 32);
    int qt = is_cls ? (xx - 32) : xx;
    int tid = threadIdx.x, lane = tid & 63, wv = tid >> 6;
    __shared__ unsigned short Qs[16][72];
    __shared__ unsigned short KV[64][72];    // K tiles; overlay redC/Cfull later
    __shared__ unsigned short sp[16][264];   // 256 + pad
    __shared__ float mrow[16];
    int q0 = qt * 16;
    int kg0 = ch * 256;                      // this chunk's first key

    if (tid < 128) {
        int r = tid >> 3, c0 = (tid & 7) * 8;
        const unsigned short* qrow = is_cls ? (qp_cls + (size_t)(q0 + r) * 128 + h * 64)
                                            : (qp_main + (size_t)(b * 512 + q0 + r) * 128 + h * 64);
        *(ushortx8*)&Qs[r][c0] = *(const ushortx8*)(qrow + c0);
    }
    __syncthreads();

    bf16x8 qf0, qf1;
    {
        int m = lane & 15, g = lane >> 4;
        qf0 = *(const bf16x8*)&Qs[m][g * 8];
        qf1 = *(const bf16x8*)&Qs[m][32 + g * 8];
    }

    for (int kt = 0; kt < 4; ++kt) {
        int k0 = kt * 64;
        {
            int kk = tid >> 3, e0 = (tid & 7) * 8;
            #pragma unroll
            for (int it = 0; it < 2; ++it, kk += 32)
                *(ushortx8*)&KV[kk][e0] =
                    *(const ushortx8*)(kp + (size_t)(b * 512 + kg0 + k0 + kk) * 128 + h * 64 + e0);
        }
        __syncthreads();
        int kn = lane & 15, g = lane >> 4;
        floatx4 acc = {0.f, 0.f, 0.f, 0.f};
        {
            bf16x8 b0 = *(const bf16x8*)&KV[wv * 16 + kn][g * 8];
            acc = __builtin_amdgcn_mfma_f32_16x16x32_bf16(qf0, b0, acc, 0, 0, 0);
            bf16x8 b1 = *(const bf16x8*)&KV[wv * 16 + kn][32 + g * 8];
            acc = __builtin_amdgcn_mfma_f32_16x16x32_bf16(qf1, b1, acc, 0, 0, 0);
        }
        int colk = k0 + wv * 16 + kn;
        #pragma unroll
        for (int rg = 0; rg < 4; ++rg) sp[g * 4 + rg][colk] = f2u(acc[rg]);
        __syncthreads();
    }

    for (int rr = wv; rr < 16; rr += 4) {
        float m = -1e30f;
        for (int k = lane; k < 256; k += 64) m = fmaxf(m, u2f(sp[rr][k]));
        m = wave_reduce_max(m);
        for (int k = lane; k < 256; k += 64) sp[rr][k] = f2u(expf(u2f(sp[rr][k]) - m));
        if (lane == 0) mrow[rr] = m;
    }
    __syncthreads();

    // chunk P@Bt: B-frags from global Bt at this chunk's k-range
    floatx4 macc = {0.f, 0.f, 0.f, 0.f};
    {
        int mq = lane & 15, g = lane >> 4;
        const unsigned short* bbase = btg + ((size_t)(b * 16 + mq)) * 512 + kg0 + g * 8;
        #pragma unroll
        for (int cc = 0; cc < 2; ++cc) {
            int koff = (wv + cc * 4) * 32;
            bf16x8 af = *(const bf16x8*)&sp[mq][koff + g * 8];
            bf16x8 bfv = *(const bf16x8*)(bbase + koff);
            macc = __builtin_amdgcn_mfma_f32_16x16x32_bf16(af, bfv, macc, 0, 0, 0);
        }
    }
    float* redC = (float*)&KV[0][0];
    float* Cfull = redC + 1024;
    #pragma unroll
    for (int rg = 0; rg < 4; ++rg) redC[(wv * 64 + lane) * 4 + rg] = macc[rg];
    __syncthreads();
    {
        int l = tid >> 2, rg = tid & 3;
        float s = redC[l * 4 + rg] + redC[(64 + l) * 4 + rg]
                + redC[(128 + l) * 4 + rg] + redC[(192 + l) * 4 + rg];
        int row = (l >> 4) * 4 + rg, c = l & 15;
        Cfull[row * 16 + c] = s;
    }
    __syncthreads();
    size_t pidx = ((size_t)(((b * 2 + h) * 40) + xx)) * 2 + ch;
    mpa[pidx * 256 + tid] = Cfull[tid];
    if (tid < 16) mma[pidx * 16 + tid] = mrow[tid];
}

// ---------------------------------------------------------------------------
// mta-out (combine 2 K-chunks -> att ratios, then K=32 matvec) + assemble +
// QKV MFMA. Grid 321 tiles.
__global__ void __launch_bounds__(256)
mta_qkv_kernel(const float* mpa, const float* mma,
               const float* Wo, const float* bo,
               const float* cls_emb, const float* pos, float* xin,
               const unsigned short* Wq, const unsigned short* Wk, const unsigned short* Wv,
               const float* bq, const float* bk, const float* bv_,
               unsigned short* outq, unsigned short* outk, unsigned short* outv) {
    int m0 = blockIdx.x * 16;
    __shared__ float As32[16][36];
    __shared__ unsigned short As[16][136];
    int tid = threadIdx.x;
    int r = tid >> 4, g = tid & 15, c0 = g * 8;

    int R = m0 + r;
    int srow, prow;
    if (R < NM_) {
        int b = R / 513, rr = R - b * 513;
        srow = (rr == 0) ? -1 : 1;
        prow = rr;
    } else {
        int mc = R - NM_;
        int b = mc / 129, rr = mc - b * 129;
        srow = (rr == 0) ? -1 : 1;
        prow = -1;
    }
    // combine: 16 threads per row, thread g handles (hh = g>>3, c = g&7)
    if (srow >= 0) {
        int hh = g >> 3, c = g & 7;
        int bb, xx2, lr2;
        if (R < NM_) {
            bb = R / 513; int ridx = R - bb * 513 - 1;
            xx2 = ridx >> 4; lr2 = ridx & 15;
        } else {
            int mc = R - NM_;
            bb = mc / 129; int ridx = mc - bb * 129 - 1;
            xx2 = 32 + (ridx >> 4); lr2 = ridx & 15;
        }
        size_t p0 = ((size_t)(((bb * 2 + hh) * 40) + xx2)) * 2;
        const float* C0 = mpa + (p0 + 0) * 256 + lr2 * 16;
        const float* C1 = mpa + (p0 + 1) * 256 + lr2 * 16;
        float m0v = mma[(p0 + 0) * 16 + lr2];
        float m1v = mma[(p0 + 1) * 16 + lr2];
        float mm = fmaxf(m0v, m1v);
        float e0 = expf(m0v - mm), e1 = expf(m1v - mm);
        float num = C0[c] * e0 + C1[c] * e1;
        float den = C0[8 + c] * e0 + C1[8 + c] * e1;
        As32[r][hh * 16 + c] = num / den;
        As32[r][hh * 16 + 8 + c] = 1.0f;
    }
    __syncthreads();

    float acc[8];
    if (srow < 0) {
        #pragma unroll
        for (int j = 0; j < 8; ++j) acc[j] = cls_emb[c0 + j];
    } else {
        #pragma unroll
        for (int j = 0; j < 8; ++j) acc[j] = bo[c0 + j];
        #pragma unroll 8
        for (int k = 0; k < 32; ++k) {
            float a = As32[r][k];
            const float4 w0 = *(const float4*)(Wo + (size_t)k * 128 + c0);
            const float4 w1 = *(const float4*)(Wo + (size_t)k * 128 + c0 + 4);
            acc[0] = fmaf(a, w0.x, acc[0]); acc[1] = fmaf(a, w0.y, acc[1]);
            acc[2] = fmaf(a, w0.z, acc[2]); acc[3] = fmaf(a, w0.w, acc[3]);
            acc[4] = fmaf(a, w1.x, acc[4]); acc[5] = fmaf(a, w1.y, acc[5]);
            acc[6] = fmaf(a, w1.z, acc[6]); acc[7] = fmaf(a, w1.w, acc[7]);
        }
    }
    if (prow >= 0) {
        const float* pr = pos + (size_t)prow * 128 + c0;
        float4 p0 = *(const float4*)(pr);
        float4 p1 = *(const float4*)(pr + 4);
        acc[0] += p0.x; acc[1] += p0.y; acc[2] += p0.z; acc[3] += p0.w;
        acc[4] += p1.x; acc[5] += p1.y; acc[6] += p1.z; acc[7] += p1.w;
    }
    *(float4*)(xin + (size_t)R * 128 + c0) = make_float4(acc[0], acc[1], acc[2], acc[3]);
    *(float4*)(xin + (size_t)R * 128 + c0 + 4) = make_float4(acc[4], acc[5], acc[6], acc[7]);
    *(ushort4*)&As[r][c0] = make_ushort4(f2u(acc[0]), f2u(acc[1]), f2u(acc[2]), f2u(acc[3]));
    *(ushort4*)&As[r][c0 + 4] = make_ushort4(f2u(acc[4]), f2u(acc[5]), f2u(acc[6]), f2u(acc[7]));
    __syncthreads();

    int wv = tid >> 6, lane = tid & 63;
    int am = lane & 15, aq = lane >> 4;
    int col = lane & 15, rowb = (lane >> 4) * 4;
    const unsigned short* Ws[3] = {Wq, Wk, Wv};
    const float* bs[3] = {bq, bk, bv_};
    float bsc[3] = {0.125f, 1.f, 1.f};
    unsigned short* Cs[3] = {outq, outk, outv};
    #pragma unroll
    for (int y = 0; y < 3; ++y) {
        floatx4 acc0 = {0.f, 0.f, 0.f, 0.f}, acc1 = acc0;
        #pragma unroll
        for (int ks = 0; ks < 4; ++ks) {
            bf16x8 af = *(bf16x8*)&As[am][ks * 32 + aq * 8];
            const unsigned short* base = Ws[y] + ((size_t)ks * 8 + 2 * wv) * 512 + lane * 8;
            bf16x8 b0 = *(const bf16x8*)(base);
            bf16x8 b1 = *(const bf16x8*)(base + 512);
            acc0 = __builtin_amdgcn_mfma_f32_16x16x32_bf16(af, b0, acc0, 0, 0, 0);
            acc1 = __builtin_amdgcn_mfma_f32_16x16x32_bf16(af, b1, acc1, 0, 0, 0);
        }
        #pragma unroll
        for (int t = 0; t < 2; ++t) {
            floatx4 a2 = t ? acc1 : acc0;
            int n = wv * 32 + t * 16 + col;
            float bvv = bs[y][n] * bsc[y];
            #pragma unroll
            for (int rg = 0; rg < 4; ++rg)
                Cs[y][(size_t)(m0 + rowb + rg) * 128 + n] = f2u(a2[rg] + bvv);
        }
    }
}

// ---------------------------------------------------------------------------
// tblock attention partial: main 3 K-chunks (192 each), cls 1 chunk.
// Grid 1728 1D (b = F&7). Writes UNNORMALIZED O partials + (m,l).
// main pidx = ((b*2+h)*33+qt)*3+ch ; cls pidx = (b*2+h)*9+qt.
__global__ void __launch_bounds__(256)
tb_att_part_kernel(const unsigned short* qp, const unsigned short* kp,
                   const unsigned short* vp,
                   float* opm, float* mlm, float* opc, float* mlc) {
    int F = blockIdx.x;
    int b = F & 7;
    int j2 = F >> 3;               // 0..215
    int h = j2 & 1;
    int t = j2 >> 1;               // 0..107
    int is_cls = (t >= 99);
    int qt, ch;
    if (is_cls) { qt = t - 99; ch = 0; }
    else        { qt = t / 3;  ch = t - qt * 3; }
    int Lq = is_cls ? 129 : 513;
    int base = is_cls ? (4104 + b * 129) : (b * 513);
    int tid = threadIdx.x, lane = tid & 63, wv = tid >> 6;
    __shared__ unsigned short Qs[16][72];
    __shared__ unsigned short KV[64][72];
    __shared__ unsigned short sp[16][200];   // 192 + pad
    __shared__ float mrow[16], lrow[16];
    int q0 = qt * 16;
    int kg0 = ch * 192;

    if (tid < 128) {
        int r = tid >> 3, c0 = (tid & 7) * 8;
        int qr = q0 + r;
        ushortx8 v = {0, 0, 0, 0, 0, 0, 0, 0};
        if (qr < Lq) v = *(const ushortx8*)(qp + (size_t)(base + qr) * 128 + h * 64 + c0);
        *(ushortx8*)&Qs[r][c0] = v;
    }
    __syncthreads();

    bf16x8 qf0, qf1;
    {
        int m = lane & 15, g = lane >> 4;
        qf0 = *(const bf16x8*)&Qs[m][g * 8];
        qf1 = *(const bf16x8*)&Qs[m][32 + g * 8];
    }

    #pragma unroll
    for (int kt = 0; kt < 3; ++kt) {
        int k0 = kt * 64;
        {
            int kk = tid >> 3, e0 = (tid & 7) * 8;
            #pragma unroll
            for (int it = 0; it < 2; ++it, kk += 32) {
                int krow = kg0 + k0 + kk;
                ushortx8 v = {0, 0, 0, 0, 0, 0, 0, 0};
                if (krow < Lq) v = *(const ushortx8*)(kp + (size_t)(base + krow) * 128 + h * 64 + e0);
                *(ushortx8*)&KV[kk][e0] = v;
            }
        }
        __syncthreads();
        int kn = lane & 15, g = lane >> 4;
        floatx4 acc = {0.f, 0.f, 0.f, 0.f};
        {
            bf16x8 b0 = *(const bf16x8*)&KV[wv * 16 + kn][g * 8];
            acc = __builtin_amdgcn_mfma_f32_16x16x32_bf16(qf0, b0, acc, 0, 0, 0);
            bf16x8 b1 = *(const bf16x8*)&KV[wv * 16 + kn][32 + g * 8];
            acc = __builtin_amdgcn_mfma_f32_16x16x32_bf16(qf1, b1, acc, 0, 0, 0);
        }
        int colk = k0 + wv * 16 + kn;
        #pragma unroll
        for (int rg = 0; rg < 4; ++rg)
            sp[g * 4 + rg][colk] = f2u((kg0 + colk < Lq) ? acc[rg] : -1e30f);
        __syncthreads();
    }

    for (int rr = wv; rr < 16; rr += 4) {
        float m = -1e30f;
        #pragma unroll
        for (int k = 0; k < 3; ++k) m = fmaxf(m, u2f(sp[rr][k * 64 + lane]));
        m = wave_reduce_max(m);
        float sum = 0.f;
        #pragma unroll
        for (int k = 0; k < 3; ++k) {
            float e = expf(u2f(sp[rr][k * 64 + lane]) - m);
            sp[rr][k * 64 + lane] = f2u(e);
            sum += e;
        }
        sum = wave_reduce_sum(sum);
        if (lane == 0) { mrow[rr] = m; lrow[rr] = sum; }
    }

    floatx4 oacc = {0.f, 0.f, 0.f, 0.f};
    #pragma unroll
    for (int kt = 0; kt < 3; ++kt) {
        int k0 = kt * 64;
        __syncthreads();
        {
            int kk = tid & 31, e0 = (tid >> 5) * 8;
            #pragma unroll
            for (int it = 0; it < 2; ++it, kk += 32) {
                int krow = kg0 + k0 + kk;
                ushortx8 v = {0, 0, 0, 0, 0, 0, 0, 0};
                if (krow < Lq) v = *(const ushortx8*)(vp + (size_t)(base + krow) * 128 + h * 64 + e0);
                #pragma unroll
                for (int j3 = 0; j3 < 8; ++j3) KV[e0 + j3][kk] = v[j3];
            }
        }
        __syncthreads();
        int dn = lane & 15, g = lane >> 4;
        #pragma unroll
        for (int c = 0; c < 2; ++c) {
            bf16x4 plo = *(const bf16x4*)&sp[lane & 15][k0 + c * 32 + g * 8];
            bf16x4 phi = *(const bf16x4*)&sp[lane & 15][k0 + c * 32 + g * 8 + 4];
            bf16x8 vf = *(const bf16x8*)&KV[wv * 16 + dn][c * 32 + g * 8];
            oacc = __builtin_amdgcn_mfma_f32_16x16x32_bf16(join8(plo, phi), vf, oacc, 0, 0, 0);
        }
    }
    float* op = is_cls ? (opc + ((size_t)((b * 2 + h) * 9 + qt)) * 1024)
                       : (opm + ((size_t)(((b * 2 + h) * 33 + qt) * 3 + ch)) * 1024);
    int dcol = wv * 16 + (lane & 15), g = lane >> 4;
    #pragma unroll
    for (int rg = 0; rg < 4; ++rg) {
        int q = g * 4 + rg;
        op[q * 64 + dcol] = oacc[rg];           // unnormalized
    }
    if (tid < 16) {
        float* ml = is_cls ? (mlc + ((size_t)((b * 2 + h) * 9 + qt)) * 32)
                           : (mlm + ((size_t)(((b * 2 + h) * 33 + qt) * 3 + ch)) * 32);
        ml[tid * 2]     = mrow[tid];
        ml[tid * 2 + 1] = lrow[tid];
    }
}

// ---------------------------------------------------------------------------
// attnout: combine tb partials -> A tile, then attnout + LN1 + FFN + LN2 +
// pool -> d_out. Grid 321 tiles.
__global__ void __launch_bounds__(256)
attnout_ffn_kernel(const float* opm, const float* mlm,
                   const float* opc, const float* mlc,
                   const unsigned short* Wao, const float* bao,
                   const float* resid, const float* g1, const float* b1ln,
                   const unsigned short* W1, const float* fb1,
                   const unsigned short* W2, const float* fb2,
                   const float* g2, const float* b2ln,
                   const float* pW, const float* pb, float* dout) {
    int m0 = blockIdx.x * 16;
    __shared__ unsigned short As[16][136];
    __shared__ float Xs[16][128];
    __shared__ unsigned short Hs[16][136];
    __shared__ float redS[4][4][4], redQ[4][4][4];
    __shared__ float smean[16], sinv[16];
    __shared__ float x2row[128];
    __shared__ int poolb;
    int tid = threadIdx.x;
    if (tid == 0) poolb = -1;
    {
        // combine: row r, 8 cols starting c0
        int r = tid >> 4, c0 = (tid & 15) * 8;
        int R = m0 + r;
        int iscl, bb, rr;
        if (R < NM_) { bb = R / 513; rr = R - bb * 513; iscl = 0; }
        else { int mc = R - NM_; bb = mc / 129; rr = mc - bb * 129; iscl = 1; }
        int qt = rr >> 4, lr = rr & 15;
        int hh = c0 >> 6, d0 = c0 & 63;
        float vals[8];
        if (iscl) {
            size_t pb2 = (size_t)((bb * 2 + hh) * 9 + qt);
            const float* op = opc + pb2 * 1024 + lr * 64 + d0;
            float linv = 1.f / mlc[pb2 * 32 + lr * 2 + 1];
            #pragma unroll
            for (int jj = 0; jj < 8; ++jj) vals[jj] = op[jj] * linv;
        } else {
            size_t pb2 = (size_t)(((bb * 2 + hh) * 33 + qt) * 3);
            const float* op0 = opm + (pb2 + 0) * 1024 + lr * 64 + d0;
            const float* op1 = opm + (pb2 + 1) * 1024 + lr * 64 + d0;
            const float* op2 = opm + (pb2 + 2) * 1024 + lr * 64 + d0;
            float m0v = mlm[(pb2 + 0) * 32 + lr * 2];
            float m1v = mlm[(pb2 + 1) * 32 + lr * 2];
            float m2v = mlm[(pb2 + 2) * 32 + lr * 2];
            float l0 = mlm[(pb2 + 0) * 32 + lr * 2 + 1];
            float l1 = mlm[(pb2 + 1) * 32 + lr * 2 + 1];
            float l2 = mlm[(pb2 + 2) * 32 + lr * 2 + 1];
            float mm = fmaxf(fmaxf(m0v, m1v), m2v);
            float e0 = expf(m0v - mm), e1 = expf(m1v - mm), e2 = expf(m2v - mm);
            float linv = 1.f / (l0 * e0 + l1 * e1 + l2 * e2);
            #pragma unroll
            for (int jj = 0; jj < 8; ++jj)
                vals[jj] = (op0[jj] * e0 + op1[jj] * e1 + op2[jj] * e2) * linv;
        }
        unsigned short o8[8];
        #pragma unroll
        for (int jj = 0; jj < 8; ++jj) o8[jj] = f2u(vals[jj]);
        *(ushortx8*)&As[r][c0] = *(ushortx8*)o8;
    }
    __syncthreads();

    int wv = tid >> 6, lane = tid & 63;
    int am = lane & 15, aq = lane >> 4;
    int col = lane & 15, g = lane >> 4, rowb = g * 4;

    float ov[2][4];
    {
        floatx4 acc0 = {0.f, 0.f, 0.f, 0.f}, acc1 = acc0;
        #pragma unroll
        for (int ks = 0; ks < 4; ++ks) {
            bf16x8 af = *(bf16x8*)&As[am][ks * 32 + aq * 8];
            const unsigned short* base = Wao + ((size_t)ks * 8 + 2 * wv) * 512 + lane * 8;
            bf16x8 bb0 = *(const bf16x8*)(base);
            bf16x8 bb1 = *(const bf16x8*)(base + 512);
            acc0 = __builtin_amdgcn_mfma_f32_16x16x32_bf16(af, bb0, acc0, 0, 0, 0);
            acc1 = __builtin_amdgcn_mfma_f32_16x16x32_bf16(af, bb1, acc1, 0, 0, 0);
        }
        #pragma unroll
        for (int t = 0; t < 2; ++t) {
            int n = wv * 32 + t * 16 + col;
            float bv = bao[n];
            floatx4 acc = t ? acc1 : acc0;
            #pragma unroll
            for (int rg = 0; rg < 4; ++rg)
                ov[t][rg] = acc[rg] + bv + resid[(size_t)(m0 + rowb + rg) * 128 + n];
        }
    }
    #pragma unroll
    for (int rg = 0; rg < 4; ++rg) {
        float s = ov[0][rg] + ov[1][rg];
        float q = ov[0][rg] * ov[0][rg] + ov[1][rg] * ov[1][rg];
        #pragma unroll
        for (int off = 8; off >= 1; off >>= 1) {
            s += __shfl_xor(s, off);
            q += __shfl_xor(q, off);
        }
        if ((lane & 15) == 0) { redS[wv][g][rg] = s; redQ[wv][g][rg] = q; }
    }
    __syncthreads();
    if (tid < 16) {
        int gg = tid >> 2, rg = tid & 3;
        float s = redS[0][gg][rg] + redS[1][gg][rg] + redS[2][gg][rg] + redS[3][gg][rg];
        float q = redQ[0][gg][rg] + redQ[1][gg][rg] + redQ[2][gg][rg] + redQ[3][gg][rg];
        float mean = s * 0.0078125f;
        float var = q * 0.0078125f - mean * mean;
        smean[tid] = mean;
        sinv[tid] = rsqrtf(var + 1e-5f);
    }
    __syncthreads();
    #pragma unroll
    for (int t = 0; t < 2; ++t) {
        int n = wv * 32 + t * 16 + col;
        float gm = g1[n], bb = b1ln[n];
        #pragma unroll
        for (int rg = 0; rg < 4; ++rg) {
            int row = rowb + rg;
            float val = (ov[t][rg] - smean[row]) * sinv[row] * gm + bb;
            Xs[row][n] = val;
            As[row][n] = f2u(val);
        }
    }
    __syncthreads();

    {
        floatx4 acc0 = {0.f, 0.f, 0.f, 0.f}, acc1 = acc0;
        #pragma unroll
        for (int ks = 0; ks < 4; ++ks) {
            bf16x8 af = *(bf16x8*)&As[am][ks * 32 + aq * 8];
            const unsigned short* base = W1 + ((size_t)ks * 8 + 2 * wv) * 512 + lane * 8;
            bf16x8 bb0 = *(const bf16x8*)(base);
            bf16x8 bb1 = *(const bf16x8*)(base + 512);
            acc0 = __builtin_amdgcn_mfma_f32_16x16x32_bf16(af, bb0, acc0, 0, 0, 0);
            acc1 = __builtin_amdgcn_mfma_f32_16x16x32_bf16(af, bb1, acc1, 0, 0, 0);
        }
        #pragma unroll
        for (int t = 0; t < 2; ++t) {
            int n = wv * 32 + t * 16 + col;
            float bv = fb1[n];
            floatx4 acc = t ? acc1 : acc0;
            #pragma unroll
            for (int rg = 0; rg < 4; ++rg)
                Hs[rowb + rg][n] = f2u(fmaxf(acc[rg] + bv, 0.f));
        }
    }
    __syncthreads();

    floatx4 acc0 = {0.f, 0.f, 0.f, 0.f}, acc1 = acc0;
    #pragma unroll
    for (int ks = 0; ks < 4; ++ks) {
        bf16x8 af = *(bf16x8*)&Hs[am][ks * 32 + aq * 8];
        const unsigned short* base = W2 + ((size_t)ks * 8 + 2 * wv) * 512 + lane * 8;
        bf16x8 bb0 = *(const bf16x8*)(base);
        bf16x8 bb1 = *(const bf16x8*)(base + 512);
        acc0 = __builtin_amdgcn_mfma_f32_16x16x32_bf16(af, bb0, acc0, 0, 0, 0);
        acc1 = __builtin_amdgcn_mfma_f32_16x16x32_bf16(af, bb1, acc1, 0, 0, 0);
    }
    #pragma unroll
    for (int t = 0; t < 2; ++t) {
        int n = wv * 32 + t * 16 + col;
        float bv = fb2[n];
        floatx4 acc = t ? acc1 : acc0;
        #pragma unroll
        for (int rg = 0; rg < 4; ++rg)
            ov[t][rg] = acc[rg] + bv + Xs[rowb + rg][n];
    }
    #pragma unroll
    for (int rg = 0; rg < 4; ++rg) {
        float s = ov[0][rg] + ov[1][rg];
        float q = ov[0][rg] * ov[0][rg] + ov[1][rg] * ov[1][rg];
        #pragma unroll
        for (int off = 8; off >= 1; off >>= 1) {
            s += __shfl_xor(s, off);
            q += __shfl_xor(q, off);
        }
        if ((lane & 15) == 0) { redS[wv][g][rg] = s; redQ[wv][g][rg] = q; }
    }
    __syncthreads();
    if (tid < 16) {
        int gg = tid >> 2, rg = tid & 3;
        float s = redS[0][gg][rg] + redS[1][gg][rg] + redS[2][gg][rg] + redS[3][gg][rg];
        float q = redQ[0][gg][rg] + redQ[1][gg][rg] + redQ[2][gg][rg] + redQ[3][gg][rg];
        float mean = s * 0.0078125f;
        float var = q * 0.0078125f - mean * mean;
        smean[tid] = mean;
        sinv[tid] = rsqrtf(var + 1e-5f);
    }
    __syncthreads();
    #pragma unroll
    for (int t = 0; t < 2; ++t) {
        int n = wv * 32 + t * 16 + col;
        float gm = g2[n], bb = b2ln[n];
        #pragma unroll
        for (int rg = 0; rg < 4; ++rg) {
            int row = rowb + rg;
            int m = m0 + row;
            float val = (ov[t][rg] - smean[row]) * sinv[row] * gm + bb;
            if (m < NM_) {
                int b = m / 513, r2 = m - b * 513;
                if (r2 >= 1)
                    dout[1024 + (size_t)b * 65536 + (size_t)(r2 - 1) * 128 + n] = val;
            } else {
                int mc = m - NM_;
                int b = mc / 129, r2 = mc - b * 129;
                if (r2 == 0) {
                    x2row[n] = val;
                    if (n == 0) poolb = b;
                }
            }
        }
    }
    __syncthreads();
    if (poolb >= 0 && tid < 128) {
        float acc = pb[tid];
        for (int k = 0; k < 128; ++k) acc = fmaf(x2row[k], pW[(size_t)k * 128 + tid], acc);
        dout[(size_t)poolb * 128 + tid] = tanhf(acc);
    }
}

// ---------------------------------------------------------------------------
extern "C" void kernel_launch(void* const* d_in, const int* in_sizes, int n_in,
                              void* d_out, int out_size, void* d_ws, size_t ws_size,
                              hipStream_t stream) {
    float* w = (float*)d_ws;
    size_t off = 0;
    auto alloc = [&](size_t n) {
        float* p = w + off;
        off += (n + 3) & ~(size_t)3;
        return p;
    };
    auto allocU = [&](size_t n) { return (unsigned short*)alloc((n + 1) / 2); };

    PrepAll pa{};
    int nn = n_in < 32 ? n_in : 32;
    float* fin[32];
    const int needconv[32] = {0,0,0,0,0,0, 0,1, 0,1, 1,1, 1,1, 0,1, 0,1, 0,1,
                              0,1, 1,1, 0,1, 0,1, 1,1, 1,1};
    int ncv = 0;
    for (int i = 0; i < nn; ++i) {
        pa.src[i] = d_in[i];
        pa.n[i] = in_sizes[i];
        fin[i] = alloc(in_sizes[i]);
        pa.dstoff[i] = (int)(fin[i] - w);
        if (needconv[i]) {
            int nb = (in_sizes[i] + 255) / 256;
            pa.cstart[i] = ncv;
            pa.cnum[i] = nb;
            ncv += nb;
        } else { pa.cstart[i] = -1; pa.cnum[i] = 0; }
    }
    for (int i = nn; i < 32; ++i) {
        pa.src[i] = nullptr; pa.n[i] = 0; pa.dstoff[i] = 0;
        pa.cstart[i] = -1; pa.cnum[i] = 0;
    }
    pa.ncv = ncv;

    const float* bq_t    = fin[7];
    const float* bk_t    = fin[9];
    const float* Wo_t    = fin[10]; const float* bo_t = fin[11];
    const float* pos_emb = fin[12]; const float* cls_emb = fin[13];
    const float* tbq = fin[15]; const float* tbk = fin[17]; const float* tbv = fin[19];
    const float* tbo = fin[21];
    const float* ln1_g = fin[22]; const float* ln1_b = fin[23];
    const float* fb1 = fin[25]; const float* fb2 = fin[27];
    const float* ln2_g = fin[28]; const float* ln2_b = fin[29];
    const float* pW = fin[30]; const float* pb = fin[31];

    const int widx[8] = {8, 6, 14, 16, 18, 20, 24, 26};
    unsigned short* wsw[8];
    for (int i = 0; i < 8; ++i) {
        wsw[i] = allocU(16384);
        pa.wsrc[i] = d_in[widx[i]];
        pa.wdst[i] = wsw[i];
        pa.wscale[i] = (i == 1 || i == 2) ? 0.125f : 1.0f;
    }
    pa.ts = d_in[1]; pa.w_per = d_in[2]; pa.b_per = d_in[3];
    pa.w_lin = d_in[4]; pa.b_lin = d_in[5];
    pa.xsrc = d_in[0];
    pa.det = (const unsigned short*)d_in[22];

    unsigned short* key_e16 = allocU(4224 * 128);
    unsigned short* cls_e16 = key_e16 + 4096 * 128;
    pa.key_e16 = key_e16;
    unsigned short* btg = allocU(8 * 16 * 512);
    pa.btg = btg;

    unsigned short* qp_main16 = allocU(4096 * 128);
    unsigned short* kp_main16 = allocU(4096 * 128);
    unsigned short* qp_cls16  = allocU(128 * 128);
    float* mpa = alloc(1280 * 256);          // mta chunk P@Bt partials
    float* mma = alloc(1280 * 16);           // mta chunk row max
    float* opm = alloc((size_t)1584 * 1024); // tb main O partials
    float* mlm = alloc(1584 * 32);           // tb main (m,l)
    float* opc = alloc((size_t)144 * 1024);  // tb cls O partials
    float* mlc = alloc(144 * 32);            // tb cls (m,l)
    float* xin = alloc((size_t)NT_ * 128);
    unsigned short* tbq16 = allocU((size_t)NT_ * 128);
    unsigned short* tbk16 = allocU((size_t)NT_ * 128);
    unsigned short* tbv16 = allocU((size_t)NT_ * 128);
    (void)ws_size;

    float* outf = (float*)d_out;

    // 1: convert (dense) + weight swizzle + time embedding + Bt build
    prep_all_kernel<<<ncv + 512 + 2112 + 32, 256, 0, stream>>>(pa, w);

    // 2: mta projections
    {
        GemmM p{};
        p.A[0] = key_e16; p.W[0] = wsw[0]; p.bias[0] = bk_t; p.C[0] = kp_main16;
        p.M[0] = 4096; p.bscale[0] = 1.f;
        p.A[1] = key_e16; p.W[1] = wsw[1]; p.bias[1] = bq_t; p.C[1] = qp_main16;
        p.M[1] = 4096; p.bscale[1] = 0.125f;
        p.A[2] = cls_e16; p.W[2] = wsw[1]; p.bias[2] = bq_t; p.C[2] = qp_cls16;
        p.M[2] = 128; p.bscale[2] = 0.125f;
        gemm_mfma_kernel<<<dim3(256, 3), 256, 0, stream>>>(p);
    }

    // 3: mta attention partials (K split x2; 1280 blocks, b = F&7)
    mta_att_part_kernel<<<1280, 256, 0, stream>>>(qp_cls16, qp_main16, kp_main16,
                                                  btg, mpa, mma);

    // 4: combine + mta-out + assemble + QKV
    mta_qkv_kernel<<<321, 256, 0, stream>>>(mpa, mma, Wo_t, bo_t, cls_emb, pos_emb, xin,
                                            wsw[2], wsw[3], wsw[4], tbq, tbk, tbv,
                                            tbq16, tbk16, tbv16);

    // 5: tblock attention partials (K split x3 main; 1728 blocks, b = F&7)
    tb_att_part_kernel<<<1728, 256, 0, stream>>>(tbq16, tbk16, tbv16,
                                                 opm, mlm, opc, mlc);

    // 6: combine + attnout + LN1 + FFN + LN2 + pool -> d_out
    attnout_ffn_kernel<<<321, 256, 0, stream>>>(opm, mlm, opc, mlc,
                                                wsw[5], tbo, xin, ln1_g, ln1_b,
                                                wsw[6], fb1, wsw[7], fb2, ln2_g, ln2_b,
                                                pW, pb, outf);
}